// Round 6
// baseline (546.080 us; speedup 1.0000x reference)
//
#include <hip/hip_runtime.h>

static constexpr int Hc  = 512;
static constexpr int NHc = 8;
static constexpr int DHc = 64;
static constexpr int NLc = 2;
static constexpr int Rc  = 64;
static constexpr int FFc = 2048;
static constexpr int Bc  = 4;
static constexpr int Tc  = 512;
#define NEGV (-1e10f)
#define EPSV 1e-5f
#define THRV 6.0f

typedef unsigned short u16;
typedef __attribute__((ext_vector_type(8))) short s16x8;
typedef __attribute__((ext_vector_type(4))) float f32x4;

__device__ __forceinline__ f32x4 mfma_bf16(s16x8 a, s16x8 b, f32x4 c) {
  return __builtin_amdgcn_mfma_f32_16x16x32_bf16(a, b, c, 0, 0, 0);
}
__device__ __forceinline__ u16 f2bf(float f) {
  union { float f; unsigned u; } x; x.f = f;
  unsigned r = (x.u + 0x7FFFu + ((x.u >> 16) & 1u)) >> 16;
  return (u16)r;
}
__device__ __forceinline__ float bf2f(u16 h) {
  union { unsigned u; float f; } x; x.u = ((unsigned)h) << 16;
  return x.f;
}
__device__ __forceinline__ unsigned cvtpk(float a, float b) {
  unsigned r;
  asm("v_cvt_pk_bf16_f32 %0, %1, %2" : "=v"(r) : "v"(a), "v"(b));
  return r;
}

// ---------------------------------------------------------------------------
// bf16 MFMA GEMM: C[M,N] = A[M,K] @ Wt[N,K]^T (+bias for col<biasN) (+relu)
// 256 threads, 4 waves (2x2). BK=32. LDS 16B-chunk XOR swizzle.
// ---------------------------------------------------------------------------
template <int BM, int BN, bool RELU, int OUT>  // OUT: 0=f32, 1=bf16
__global__ __launch_bounds__(256) void gemm_mfma(
    const u16* __restrict__ A, const u16* __restrict__ Wt,
    const float* __restrict__ bias, int biasN,
    void* __restrict__ Cout, int N, int K) {
  __shared__ u16 As[BM * 32];
  __shared__ u16 Bs[BN * 32];
  const int tid = threadIdx.x;
  const int w = tid >> 6, lane = tid & 63, g = lane >> 4, li = lane & 15;
  const int bn = blockIdx.x * BN, bm = blockIdx.y * BM;
  const int r0 = (w & 1) * (BM / 2), c0 = (w >> 1) * (BN / 2);
  constexpr int MR = BM / 32, NR = BN / 32;
  f32x4 acc[MR][NR];
#pragma unroll
  for (int i = 0; i < MR; ++i)
#pragma unroll
    for (int j = 0; j < NR; ++j) acc[i][j] = (f32x4){0.f, 0.f, 0.f, 0.f};

  for (int k0 = 0; k0 < K; k0 += 32) {
    __syncthreads();
#pragma unroll
    for (int it = 0; it < BM / 64; ++it) {
      int s = it * 256 + tid;
      int row = s >> 2, ch = s & 3;
      s16x8 v = *(const s16x8*)(A + (size_t)(bm + row) * K + k0 + ch * 8);
      *(s16x8*)&As[row * 32 + ((ch ^ (row & 3)) * 8)] = v;
    }
#pragma unroll
    for (int it = 0; it < BN / 64; ++it) {
      int s = it * 256 + tid;
      int row = s >> 2, ch = s & 3;
      s16x8 v = *(const s16x8*)(Wt + (size_t)(bn + row) * K + k0 + ch * 8);
      *(s16x8*)&Bs[row * 32 + ((ch ^ (row & 3)) * 8)] = v;
    }
    __syncthreads();
    s16x8 ar[MR], br[NR];
#pragma unroll
    for (int i = 0; i < MR; ++i) {
      int row = r0 + i * 16 + li;
      ar[i] = *(const s16x8*)&As[row * 32 + ((g ^ (row & 3)) * 8)];
    }
#pragma unroll
    for (int j = 0; j < NR; ++j) {
      int row = c0 + j * 16 + li;
      br[j] = *(const s16x8*)&Bs[row * 32 + ((g ^ (row & 3)) * 8)];
    }
#pragma unroll
    for (int i = 0; i < MR; ++i)
#pragma unroll
      for (int j = 0; j < NR; ++j) acc[i][j] = mfma_bf16(ar[i], br[j], acc[i][j]);
  }

#pragma unroll
  for (int j = 0; j < NR; ++j) {
    int col = bn + c0 + j * 16 + li;
    float bv = (bias && col < biasN) ? bias[col] : 0.f;
#pragma unroll
    for (int i = 0; i < MR; ++i) {
#pragma unroll
      for (int r = 0; r < 4; ++r) {
        int rowg = bm + r0 + i * 16 + 4 * g + r;
        float v = acc[i][j][r] + bv;
        if (RELU) v = fmaxf(v, 0.f);
        if (OUT == 0) ((float*)Cout)[(size_t)rowg * N + col] = v;
        else          ((u16*)Cout)[(size_t)rowg * N + col] = f2bf(v);
      }
    }
  }
}

// ---------------------------------------------------------------------------
// Weight transpose+convert: f32 [Ks][Ns] -> bf16 [Ns][Ks] at dstOff
// ---------------------------------------------------------------------------
struct WPtrs { const float* p[10]; };

__global__ __launch_bounds__(256) void wcvt(WPtrs wp, u16* __restrict__ dst) {
  constexpr int NE = 20;
  constexpr int srcIdx[NE] = {0,1,0,1,3,3,4,4,5,5,6,6,7,7,2,2,8,8,9,9};
  constexpr int srcOff[NE] = {0,0,262144,262144,0,262144,0,262144,0,262144,
                              0,262144,0,262144,0,262144,0,1048576,0,1048576};
  constexpr int dstOff[NE] = {0,262144,524288,786432,1048576,1310720,
                              1572864,1835008,2097152,2359296,2621440,2883584,
                              3145728,3407872,3670016,3932160,
                              4194304,5242880,6291456,7340032};
  constexpr int KsA[NE] = {512,512,512,512,512,512,512,512,512,512,
                           512,512,512,512,512,512,512,512,2048,2048};
  constexpr int NsA[NE] = {512,512,512,512,512,512,512,512,512,512,
                           512,512,512,512,512,512,2048,2048,512,512};
  constexpr int tileStart[NE] = {0,64,128,192,256,320,384,448,512,576,
                                 640,704,768,832,896,960,1024,1280,1536,1792};
  __shared__ float ts[64 * 65];
  const int tid = threadIdx.x;
  const int bid = blockIdx.x;
  int e = 0;
#pragma unroll
  for (int i = 1; i < NE; ++i) if (bid >= tileStart[i]) e = i;
  const int t = bid - tileStart[e];
  const int Ks_ = KsA[e], Ns_ = NsA[e];
  const int tn = t % (Ns_ >> 6), tk = t / (Ns_ >> 6);
  const float* src = wp.p[srcIdx[e]] + srcOff[e];

  {
    int r = tid >> 2, cb = (tid & 3) * 16;
    const float* sp = src + (size_t)(tk * 64 + r) * Ns_ + tn * 64 + cb;
#pragma unroll
    for (int j = 0; j < 4; ++j) {
      float4 v = ((const float4*)sp)[j];
      float* d = &ts[r * 65 + cb + j * 4];
      d[0] = v.x; d[1] = v.y; d[2] = v.z; d[3] = v.w;
    }
  }
  __syncthreads();
  {
    int n = tid >> 2, kb = (tid & 3) * 16;
    u16* dp = dst + dstOff[e] + (size_t)(tn * 64 + n) * Ks_ + tk * 64 + kb;
    s16x8 o0, o1;
#pragma unroll
    for (int j = 0; j < 8; ++j) o0[j] = (short)f2bf(ts[(kb + j) * 65 + n]);
#pragma unroll
    for (int j = 0; j < 8; ++j) o1[j] = (short)f2bf(ts[(kb + 8 + j) * 65 + n]);
    *(s16x8*)dp = o0;
    *(s16x8*)(dp + 8) = o1;
  }
}

// ---------------------------------------------------------------------------
// activations f32->bf16 (blocks 0..1023); block 1024: relv -> relv^T bf16
// ---------------------------------------------------------------------------
__global__ __launch_bounds__(256) void acvt(
    const float* __restrict__ q, const float* __restrict__ kv,
    const float* __restrict__ relv,
    u16* __restrict__ obf, u16* __restrict__ kvbf, u16* __restrict__ relvt) {
  int bid = blockIdx.x, tid = threadIdx.x;
  if (bid == 1024) {
    int d = tid >> 2, rb = (tid & 3) * 16;
    s16x8 o0, o1;
#pragma unroll
    for (int j = 0; j < 8; ++j) o0[j] = (short)f2bf(relv[(rb + j) * 64 + d]);
#pragma unroll
    for (int j = 0; j < 8; ++j) o1[j] = (short)f2bf(relv[(rb + 8 + j) * 64 + d]);
    *(s16x8*)(relvt + d * 64 + rb) = o0;
    *(s16x8*)(relvt + d * 64 + rb + 8) = o1;
    return;
  }
  int i = bid * 256 + tid;
  const float* src; u16* dst; size_t off;
  if (i < 131072) { src = q; dst = obf; off = (size_t)i * 8; }
  else { src = kv; dst = kvbf; off = (size_t)(i - 131072) * 8; }
  float4 a = *(const float4*)(src + off);
  float4 b = *(const float4*)(src + off + 4);
  s16x8 o;
  o[0] = (short)f2bf(a.x); o[1] = (short)f2bf(a.y);
  o[2] = (short)f2bf(a.z); o[3] = (short)f2bf(a.w);
  o[4] = (short)f2bf(b.x); o[5] = (short)f2bf(b.y);
  o[6] = (short)f2bf(b.z); o[7] = (short)f2bf(b.w);
  *(s16x8*)(dst + off) = o;
}

// ---------------------------------------------------------------------------
// Qr[(row*8+h), r] = sum_d Q[row, h*64+d] * relk[r, d]  (Q = bQK, stride 1024)
// ---------------------------------------------------------------------------
__global__ __launch_bounds__(256) void qr_kernel(
    const u16* __restrict__ Q, const float* __restrict__ relk,
    float* __restrict__ Qr) {
  __shared__ float rk[64 * 65];
  __shared__ float qs[4][64];
  const int tid = threadIdx.x;
  {
    int r = tid >> 2, cb = (tid & 3) * 16;
    const float* sp = relk + r * 64 + cb;
#pragma unroll
    for (int j = 0; j < 4; ++j) {
      float4 v = ((const float4*)sp)[j];
      float* d = &rk[r * 65 + cb + j * 4];
      d[0] = v.x; d[1] = v.y; d[2] = v.z; d[3] = v.w;
    }
  }
  const int sub = tid >> 6, r = tid & 63;
  const int unit = blockIdx.x * 4 + sub;  // unit = row*8 + h
  qs[sub][r] = bf2f(Q[(size_t)(unit >> 3) * 1024 + (unit & 7) * 64 + r]);
  __syncthreads();
  float acc = 0.f;
#pragma unroll
  for (int d = 0; d < 64; ++d) acc += qs[sub][d] * rk[r * 65 + d];
  Qr[(size_t)unit * 64 + r] = acc;
}

// ---------------------------------------------------------------------------
// Relation-aware masked self-attention, SPLIT-KV: 4 waves/block, wave w
// handles chunks c = w, w+4, ... <= c_hi with private (mrow,rsum,oacc,buck);
// exact merge via m = max_w, f_w = exp(m_w - m); rel-V folded per wave.
// Grid: (32 qtile16, 8 head, 4 batch) x 256 threads.
// ---------------------------------------------------------------------------
#define RELID(RV, r) ((r) == 0 ? (RV).x : (r) == 1 ? (RV).y : (r) == 2 ? (RV).z : (RV).w)

#define LOADKREL(KF, RF, C8) do {                                              \
    _Pragma("unroll") for (int mt = 0; mt < 4; ++mt) {                         \
      KF[mt * 2 + 0] = *(const s16x8*)(kp + (size_t)(C8) * 65536 + mt * 16384);\
      KF[mt * 2 + 1] = *(const s16x8*)(kp + (size_t)(C8) * 65536 + mt * 16384 + 32); \
      RF[mt] = *(const int4*)(rp + (C8) * 64 + mt * 16);                       \
    } } while (0)

#define COMPUTE_SELF(KF, RF, C8) do {                                          \
    s16x8 vf[8];                                                               \
    _Pragma("unroll") for (int df = 0; df < 4; ++df) {                         \
      vf[df * 2 + 0] = *(const s16x8*)(vp + (size_t)(C8) * 64 + df * 32768);   \
      vf[df * 2 + 1] = *(const s16x8*)(vp + (size_t)(C8) * 64 + df * 32768 + 32); } \
    f32x4 sf[4];                                                               \
    _Pragma("unroll") for (int mt = 0; mt < 4; ++mt) {                         \
      sf[mt] = (f32x4){0.f, 0.f, 0.f, 0.f};                                    \
      sf[mt] = mfma_bf16(KF[mt * 2 + 0], aq0, sf[mt]);                         \
      sf[mt] = mfma_bf16(KF[mt * 2 + 1], aq1, sf[mt]); }                       \
    float p[4][4];                                                             \
    float pmax = NEGV;                                                         \
    _Pragma("unroll") for (int mt = 0; mt < 4; ++mt) {                         \
      _Pragma("unroll") for (int r = 0; r < 4; ++r) {                          \
        int rel = RELID(RF[mt], r);                                            \
        bool valid = (rel != 0) && ((C8) * 64 + mt * 16 + 4 * g + r <= lrow);  \
        p[mt][r] = valid ? (sf[mt][r] + qrs[li * 66 + rel]) * 0.125f : NEGV;   \
        pmax = fmaxf(pmax, p[mt][r]); } }                                      \
    pmax = fmaxf(pmax, __shfl_xor(pmax, 16));                                  \
    pmax = fmaxf(pmax, __shfl_xor(pmax, 32));                                  \
    if (__any(pmax > mrow + THRV)) {                                           \
      float mnew = (pmax > mrow + THRV) ? pmax : mrow;                         \
      float f = __expf(mrow - mnew);                                           \
      rsum *= f;                                                               \
      _Pragma("unroll") for (int j = 0; j < 8; ++j) {                          \
        float2* p2 = (float2*)&bk[li * 66 + g * 16 + 2 * j];                   \
        float2 v = *p2; v.x *= f; v.y *= f; *p2 = v; }                         \
      _Pragma("unroll") for (int r = 0; r < 4; ++r) {                          \
        float fr = __shfl(f, 4 * g + r);                                       \
        _Pragma("unroll") for (int df = 0; df < 4; ++df) oacc[df][r] *= fr; }  \
      mrow = mnew; }                                                           \
    unsigned pk[4][2];                                                         \
    _Pragma("unroll") for (int mt = 0; mt < 4; ++mt) {                         \
      _Pragma("unroll") for (int r = 0; r < 4; ++r) {                          \
        float pv = __expf(p[mt][r] - mrow);                                    \
        p[mt][r] = pv;                                                         \
        rsum += pv;                                                            \
        if (pv > 0.f) atomicAdd(&bk[li * 66 + RELID(RF[mt], r)], pv); }        \
      pk[mt][0] = cvtpk(p[mt][0], p[mt][1]);                                   \
      pk[mt][1] = cvtpk(p[mt][2], p[mt][3]); }                                 \
    _Pragma("unroll") for (int kk = 0; kk < 2; ++kk) {                         \
      union { s16x8 v; unsigned u[4]; } pa;                                    \
      _Pragma("unroll") for (int q = 0; q < 4; ++q) {                          \
        int src = ((2 * (g & 1) + (q >> 1)) << 4) + li;                        \
        unsigned uA = __shfl(pk[2 * kk][q & 1], src);                          \
        unsigned uB = __shfl(pk[2 * kk + 1][q & 1], src);                      \
        pa.u[q] = (g < 2) ? uA : uB; }                                         \
      _Pragma("unroll") for (int df = 0; df < 4; ++df)                         \
        oacc[df] = mfma_bf16(pa.v, vf[df * 2 + kk], oacc[df]); }               \
  } while (0)

__global__ __launch_bounds__(256, 4) void attn_self(
    const u16* __restrict__ Qb, const u16* __restrict__ Kb,  // stride 1024
    const u16* __restrict__ VT,                              // [512][2048]
    const float* __restrict__ Qr, const int* __restrict__ rel_ids,
    const u16* __restrict__ relvt, u16* __restrict__ att) {
  __shared__ float qrs[16 * 66];
  __shared__ float buck[4 * 16 * 66];
  __shared__ float m_s[256];
  __shared__ float oaccA[16 * 64];
  __shared__ float r_sA[16];

  const int tid = threadIdx.x;
  const int w = tid >> 6, lane = tid & 63;
  const int g = lane >> 4, li = lane & 15;
  const int qt = blockIdx.x, h = blockIdx.y, b = blockIdx.z;
  const int lrow = qt * 16 + li;            // q-row within batch (this lane)
  const int growq = b * 512 + qt * 16;
  const int c_hi = qt >> 2;
  float* bk = buck + w * (16 * 66);         // this wave's private buckets

  const u16* qp = Qb + (size_t)(growq + li) * 1024 + h * 64;
  s16x8 aq0 = *(const s16x8*)(qp + g * 8);
  s16x8 aq1 = *(const s16x8*)(qp + 32 + g * 8);
  const u16* kp = Kb + (size_t)(b * 512 + li) * 1024 + h * 64 + g * 8;
  const u16* vp = VT + (size_t)(h * 64 + li) * 2048 + b * 512 + g * 8;
  const int* rp = rel_ids + (size_t)(growq + li) * 512 + 4 * g;

  {  // stage Qr cooperatively; zero shared accumulators + own buckets
    int row = tid >> 4, c4 = (tid & 15) * 4;
    float4 v = *(const float4*)(Qr + ((size_t)(growq + row) * 8 + h) * 64 + c4);
    *(float4*)&qrs[row * 66 + c4] = v;
    ((float4*)oaccA)[tid] = make_float4(0.f, 0.f, 0.f, 0.f);
    if (tid < 16) r_sA[tid] = 0.f;
#pragma unroll
    for (int j = 0; j < 8; ++j)
      *(float2*)&bk[li * 66 + g * 16 + 2 * j] = make_float2(0.f, 0.f);
  }
  __syncthreads();

  float mrow = NEGV, rsum = 0.f;
  f32x4 oacc[4];
#pragma unroll
  for (int d = 0; d < 4; ++d) oacc[d] = (f32x4){0.f, 0.f, 0.f, 0.f};

  {  // main loop: chunks w, w+4, ... <= c_hi (2-deep prefetch)
    s16x8 kA[8], kB[8];
    int4 rA[4], rB[4];
    int c = w;
    if (c <= c_hi) {
      LOADKREL(kA, rA, c);
      for (;;) {
        if (c + 4 <= c_hi) LOADKREL(kB, rB, c + 4);
        COMPUTE_SELF(kA, rA, c);
        c += 4;
        if (c > c_hi) break;
        if (c + 4 <= c_hi) LOADKREL(kA, rA, c + 4);
        COMPUTE_SELF(kB, rB, c);
        c += 4;
        if (c > c_hi) break;
      }
    }
  }

  // ---- exact cross-wave merge: m = max_w m_w, f_w = exp(m_w - m) ----
  m_s[tid] = mrow;
  __syncthreads();
  const float m = fmaxf(fmaxf(m_s[lane], m_s[64 + lane]),
                        fmaxf(m_s[128 + lane], m_s[192 + lane]));
  const float fw = __expf(mrow - m);  // exp(NEGV-NEGV)=1; exp(NEGV-finite)=0
  rsum *= fw;
#pragma unroll
  for (int r = 0; r < 4; ++r) {
    float fr = __shfl(fw, 4 * g + r);
#pragma unroll
    for (int df = 0; df < 4; ++df) oacc[df][r] *= fr;
  }
#pragma unroll
  for (int j = 0; j < 8; ++j) {
    float2* p2 = (float2*)&bk[li * 66 + g * 16 + 2 * j];
    float2 v = *p2; v.x *= fw; v.y *= fw; *p2 = v;
  }

  // fully-masked-row continuation (rare): uniform weight over remaining
  // chunks, split across waves (merged m makes the condition wave-uniform)
  if (__any(m == NEGV)) {
    float pm = (m == NEGV) ? 1.f : 0.f;
    union { s16x8 v; unsigned u[4]; } pa;
    unsigned pku = cvtpk(pm, pm);
#pragma unroll
    for (int q = 0; q < 4; ++q) pa.u[q] = pku;
    for (int cc = c_hi + 1 + w; cc < 8; cc += 4) {
      if (pm > 0.f) {
        rsum += 16.f;
#pragma unroll
        for (int mt = 0; mt < 4; ++mt) {
          int4 rv = *(const int4*)(rp + cc * 64 + mt * 16);
#pragma unroll
          for (int r = 0; r < 4; ++r) atomicAdd(&bk[li * 66 + RELID(rv, r)], 1.f);
        }
      }
#pragma unroll
      for (int kk = 0; kk < 2; ++kk)
#pragma unroll
        for (int df = 0; df < 4; ++df) {
          s16x8 bv = *(const s16x8*)(vp + (size_t)cc * 64 + df * 32768 + kk * 32);
          oacc[df] = mfma_bf16(pa.v, bv, oacc[df]);
        }
    }
  }

  // rel-V per wave on own buckets: oacc += bk @ relv (B = relv^T)
#pragma unroll
  for (int kk = 0; kk < 2; ++kk) {
    float bb[8];
#pragma unroll
    for (int j = 0; j < 4; ++j) {
      float2 v = *(const float2*)&bk[li * 66 + kk * 32 + g * 8 + 2 * j];
      bb[2 * j] = v.x; bb[2 * j + 1] = v.y;
    }
    union { s16x8 v; unsigned u[4]; } pb;
#pragma unroll
    for (int q = 0; q < 4; ++q) pb.u[q] = cvtpk(bb[2 * q], bb[2 * q + 1]);
#pragma unroll
    for (int df = 0; df < 4; ++df) {
      s16x8 rb = *(const s16x8*)(relvt + (df * 16 + li) * 64 + kk * 32 + g * 8);
      oacc[df] = mfma_bf16(pb.v, rb, oacc[df]);
    }
  }

  // in-wave row reduce, then atomic merge into shared accumulators
  rsum += __shfl_xor(rsum, 16);
  rsum += __shfl_xor(rsum, 32);
#pragma unroll
  for (int df = 0; df < 4; ++df)
#pragma unroll
    for (int r = 0; r < 4; ++r)
      atomicAdd(&oaccA[(4 * g + r) * 64 + df * 16 + li], oacc[df][r]);
  if (lane < 16) atomicAdd(&r_sA[lane], rsum);
  __syncthreads();

  {  // cooperative writeout: 16 threads per row, 4 d each
    int row = tid >> 4, d4 = (tid & 15) * 4;
    float inv = 1.f / r_sA[row];
    ushort4 ov;
    ov.x = f2bf(oaccA[row * 64 + d4 + 0] * inv);
    ov.y = f2bf(oaccA[row * 64 + d4 + 1] * inv);
    ov.z = f2bf(oaccA[row * 64 + d4 + 2] * inv);
    ov.w = f2bf(oaccA[row * 64 + d4 + 3] * inv);
    *(ushort4*)(att + (size_t)(growq + row) * 512 + h * 64 + d4) = ov;
  }
}

// ---------------------------------------------------------------------------
// Cross-attention, SPLIT-KV: 4 waves/block, wave w handles chunks w and w+4.
// Grid: (32 qtile16, 8 head, 4 batch) x 256 threads.
// ---------------------------------------------------------------------------
#define LOADK_X(KF, C8) do {                                                   \
    _Pragma("unroll") for (int mt = 0; mt < 4; ++mt) {                         \
      KF[mt * 2 + 0] = *(const s16x8*)(kp + (size_t)(C8) * 65536 + mt * 16384);\
      KF[mt * 2 + 1] = *(const s16x8*)(kp + (size_t)(C8) * 65536 + mt * 16384 + 32); \
    } } while (0)

#define COMPUTE_X(KF, C8) do {                                                 \
    s16x8 vf[8];                                                               \
    _Pragma("unroll") for (int df = 0; df < 4; ++df) {                         \
      vf[df * 2 + 0] = *(const s16x8*)(vp + (size_t)(C8) * 64 + df * 32768);   \
      vf[df * 2 + 1] = *(const s16x8*)(vp + (size_t)(C8) * 64 + df * 32768 + 32); } \
    f32x4 sf[4];                                                               \
    _Pragma("unroll") for (int mt = 0; mt < 4; ++mt) {                         \
      sf[mt] = (f32x4){0.f, 0.f, 0.f, 0.f};                                    \
      sf[mt] = mfma_bf16(KF[mt * 2 + 0], aq0, sf[mt]);                         \
      sf[mt] = mfma_bf16(KF[mt * 2 + 1], aq1, sf[mt]); }                       \
    float p[4][4];                                                             \
    float pmax = NEGV;                                                         \
    _Pragma("unroll") for (int mt = 0; mt < 4; ++mt)                           \
      _Pragma("unroll") for (int r = 0; r < 4; ++r) {                          \
        p[mt][r] = sf[mt][r] * 0.125f;                                         \
        pmax = fmaxf(pmax, p[mt][r]); }                                        \
    pmax = fmaxf(pmax, __shfl_xor(pmax, 16));                                  \
    pmax = fmaxf(pmax, __shfl_xor(pmax, 32));                                  \
    if (__any(pmax > mrow + THRV)) {                                           \
      float mnew = (pmax > mrow + THRV) ? pmax : mrow;                         \
      float f = __expf(mrow - mnew);                                           \
      rsum *= f;                                                               \
      _Pragma("unroll") for (int r = 0; r < 4; ++r) {                          \
        float fr = __shfl(f, 4 * g + r);                                       \
        _Pragma("unroll") for (int df = 0; df < 4; ++df) oacc[df][r] *= fr; }  \
      mrow = mnew; }                                                           \
    unsigned pk[4][2];                                                         \
    _Pragma("unroll") for (int mt = 0; mt < 4; ++mt) {                         \
      _Pragma("unroll") for (int r = 0; r < 4; ++r) {                          \
        float pv = __expf(p[mt][r] - mrow);                                    \
        p[mt][r] = pv;                                                         \
        rsum += pv; }                                                          \
      pk[mt][0] = cvtpk(p[mt][0], p[mt][1]);                                   \
      pk[mt][1] = cvtpk(p[mt][2], p[mt][3]); }                                 \
    _Pragma("unroll") for (int kk = 0; kk < 2; ++kk) {                         \
      union { s16x8 v; unsigned u[4]; } pa;                                    \
      _Pragma("unroll") for (int q = 0; q < 4; ++q) {                          \
        int src = ((2 * (g & 1) + (q >> 1)) << 4) + li;                        \
        unsigned uA = __shfl(pk[2 * kk][q & 1], src);                          \
        unsigned uB = __shfl(pk[2 * kk + 1][q & 1], src);                      \
        pa.u[q] = (g < 2) ? uA : uB; }                                         \
      _Pragma("unroll") for (int df = 0; df < 4; ++df)                         \
        oacc[df] = mfma_bf16(pa.v, vf[df * 2 + kk], oacc[df]); }               \
  } while (0)

__global__ __launch_bounds__(256, 4) void attn_cross(
    const u16* __restrict__ Qb,   // stride 512
    const u16* __restrict__ Kb,   // stride 1024
    const u16* __restrict__ VT,   // stride 2048
    u16* __restrict__ att) {
  __shared__ float m_s[256];
  __shared__ float oaccA[16 * 64];
  __shared__ float r_sA[16];

  const int tid = threadIdx.x;
  const int w = tid >> 6, lane = tid & 63;
  const int g = lane >> 4, li = lane & 15;
  const int qt = blockIdx.x, h = blockIdx.y, b = blockIdx.z;
  const int growq = b * 512 + qt * 16;

  const u16* qp = Qb + (size_t)(growq + li) * 512 + h * 64;
  s16x8 aq0 = *(const s16x8*)(qp + g * 8);
  s16x8 aq1 = *(const s16x8*)(qp + 32 + g * 8);
  const u16* kp = Kb + (size_t)(b * 512 + li) * 1024 + h * 64 + g * 8;
  const u16* vp = VT + (size_t)(h * 64 + li) * 2048 + b * 512 + g * 8;

  ((float4*)oaccA)[tid] = make_float4(0.f, 0.f, 0.f, 0.f);
  if (tid < 16) r_sA[tid] = 0.f;
  __syncthreads();

  float mrow = NEGV, rsum = 0.f;
  f32x4 oacc[4];
#pragma unroll
  for (int d = 0; d < 4; ++d) oacc[d] = (f32x4){0.f, 0.f, 0.f, 0.f};

  {
    s16x8 kA[8];
    LOADK_X(kA, w);
    COMPUTE_X(kA, w);
    LOADK_X(kA, w + 4);
    COMPUTE_X(kA, w + 4);
  }

  // exact cross-wave merge
  m_s[tid] = mrow;
  __syncthreads();
  const float m = fmaxf(fmaxf(m_s[lane], m_s[64 + lane]),
                        fmaxf(m_s[128 + lane], m_s[192 + lane]));
  const float fw = __expf(mrow - m);
  rsum *= fw;
#pragma unroll
  for (int r = 0; r < 4; ++r) {
    float fr = __shfl(fw, 4 * g + r);
#pragma unroll
    for (int df = 0; df < 4; ++df) oacc[df][r] *= fr;
  }
  rsum += __shfl_xor(rsum, 16);
  rsum += __shfl_xor(rsum, 32);
#pragma unroll
  for (int df = 0; df < 4; ++df)
#pragma unroll
    for (int r = 0; r < 4; ++r)
      atomicAdd(&oaccA[(4 * g + r) * 64 + df * 16 + li], oacc[df][r]);
  if (lane < 16) atomicAdd(&r_sA[lane], rsum);
  __syncthreads();

  {
    int row = tid >> 4, d4 = (tid & 15) * 4;
    float inv = 1.f / r_sA[row];
    ushort4 ov;
    ov.x = f2bf(oaccA[row * 64 + d4 + 0] * inv);
    ov.y = f2bf(oaccA[row * 64 + d4 + 1] * inv);
    ov.z = f2bf(oaccA[row * 64 + d4 + 2] * inv);
    ov.w = f2bf(oaccA[row * 64 + d4 + 3] * inv);
    *(ushort4*)(att + (size_t)(growq + row) * 512 + h * 64 + d4) = ov;
  }
}

// ---------------------------------------------------------------------------
// out = LayerNorm(x + dlt) * g + b ; also writes bf16 copy
// ---------------------------------------------------------------------------
__global__ __launch_bounds__(256) void ln_res(
    const float* __restrict__ x, const float* __restrict__ dlt,
    const float* __restrict__ g, const float* __restrict__ bta,
    float* __restrict__ out, u16* __restrict__ obf) {
  __shared__ float red_s[256];
  const int row = blockIdx.x, tid = threadIdx.x;
  const size_t base = (size_t)row * Hc;
  float v0 = x[base + tid] + dlt[base + tid];
  float v1 = x[base + tid + 256] + dlt[base + tid + 256];

  red_s[tid] = v0 + v1;
  __syncthreads();
  for (int s = 128; s > 0; s >>= 1) {
    if (tid < s) red_s[tid] += red_s[tid + s];
    __syncthreads();
  }
  const float mean = red_s[0] * (1.f / Hc);
  __syncthreads();
  const float d0 = v0 - mean, d1 = v1 - mean;
  red_s[tid] = d0 * d0 + d1 * d1;
  __syncthreads();
  for (int s = 128; s > 0; s >>= 1) {
    if (tid < s) red_s[tid] += red_s[tid + s];
    __syncthreads();
  }
  const float rstd = rsqrtf(red_s[0] * (1.f / Hc) + EPSV);
  float o0 = d0 * rstd * g[tid] + bta[tid];
  float o1 = d1 * rstd * g[tid + 256] + bta[tid + 256];
  out[base + tid] = o0;
  out[base + tid + 256] = o1;
  obf[base + tid] = f2bf(o0);
  obf[base + tid + 256] = f2bf(o1);
}

// ---------------------------------------------------------------------------
extern "C" void kernel_launch(void* const* d_in, const int* in_sizes, int n_in,
                              void* d_out, int out_size, void* d_ws, size_t ws_size,
                              hipStream_t stream) {
  const float* q    = (const float*)d_in[0];
  const float* kv   = (const float*)d_in[1];
  const float* relk = (const float*)d_in[2];
  const float* relv = (const float*)d_in[3];
  const float* Wq_s = (const float*)d_in[4];
  const float* bq_s = (const float*)d_in[5];
  const float* Wk_s = (const float*)d_in[6];
  const float* Wv_s = (const float*)d_in[7];
  const float* Wo_s = (const float*)d_in[8];
  const float* bo_s = (const float*)d_in[9];
  const float* ln1g = (const float*)d_in[10];
  const float* ln1b = (const float*)d_in[11];
  const float* Wq_c = (const float*)d_in[12];
  const float* bq_c = (const float*)d_in[13];
  const float* Wk_c = (const float*)d_in[14];
  const float* Wv_c = (const float*)d_in[15];
  const float* Wo_c = (const float*)d_in[16];
  const float* bo_c = (const float*)d_in[17];
  const float* ln2g = (const float*)d_in[18];
  const float* ln2b = (const float*)d_in[19];
  const float* W1   = (const float*)d_in[20];
  const float* b1   = (const float*)d_in[21];
  const float* W2   = (const float*)d_in[22];
  const float* b2   = (const float*)d_in[23];
  const float* ln3g = (const float*)d_in[24];
  const float* ln3b = (const float*)d_in[25];
  const int*   rel  = (const int*)d_in[26];

  char* wsb = (char*)d_ws;
  const size_t NT = (size_t)Bc * Tc;  // 2048 token rows
  float* o     = (float*)wsb;  wsb += NT * Hc * 4;       // 4MB
  float* bDlt  = (float*)wsb;  wsb += NT * Hc * 4;       // 4MB
  float* Qr    = (float*)wsb;  wsb += NT * 8 * 64 * 4;   // 4MB
  u16* obf     = (u16*)wsb;    wsb += NT * Hc * 2;       // 2MB
  u16* kvbf    = (u16*)wsb;    wsb += NT * Hc * 2;       // 2MB
  u16* bQK     = (u16*)wsb;    wsb += NT * 1024 * 2;     // 4MB
  u16* bVt     = (u16*)wsb;    wsb += (size_t)512 * 2048 * 2;   // 2MB
  u16* bQc     = (u16*)wsb;    wsb += NT * Hc * 2;       // 2MB
  u16* bKc     = (u16*)wsb;    wsb += NT * 1024 * 2;     // 4MB
  u16* bVtc    = (u16*)wsb;    wsb += (size_t)1024 * 2048 * 2;  // 4MB
  u16* bAtt    = (u16*)wsb;    wsb += NT * Hc * 2;       // 2MB
  u16* bH      = (u16*)wsb;    wsb += NT * FFc * 2;      // 8MB
  u16* relvt   = (u16*)wsb;    wsb += 64 * 64 * 2;       // 8KB
  u16* wbuf    = (u16*)wsb;    wsb += (size_t)8388608 * 2;  // 16MB

  WPtrs wp;
  wp.p[0] = Wq_s; wp.p[1] = Wk_s; wp.p[2] = Wv_s; wp.p[3] = Wo_s;
  wp.p[4] = Wq_c; wp.p[5] = Wk_c; wp.p[6] = Wv_c; wp.p[7] = Wo_c;
  wp.p[8] = W1;   wp.p[9] = W2;

  dim3 blk(256);
  wcvt<<<dim3(2048), blk, 0, stream>>>(wp, wbuf);
  acvt<<<dim3(1025), blk, 0, stream>>>(q, kv, relv, obf, kvbf, relvt);
  hipMemcpyAsync(o, q, NT * Hc * 4, hipMemcpyDeviceToDevice, stream);

  // cross K (both layers) and cross V^T (both layers)
  gemm_mfma<64, 128, false, 1><<<dim3(8, 32), blk, 0, stream>>>(
      kvbf, wbuf + 2097152, nullptr, 0, bKc, 1024, 512);
  gemm_mfma<64, 128, false, 1><<<dim3(16, 16), blk, 0, stream>>>(
      wbuf + 2621440, kvbf, nullptr, 0, bVtc, 2048, 512);

  const dim3 gLN(NT);
  const dim3 gATT(32, 8, 4);
  for (int i = 0; i < NLc; ++i) {
    // --- relation-aware masked self-attention ---
    gemm_mfma<64, 128, false, 1><<<dim3(8, 32), blk, 0, stream>>>(
        obf, wbuf + (size_t)i * 524288, bq_s + i * Hc, Hc, bQK, 1024, 512);
    gemm_mfma<64, 64, false, 1><<<dim3(32, 8), blk, 0, stream>>>(
        wbuf + 3670016 + (size_t)i * 262144, obf, nullptr, 0, bVt, 2048, 512);
    qr_kernel<<<dim3(4096), blk, 0, stream>>>(bQK, relk, Qr);
    attn_self<<<gATT, blk, 0, stream>>>(
        bQK, bQK + 512, bVt, Qr, rel, relvt, bAtt);
    gemm_mfma<64, 64, false, 0><<<dim3(8, 32), blk, 0, stream>>>(
        bAtt, wbuf + 1048576 + (size_t)i * 262144, bo_s + i * Hc, Hc, bDlt, Hc, 512);
    ln_res<<<gLN, blk, 0, stream>>>(o, bDlt, ln1g + i * Hc, ln1b + i * Hc, o, obf);

    // --- cross-attention ---
    gemm_mfma<64, 64, false, 1><<<dim3(8, 32), blk, 0, stream>>>(
        obf, wbuf + 1572864 + (size_t)i * 262144, bq_c + i * Hc, Hc, bQc, Hc, 512);
    attn_cross<<<gATT, blk, 0, stream>>>(
        bQc, bKc + i * 512, bVtc + (size_t)i * 512 * 2048, bAtt);
    gemm_mfma<64, 64, false, 0><<<dim3(8, 32), blk, 0, stream>>>(
        bAtt, wbuf + 3145728 + (size_t)i * 262144, bo_c + i * Hc, Hc, bDlt, Hc, 512);
    ln_res<<<gLN, blk, 0, stream>>>(o, bDlt, ln2g + i * Hc, ln2b + i * Hc, o, obf);

    // --- feedforward ---
    gemm_mfma<128, 128, true, 1><<<dim3(16, 16), blk, 0, stream>>>(
        obf, wbuf + 4194304 + (size_t)i * 1048576, b1 + i * FFc, FFc, bH, FFc, 512);
    gemm_mfma<64, 64, false, 0><<<dim3(8, 32), blk, 0, stream>>>(
        bH, wbuf + 6291456 + (size_t)i * 1048576, b2 + i * Hc, Hc, bDlt, Hc, 2048);
    float* lnout = (i == NLc - 1) ? (float*)d_out : o;
    ln_res<<<gLN, blk, 0, stream>>>(o, bDlt, ln3g + i * Hc, ln3b + i * Hc, lnout, obf);
  }
}

// Round 7
// 495.789 us; speedup vs baseline: 1.1014x; 1.1014x over previous
//
#include <hip/hip_runtime.h>

static constexpr int Hc  = 512;
static constexpr int NHc = 8;
static constexpr int DHc = 64;
static constexpr int NLc = 2;
static constexpr int Rc  = 64;
static constexpr int FFc = 2048;
static constexpr int Bc  = 4;
static constexpr int Tc  = 512;
#define NEGV (-1e10f)
#define EPSV 1e-5f
#define THRV 6.0f

typedef unsigned short u16;
typedef __attribute__((ext_vector_type(8))) short s16x8;
typedef __attribute__((ext_vector_type(4))) float f32x4;

__device__ __forceinline__ f32x4 mfma_bf16(s16x8 a, s16x8 b, f32x4 c) {
  return __builtin_amdgcn_mfma_f32_16x16x32_bf16(a, b, c, 0, 0, 0);
}
__device__ __forceinline__ u16 f2bf(float f) {
  union { float f; unsigned u; } x; x.f = f;
  unsigned r = (x.u + 0x7FFFu + ((x.u >> 16) & 1u)) >> 16;
  return (u16)r;
}
__device__ __forceinline__ float bf2f(u16 h) {
  union { unsigned u; float f; } x; x.u = ((unsigned)h) << 16;
  return x.f;
}
__device__ __forceinline__ unsigned cvtpk(float a, float b) {
  unsigned r;
  asm("v_cvt_pk_bf16_f32 %0, %1, %2" : "=v"(r) : "v"(a), "v"(b));
  return r;
}

// ---------------------------------------------------------------------------
// bf16 MFMA GEMM: C[M,N] = A[M,K] @ Wt[N,K]^T (+bias for col<biasN) (+relu)
// 256 threads, 4 waves (2x2). BK=32. LDS 16B-chunk XOR swizzle.
// ---------------------------------------------------------------------------
template <int BM, int BN, bool RELU, int OUT>  // OUT: 0=f32, 1=bf16
__global__ __launch_bounds__(256) void gemm_mfma(
    const u16* __restrict__ A, const u16* __restrict__ Wt,
    const float* __restrict__ bias, int biasN,
    void* __restrict__ Cout, int N, int K) {
  __shared__ u16 As[BM * 32];
  __shared__ u16 Bs[BN * 32];
  const int tid = threadIdx.x;
  const int w = tid >> 6, lane = tid & 63, g = lane >> 4, li = lane & 15;
  const int bn = blockIdx.x * BN, bm = blockIdx.y * BM;
  const int r0 = (w & 1) * (BM / 2), c0 = (w >> 1) * (BN / 2);
  constexpr int MR = BM / 32, NR = BN / 32;
  f32x4 acc[MR][NR];
#pragma unroll
  for (int i = 0; i < MR; ++i)
#pragma unroll
    for (int j = 0; j < NR; ++j) acc[i][j] = (f32x4){0.f, 0.f, 0.f, 0.f};

  for (int k0 = 0; k0 < K; k0 += 32) {
    __syncthreads();
#pragma unroll
    for (int it = 0; it < BM / 64; ++it) {
      int s = it * 256 + tid;
      int row = s >> 2, ch = s & 3;
      s16x8 v = *(const s16x8*)(A + (size_t)(bm + row) * K + k0 + ch * 8);
      *(s16x8*)&As[row * 32 + ((ch ^ (row & 3)) * 8)] = v;
    }
#pragma unroll
    for (int it = 0; it < BN / 64; ++it) {
      int s = it * 256 + tid;
      int row = s >> 2, ch = s & 3;
      s16x8 v = *(const s16x8*)(Wt + (size_t)(bn + row) * K + k0 + ch * 8);
      *(s16x8*)&Bs[row * 32 + ((ch ^ (row & 3)) * 8)] = v;
    }
    __syncthreads();
    s16x8 ar[MR], br[NR];
#pragma unroll
    for (int i = 0; i < MR; ++i) {
      int row = r0 + i * 16 + li;
      ar[i] = *(const s16x8*)&As[row * 32 + ((g ^ (row & 3)) * 8)];
    }
#pragma unroll
    for (int j = 0; j < NR; ++j) {
      int row = c0 + j * 16 + li;
      br[j] = *(const s16x8*)&Bs[row * 32 + ((g ^ (row & 3)) * 8)];
    }
#pragma unroll
    for (int i = 0; i < MR; ++i)
#pragma unroll
      for (int j = 0; j < NR; ++j) acc[i][j] = mfma_bf16(ar[i], br[j], acc[i][j]);
  }

#pragma unroll
  for (int j = 0; j < NR; ++j) {
    int col = bn + c0 + j * 16 + li;
    float bv = (bias && col < biasN) ? bias[col] : 0.f;
#pragma unroll
    for (int i = 0; i < MR; ++i) {
#pragma unroll
      for (int r = 0; r < 4; ++r) {
        int rowg = bm + r0 + i * 16 + 4 * g + r;
        float v = acc[i][j][r] + bv;
        if (RELU) v = fmaxf(v, 0.f);
        if (OUT == 0) ((float*)Cout)[(size_t)rowg * N + col] = v;
        else          ((u16*)Cout)[(size_t)rowg * N + col] = f2bf(v);
      }
    }
  }
}

// ---------------------------------------------------------------------------
// Weight transpose+convert: f32 [Ks][Ns] -> bf16 [Ns][Ks] at dstOff
// ---------------------------------------------------------------------------
struct WPtrs { const float* p[10]; };

__global__ __launch_bounds__(256) void wcvt(WPtrs wp, u16* __restrict__ dst) {
  constexpr int NE = 20;
  constexpr int srcIdx[NE] = {0,1,0,1,3,3,4,4,5,5,6,6,7,7,2,2,8,8,9,9};
  constexpr int srcOff[NE] = {0,0,262144,262144,0,262144,0,262144,0,262144,
                              0,262144,0,262144,0,262144,0,1048576,0,1048576};
  constexpr int dstOff[NE] = {0,262144,524288,786432,1048576,1310720,
                              1572864,1835008,2097152,2359296,2621440,2883584,
                              3145728,3407872,3670016,3932160,
                              4194304,5242880,6291456,7340032};
  constexpr int KsA[NE] = {512,512,512,512,512,512,512,512,512,512,
                           512,512,512,512,512,512,512,512,2048,2048};
  constexpr int NsA[NE] = {512,512,512,512,512,512,512,512,512,512,
                           512,512,512,512,512,512,2048,2048,512,512};
  constexpr int tileStart[NE] = {0,64,128,192,256,320,384,448,512,576,
                                 640,704,768,832,896,960,1024,1280,1536,1792};
  __shared__ float ts[64 * 65];
  const int tid = threadIdx.x;
  const int bid = blockIdx.x;
  int e = 0;
#pragma unroll
  for (int i = 1; i < NE; ++i) if (bid >= tileStart[i]) e = i;
  const int t = bid - tileStart[e];
  const int Ks_ = KsA[e], Ns_ = NsA[e];
  const int tn = t % (Ns_ >> 6), tk = t / (Ns_ >> 6);
  const float* src = wp.p[srcIdx[e]] + srcOff[e];

  {
    int r = tid >> 2, cb = (tid & 3) * 16;
    const float* sp = src + (size_t)(tk * 64 + r) * Ns_ + tn * 64 + cb;
#pragma unroll
    for (int j = 0; j < 4; ++j) {
      float4 v = ((const float4*)sp)[j];
      float* d = &ts[r * 65 + cb + j * 4];
      d[0] = v.x; d[1] = v.y; d[2] = v.z; d[3] = v.w;
    }
  }
  __syncthreads();
  {
    int n = tid >> 2, kb = (tid & 3) * 16;
    u16* dp = dst + dstOff[e] + (size_t)(tn * 64 + n) * Ks_ + tk * 64 + kb;
    s16x8 o0, o1;
#pragma unroll
    for (int j = 0; j < 8; ++j) o0[j] = (short)f2bf(ts[(kb + j) * 65 + n]);
#pragma unroll
    for (int j = 0; j < 8; ++j) o1[j] = (short)f2bf(ts[(kb + 8 + j) * 65 + n]);
    *(s16x8*)dp = o0;
    *(s16x8*)(dp + 8) = o1;
  }
}

// ---------------------------------------------------------------------------
// activations f32->bf16 (blocks 0..1023); block 1024: relv -> relv^T bf16
// ---------------------------------------------------------------------------
__global__ __launch_bounds__(256) void acvt(
    const float* __restrict__ q, const float* __restrict__ kv,
    const float* __restrict__ relv,
    u16* __restrict__ obf, u16* __restrict__ kvbf, u16* __restrict__ relvt) {
  int bid = blockIdx.x, tid = threadIdx.x;
  if (bid == 1024) {
    int d = tid >> 2, rb = (tid & 3) * 16;
    s16x8 o0, o1;
#pragma unroll
    for (int j = 0; j < 8; ++j) o0[j] = (short)f2bf(relv[(rb + j) * 64 + d]);
#pragma unroll
    for (int j = 0; j < 8; ++j) o1[j] = (short)f2bf(relv[(rb + 8 + j) * 64 + d]);
    *(s16x8*)(relvt + d * 64 + rb) = o0;
    *(s16x8*)(relvt + d * 64 + rb + 8) = o1;
    return;
  }
  int i = bid * 256 + tid;
  const float* src; u16* dst; size_t off;
  if (i < 131072) { src = q; dst = obf; off = (size_t)i * 8; }
  else { src = kv; dst = kvbf; off = (size_t)(i - 131072) * 8; }
  float4 a = *(const float4*)(src + off);
  float4 b = *(const float4*)(src + off + 4);
  s16x8 o;
  o[0] = (short)f2bf(a.x); o[1] = (short)f2bf(a.y);
  o[2] = (short)f2bf(a.z); o[3] = (short)f2bf(a.w);
  o[4] = (short)f2bf(b.x); o[5] = (short)f2bf(b.y);
  o[6] = (short)f2bf(b.z); o[7] = (short)f2bf(b.w);
  *(s16x8*)(dst + off) = o;
}

// ---------------------------------------------------------------------------
// Qr[(row*8+h), r] = sum_d Q[row, h*64+d] * relk[r, d]  (Q = bQK, stride 1024)
// ---------------------------------------------------------------------------
__global__ __launch_bounds__(256) void qr_kernel(
    const u16* __restrict__ Q, const float* __restrict__ relk,
    float* __restrict__ Qr) {
  __shared__ float rk[64 * 65];
  __shared__ float qs[4][64];
  const int tid = threadIdx.x;
  {
    int r = tid >> 2, cb = (tid & 3) * 16;
    const float* sp = relk + r * 64 + cb;
#pragma unroll
    for (int j = 0; j < 4; ++j) {
      float4 v = ((const float4*)sp)[j];
      float* d = &rk[r * 65 + cb + j * 4];
      d[0] = v.x; d[1] = v.y; d[2] = v.z; d[3] = v.w;
    }
  }
  const int sub = tid >> 6, r = tid & 63;
  const int unit = blockIdx.x * 4 + sub;  // unit = row*8 + h
  qs[sub][r] = bf2f(Q[(size_t)(unit >> 3) * 1024 + (unit & 7) * 64 + r]);
  __syncthreads();
  float acc = 0.f;
#pragma unroll
  for (int d = 0; d < 64; ++d) acc += qs[sub][d] * rk[r * 65 + d];
  Qr[(size_t)unit * 64 + r] = acc;
}

// ---------------------------------------------------------------------------
// Relation-aware masked self-attention, SPLIT-KV: 4 waves/block, wave w
// handles chunks c = w, w+4 (<= c_hi) with private (mrow,rsum,oacc,buck);
// exact merge via m = max_w, f_w = exp(m_w - m); rel-V folded per wave.
// No launch_bounds min-waves: VGPR cap at 256 avoids the round-6 spill.
// Grid: (32 qtile16, 8 head, 4 batch) x 256 threads.
// ---------------------------------------------------------------------------
#define RELID(RV, r) ((r) == 0 ? (RV).x : (r) == 1 ? (RV).y : (r) == 2 ? (RV).z : (RV).w)

#define LOADKREL(KF, RF, C8) do {                                              \
    _Pragma("unroll") for (int mt = 0; mt < 4; ++mt) {                         \
      KF[mt * 2 + 0] = *(const s16x8*)(kp + (size_t)(C8) * 65536 + mt * 16384);\
      KF[mt * 2 + 1] = *(const s16x8*)(kp + (size_t)(C8) * 65536 + mt * 16384 + 32); \
      RF[mt] = *(const int4*)(rp + (C8) * 64 + mt * 16);                       \
    } } while (0)

#define COMPUTE_SELF(KF, RF, C8) do {                                          \
    s16x8 vf[8];                                                               \
    _Pragma("unroll") for (int df = 0; df < 4; ++df) {                         \
      vf[df * 2 + 0] = *(const s16x8*)(vp + (size_t)(C8) * 64 + df * 32768);   \
      vf[df * 2 + 1] = *(const s16x8*)(vp + (size_t)(C8) * 64 + df * 32768 + 32); } \
    f32x4 sf[4];                                                               \
    _Pragma("unroll") for (int mt = 0; mt < 4; ++mt) {                         \
      sf[mt] = (f32x4){0.f, 0.f, 0.f, 0.f};                                    \
      sf[mt] = mfma_bf16(KF[mt * 2 + 0], aq0, sf[mt]);                         \
      sf[mt] = mfma_bf16(KF[mt * 2 + 1], aq1, sf[mt]); }                       \
    float p[4][4];                                                             \
    float pmax = NEGV;                                                         \
    _Pragma("unroll") for (int mt = 0; mt < 4; ++mt) {                         \
      _Pragma("unroll") for (int r = 0; r < 4; ++r) {                          \
        int rel = RELID(RF[mt], r);                                            \
        bool valid = (rel != 0) && ((C8) * 64 + mt * 16 + 4 * g + r <= lrow);  \
        p[mt][r] = valid ? (sf[mt][r] + qrs[li * 66 + rel]) * 0.125f : NEGV;   \
        pmax = fmaxf(pmax, p[mt][r]); } }                                      \
    pmax = fmaxf(pmax, __shfl_xor(pmax, 16));                                  \
    pmax = fmaxf(pmax, __shfl_xor(pmax, 32));                                  \
    if (__any(pmax > mrow + THRV)) {                                           \
      float mnew = (pmax > mrow + THRV) ? pmax : mrow;                         \
      float f = __expf(mrow - mnew);                                           \
      rsum *= f;                                                               \
      _Pragma("unroll") for (int j = 0; j < 8; ++j) {                          \
        float2* p2 = (float2*)&bk[li * 66 + g * 16 + 2 * j];                   \
        float2 v = *p2; v.x *= f; v.y *= f; *p2 = v; }                         \
      _Pragma("unroll") for (int r = 0; r < 4; ++r) {                          \
        float fr = __shfl(f, 4 * g + r);                                       \
        _Pragma("unroll") for (int df = 0; df < 4; ++df) oacc[df][r] *= fr; }  \
      mrow = mnew; }                                                           \
    unsigned pk[4][2];                                                         \
    _Pragma("unroll") for (int mt = 0; mt < 4; ++mt) {                         \
      _Pragma("unroll") for (int r = 0; r < 4; ++r) {                          \
        float pv = __expf(p[mt][r] - mrow);                                    \
        p[mt][r] = pv;                                                         \
        rsum += pv;                                                            \
        if (pv > 0.f) atomicAdd(&bk[li * 66 + RELID(RF[mt], r)], pv); }        \
      pk[mt][0] = cvtpk(p[mt][0], p[mt][1]);                                   \
      pk[mt][1] = cvtpk(p[mt][2], p[mt][3]); }                                 \
    _Pragma("unroll") for (int kk = 0; kk < 2; ++kk) {                         \
      union { s16x8 v; unsigned u[4]; } pa;                                    \
      _Pragma("unroll") for (int q = 0; q < 4; ++q) {                          \
        int src = ((2 * (g & 1) + (q >> 1)) << 4) + li;                        \
        unsigned uA = __shfl(pk[2 * kk][q & 1], src);                          \
        unsigned uB = __shfl(pk[2 * kk + 1][q & 1], src);                      \
        pa.u[q] = (g < 2) ? uA : uB; }                                         \
      _Pragma("unroll") for (int df = 0; df < 4; ++df)                         \
        oacc[df] = mfma_bf16(pa.v, vf[df * 2 + kk], oacc[df]); }               \
  } while (0)

__global__ __launch_bounds__(256) void attn_self(
    const u16* __restrict__ Qb, const u16* __restrict__ Kb,  // stride 1024
    const u16* __restrict__ VT,                              // [512][2048]
    const float* __restrict__ Qr, const int* __restrict__ rel_ids,
    const u16* __restrict__ relvt, u16* __restrict__ att) {
  __shared__ float qrs[16 * 66];
  __shared__ float buck[4 * 16 * 66];
  __shared__ float m_s[256];
  __shared__ float oaccA[16 * 64];
  __shared__ float r_sA[16];

  const int tid = threadIdx.x;
  const int w = tid >> 6, lane = tid & 63;
  const int g = lane >> 4, li = lane & 15;
  const int qt = blockIdx.x, h = blockIdx.y, b = blockIdx.z;
  const int lrow = qt * 16 + li;            // q-row within batch (this lane)
  const int growq = b * 512 + qt * 16;
  const int c_hi = qt >> 2;
  float* bk = buck + w * (16 * 66);         // this wave's private buckets

  const u16* qp = Qb + (size_t)(growq + li) * 1024 + h * 64;
  s16x8 aq0 = *(const s16x8*)(qp + g * 8);
  s16x8 aq1 = *(const s16x8*)(qp + 32 + g * 8);
  const u16* kp = Kb + (size_t)(b * 512 + li) * 1024 + h * 64 + g * 8;
  const u16* vp = VT + (size_t)(h * 64 + li) * 2048 + b * 512 + g * 8;
  const int* rp = rel_ids + (size_t)(growq + li) * 512 + 4 * g;

  {  // stage Qr cooperatively; zero shared accumulators + own buckets
    int row = tid >> 4, c4 = (tid & 15) * 4;
    float4 v = *(const float4*)(Qr + ((size_t)(growq + row) * 8 + h) * 64 + c4);
    *(float4*)&qrs[row * 66 + c4] = v;
    ((float4*)oaccA)[tid] = make_float4(0.f, 0.f, 0.f, 0.f);
    if (tid < 16) r_sA[tid] = 0.f;
#pragma unroll
    for (int j = 0; j < 8; ++j)
      *(float2*)&bk[li * 66 + g * 16 + 2 * j] = make_float2(0.f, 0.f);
  }
  __syncthreads();

  float mrow = NEGV, rsum = 0.f;
  f32x4 oacc[4];
#pragma unroll
  for (int d = 0; d < 4; ++d) oacc[d] = (f32x4){0.f, 0.f, 0.f, 0.f};

  // main loop: chunks w, w+4 (<= c_hi); sequential load->compute (TLP hides)
  for (int c = w; c <= c_hi; c += 4) {
    s16x8 kA[8];
    int4 rA[4];
    LOADKREL(kA, rA, c);
    COMPUTE_SELF(kA, rA, c);
  }

  // ---- exact cross-wave merge: m = max_w m_w, f_w = exp(m_w - m) ----
  m_s[tid] = mrow;
  __syncthreads();
  const float m = fmaxf(fmaxf(m_s[lane], m_s[64 + lane]),
                        fmaxf(m_s[128 + lane], m_s[192 + lane]));
  const float fw = __expf(mrow - m);  // exp(NEGV-NEGV)=1; exp(NEGV-finite)=0
  rsum *= fw;
#pragma unroll
  for (int r = 0; r < 4; ++r) {
    float fr = __shfl(fw, 4 * g + r);
#pragma unroll
    for (int df = 0; df < 4; ++df) oacc[df][r] *= fr;
  }
#pragma unroll
  for (int j = 0; j < 8; ++j) {
    float2* p2 = (float2*)&bk[li * 66 + g * 16 + 2 * j];
    float2 v = *p2; v.x *= fw; v.y *= fw; *p2 = v;
  }

  // fully-masked-row continuation (rare): uniform weight over remaining
  // chunks, split across waves (merged m makes the condition wave-uniform)
  if (__any(m == NEGV)) {
    float pm = (m == NEGV) ? 1.f : 0.f;
    union { s16x8 v; unsigned u[4]; } pa;
    unsigned pku = cvtpk(pm, pm);
#pragma unroll
    for (int q = 0; q < 4; ++q) pa.u[q] = pku;
    for (int cc = c_hi + 1 + w; cc < 8; cc += 4) {
      if (pm > 0.f) {
        rsum += 16.f;
#pragma unroll
        for (int mt = 0; mt < 4; ++mt) {
          int4 rv = *(const int4*)(rp + cc * 64 + mt * 16);
#pragma unroll
          for (int r = 0; r < 4; ++r) atomicAdd(&bk[li * 66 + RELID(rv, r)], 1.f);
        }
      }
#pragma unroll
      for (int kk = 0; kk < 2; ++kk)
#pragma unroll
        for (int df = 0; df < 4; ++df) {
          s16x8 bv = *(const s16x8*)(vp + (size_t)cc * 64 + df * 32768 + kk * 32);
          oacc[df] = mfma_bf16(pa.v, bv, oacc[df]);
        }
    }
  }

  // rel-V per wave on own buckets: oacc += bk @ relv (B = relv^T)
#pragma unroll
  for (int kk = 0; kk < 2; ++kk) {
    float bb[8];
#pragma unroll
    for (int j = 0; j < 4; ++j) {
      float2 v = *(const float2*)&bk[li * 66 + kk * 32 + g * 8 + 2 * j];
      bb[2 * j] = v.x; bb[2 * j + 1] = v.y;
    }
    union { s16x8 v; unsigned u[4]; } pb;
#pragma unroll
    for (int q = 0; q < 4; ++q) pb.u[q] = cvtpk(bb[2 * q], bb[2 * q + 1]);
#pragma unroll
    for (int df = 0; df < 4; ++df) {
      s16x8 rb = *(const s16x8*)(relvt + (df * 16 + li) * 64 + kk * 32 + g * 8);
      oacc[df] = mfma_bf16(pb.v, rb, oacc[df]);
    }
  }

  // in-wave row reduce, then atomic merge into shared accumulators
  rsum += __shfl_xor(rsum, 16);
  rsum += __shfl_xor(rsum, 32);
#pragma unroll
  for (int df = 0; df < 4; ++df)
#pragma unroll
    for (int r = 0; r < 4; ++r)
      atomicAdd(&oaccA[(4 * g + r) * 64 + df * 16 + li], oacc[df][r]);
  if (lane < 16) atomicAdd(&r_sA[lane], rsum);
  __syncthreads();

  {  // cooperative writeout: 16 threads per row, 4 d each
    int row = tid >> 4, d4 = (tid & 15) * 4;
    float inv = 1.f / r_sA[row];
    ushort4 ov;
    ov.x = f2bf(oaccA[row * 64 + d4 + 0] * inv);
    ov.y = f2bf(oaccA[row * 64 + d4 + 1] * inv);
    ov.z = f2bf(oaccA[row * 64 + d4 + 2] * inv);
    ov.w = f2bf(oaccA[row * 64 + d4 + 3] * inv);
    *(ushort4*)(att + (size_t)(growq + row) * 512 + h * 64 + d4) = ov;
  }
}

// ---------------------------------------------------------------------------
// Cross-attention, SPLIT-KV: 4 waves/block, wave w handles chunks w and w+4.
// Grid: (32 qtile16, 8 head, 4 batch) x 256 threads.
// ---------------------------------------------------------------------------
#define LOADK_X(KF, C8) do {                                                   \
    _Pragma("unroll") for (int mt = 0; mt < 4; ++mt) {                         \
      KF[mt * 2 + 0] = *(const s16x8*)(kp + (size_t)(C8) * 65536 + mt * 16384);\
      KF[mt * 2 + 1] = *(const s16x8*)(kp + (size_t)(C8) * 65536 + mt * 16384 + 32); \
    } } while (0)

#define COMPUTE_X(KF, C8) do {                                                 \
    s16x8 vf[8];                                                               \
    _Pragma("unroll") for (int df = 0; df < 4; ++df) {                         \
      vf[df * 2 + 0] = *(const s16x8*)(vp + (size_t)(C8) * 64 + df * 32768);   \
      vf[df * 2 + 1] = *(const s16x8*)(vp + (size_t)(C8) * 64 + df * 32768 + 32); } \
    f32x4 sf[4];                                                               \
    _Pragma("unroll") for (int mt = 0; mt < 4; ++mt) {                         \
      sf[mt] = (f32x4){0.f, 0.f, 0.f, 0.f};                                    \
      sf[mt] = mfma_bf16(KF[mt * 2 + 0], aq0, sf[mt]);                         \
      sf[mt] = mfma_bf16(KF[mt * 2 + 1], aq1, sf[mt]); }                       \
    float p[4][4];                                                             \
    float pmax = NEGV;                                                         \
    _Pragma("unroll") for (int mt = 0; mt < 4; ++mt)                           \
      _Pragma("unroll") for (int r = 0; r < 4; ++r) {                          \
        p[mt][r] = sf[mt][r] * 0.125f;                                         \
        pmax = fmaxf(pmax, p[mt][r]); }                                        \
    pmax = fmaxf(pmax, __shfl_xor(pmax, 16));                                  \
    pmax = fmaxf(pmax, __shfl_xor(pmax, 32));                                  \
    if (__any(pmax > mrow + THRV)) {                                           \
      float mnew = (pmax > mrow + THRV) ? pmax : mrow;                         \
      float f = __expf(mrow - mnew);                                           \
      rsum *= f;                                                               \
      _Pragma("unroll") for (int r = 0; r < 4; ++r) {                          \
        float fr = __shfl(f, 4 * g + r);                                       \
        _Pragma("unroll") for (int df = 0; df < 4; ++df) oacc[df][r] *= fr; }  \
      mrow = mnew; }                                                           \
    unsigned pk[4][2];                                                         \
    _Pragma("unroll") for (int mt = 0; mt < 4; ++mt) {                         \
      _Pragma("unroll") for (int r = 0; r < 4; ++r) {                          \
        float pv = __expf(p[mt][r] - mrow);                                    \
        p[mt][r] = pv;                                                         \
        rsum += pv; }                                                          \
      pk[mt][0] = cvtpk(p[mt][0], p[mt][1]);                                   \
      pk[mt][1] = cvtpk(p[mt][2], p[mt][3]); }                                 \
    _Pragma("unroll") for (int kk = 0; kk < 2; ++kk) {                         \
      union { s16x8 v; unsigned u[4]; } pa;                                    \
      _Pragma("unroll") for (int q = 0; q < 4; ++q) {                          \
        int src = ((2 * (g & 1) + (q >> 1)) << 4) + li;                        \
        unsigned uA = __shfl(pk[2 * kk][q & 1], src);                          \
        unsigned uB = __shfl(pk[2 * kk + 1][q & 1], src);                      \
        pa.u[q] = (g < 2) ? uA : uB; }                                         \
      _Pragma("unroll") for (int df = 0; df < 4; ++df)                         \
        oacc[df] = mfma_bf16(pa.v, vf[df * 2 + kk], oacc[df]); }               \
  } while (0)

__global__ __launch_bounds__(256) void attn_cross(
    const u16* __restrict__ Qb,   // stride 512
    const u16* __restrict__ Kb,   // stride 1024
    const u16* __restrict__ VT,   // stride 2048
    u16* __restrict__ att) {
  __shared__ float m_s[256];
  __shared__ float oaccA[16 * 64];
  __shared__ float r_sA[16];

  const int tid = threadIdx.x;
  const int w = tid >> 6, lane = tid & 63;
  const int g = lane >> 4, li = lane & 15;
  const int qt = blockIdx.x, h = blockIdx.y, b = blockIdx.z;
  const int growq = b * 512 + qt * 16;

  const u16* qp = Qb + (size_t)(growq + li) * 512 + h * 64;
  s16x8 aq0 = *(const s16x8*)(qp + g * 8);
  s16x8 aq1 = *(const s16x8*)(qp + 32 + g * 8);
  const u16* kp = Kb + (size_t)(b * 512 + li) * 1024 + h * 64 + g * 8;
  const u16* vp = VT + (size_t)(h * 64 + li) * 2048 + b * 512 + g * 8;

  ((float4*)oaccA)[tid] = make_float4(0.f, 0.f, 0.f, 0.f);
  if (tid < 16) r_sA[tid] = 0.f;
  __syncthreads();

  float mrow = NEGV, rsum = 0.f;
  f32x4 oacc[4];
#pragma unroll
  for (int d = 0; d < 4; ++d) oacc[d] = (f32x4){0.f, 0.f, 0.f, 0.f};

  {
    s16x8 kA[8];
    LOADK_X(kA, w);
    COMPUTE_X(kA, w);
    LOADK_X(kA, w + 4);
    COMPUTE_X(kA, w + 4);
  }

  // exact cross-wave merge
  m_s[tid] = mrow;
  __syncthreads();
  const float m = fmaxf(fmaxf(m_s[lane], m_s[64 + lane]),
                        fmaxf(m_s[128 + lane], m_s[192 + lane]));
  const float fw = __expf(mrow - m);
  rsum *= fw;
#pragma unroll
  for (int r = 0; r < 4; ++r) {
    float fr = __shfl(fw, 4 * g + r);
#pragma unroll
    for (int df = 0; df < 4; ++df) oacc[df][r] *= fr;
  }
  rsum += __shfl_xor(rsum, 16);
  rsum += __shfl_xor(rsum, 32);
#pragma unroll
  for (int df = 0; df < 4; ++df)
#pragma unroll
    for (int r = 0; r < 4; ++r)
      atomicAdd(&oaccA[(4 * g + r) * 64 + df * 16 + li], oacc[df][r]);
  if (lane < 16) atomicAdd(&r_sA[lane], rsum);
  __syncthreads();

  {
    int row = tid >> 4, d4 = (tid & 15) * 4;
    float inv = 1.f / r_sA[row];
    ushort4 ov;
    ov.x = f2bf(oaccA[row * 64 + d4 + 0] * inv);
    ov.y = f2bf(oaccA[row * 64 + d4 + 1] * inv);
    ov.z = f2bf(oaccA[row * 64 + d4 + 2] * inv);
    ov.w = f2bf(oaccA[row * 64 + d4 + 3] * inv);
    *(ushort4*)(att + (size_t)(growq + row) * 512 + h * 64 + d4) = ov;
  }
}

// ---------------------------------------------------------------------------
// out = LayerNorm(x + dlt) * g + b ; also writes bf16 copy
// ---------------------------------------------------------------------------
__global__ __launch_bounds__(256) void ln_res(
    const float* __restrict__ x, const float* __restrict__ dlt,
    const float* __restrict__ g, const float* __restrict__ bta,
    float* __restrict__ out, u16* __restrict__ obf) {
  __shared__ float red_s[256];
  const int row = blockIdx.x, tid = threadIdx.x;
  const size_t base = (size_t)row * Hc;
  float v0 = x[base + tid] + dlt[base + tid];
  float v1 = x[base + tid + 256] + dlt[base + tid + 256];

  red_s[tid] = v0 + v1;
  __syncthreads();
  for (int s = 128; s > 0; s >>= 1) {
    if (tid < s) red_s[tid] += red_s[tid + s];
    __syncthreads();
  }
  const float mean = red_s[0] * (1.f / Hc);
  __syncthreads();
  const float d0 = v0 - mean, d1 = v1 - mean;
  red_s[tid] = d0 * d0 + d1 * d1;
  __syncthreads();
  for (int s = 128; s > 0; s >>= 1) {
    if (tid < s) red_s[tid] += red_s[tid + s];
    __syncthreads();
  }
  const float rstd = rsqrtf(red_s[0] * (1.f / Hc) + EPSV);
  float o0 = d0 * rstd * g[tid] + bta[tid];
  float o1 = d1 * rstd * g[tid + 256] + bta[tid + 256];
  out[base + tid] = o0;
  out[base + tid + 256] = o1;
  obf[base + tid] = f2bf(o0);
  obf[base + tid + 256] = f2bf(o1);
}

// ---------------------------------------------------------------------------
extern "C" void kernel_launch(void* const* d_in, const int* in_sizes, int n_in,
                              void* d_out, int out_size, void* d_ws, size_t ws_size,
                              hipStream_t stream) {
  const float* q    = (const float*)d_in[0];
  const float* kv   = (const float*)d_in[1];
  const float* relk = (const float*)d_in[2];
  const float* relv = (const float*)d_in[3];
  const float* Wq_s = (const float*)d_in[4];
  const float* bq_s = (const float*)d_in[5];
  const float* Wk_s = (const float*)d_in[6];
  const float* Wv_s = (const float*)d_in[7];
  const float* Wo_s = (const float*)d_in[8];
  const float* bo_s = (const float*)d_in[9];
  const float* ln1g = (const float*)d_in[10];
  const float* ln1b = (const float*)d_in[11];
  const float* Wq_c = (const float*)d_in[12];
  const float* bq_c = (const float*)d_in[13];
  const float* Wk_c = (const float*)d_in[14];
  const float* Wv_c = (const float*)d_in[15];
  const float* Wo_c = (const float*)d_in[16];
  const float* bo_c = (const float*)d_in[17];
  const float* ln2g = (const float*)d_in[18];
  const float* ln2b = (const float*)d_in[19];
  const float* W1   = (const float*)d_in[20];
  const float* b1   = (const float*)d_in[21];
  const float* W2   = (const float*)d_in[22];
  const float* b2   = (const float*)d_in[23];
  const float* ln3g = (const float*)d_in[24];
  const float* ln3b = (const float*)d_in[25];
  const int*   rel  = (const int*)d_in[26];

  char* wsb = (char*)d_ws;
  const size_t NT = (size_t)Bc * Tc;  // 2048 token rows
  float* o     = (float*)wsb;  wsb += NT * Hc * 4;       // 4MB
  float* bDlt  = (float*)wsb;  wsb += NT * Hc * 4;       // 4MB
  float* Qr    = (float*)wsb;  wsb += NT * 8 * 64 * 4;   // 4MB
  u16* obf     = (u16*)wsb;    wsb += NT * Hc * 2;       // 2MB
  u16* kvbf    = (u16*)wsb;    wsb += NT * Hc * 2;       // 2MB
  u16* bQK     = (u16*)wsb;    wsb += NT * 1024 * 2;     // 4MB
  u16* bVt     = (u16*)wsb;    wsb += (size_t)512 * 2048 * 2;   // 2MB
  u16* bQc     = (u16*)wsb;    wsb += NT * Hc * 2;       // 2MB
  u16* bKc     = (u16*)wsb;    wsb += NT * 1024 * 2;     // 4MB
  u16* bVtc    = (u16*)wsb;    wsb += (size_t)1024 * 2048 * 2;  // 4MB
  u16* bAtt    = (u16*)wsb;    wsb += NT * Hc * 2;       // 2MB
  u16* bH      = (u16*)wsb;    wsb += NT * FFc * 2;      // 8MB
  u16* relvt   = (u16*)wsb;    wsb += 64 * 64 * 2;       // 8KB
  u16* wbuf    = (u16*)wsb;    wsb += (size_t)8388608 * 2;  // 16MB

  WPtrs wp;
  wp.p[0] = Wq_s; wp.p[1] = Wk_s; wp.p[2] = Wv_s; wp.p[3] = Wo_s;
  wp.p[4] = Wq_c; wp.p[5] = Wk_c; wp.p[6] = Wv_c; wp.p[7] = Wo_c;
  wp.p[8] = W1;   wp.p[9] = W2;

  dim3 blk(256);
  wcvt<<<dim3(2048), blk, 0, stream>>>(wp, wbuf);
  acvt<<<dim3(1025), blk, 0, stream>>>(q, kv, relv, obf, kvbf, relvt);
  hipMemcpyAsync(o, q, NT * Hc * 4, hipMemcpyDeviceToDevice, stream);

  // cross K (both layers) and cross V^T (both layers)
  gemm_mfma<64, 128, false, 1><<<dim3(8, 32), blk, 0, stream>>>(
      kvbf, wbuf + 2097152, nullptr, 0, bKc, 1024, 512);
  gemm_mfma<64, 128, false, 1><<<dim3(16, 16), blk, 0, stream>>>(
      wbuf + 2621440, kvbf, nullptr, 0, bVtc, 2048, 512);

  const dim3 gLN(NT);
  const dim3 gATT(32, 8, 4);
  for (int i = 0; i < NLc; ++i) {
    // --- relation-aware masked self-attention ---
    gemm_mfma<64, 128, false, 1><<<dim3(8, 32), blk, 0, stream>>>(
        obf, wbuf + (size_t)i * 524288, bq_s + i * Hc, Hc, bQK, 1024, 512);
    gemm_mfma<64, 64, false, 1><<<dim3(32, 8), blk, 0, stream>>>(
        wbuf + 3670016 + (size_t)i * 262144, obf, nullptr, 0, bVt, 2048, 512);
    qr_kernel<<<dim3(4096), blk, 0, stream>>>(bQK, relk, Qr);
    attn_self<<<gATT, blk, 0, stream>>>(
        bQK, bQK + 512, bVt, Qr, rel, relvt, bAtt);
    gemm_mfma<64, 64, false, 0><<<dim3(8, 32), blk, 0, stream>>>(
        bAtt, wbuf + 1048576 + (size_t)i * 262144, bo_s + i * Hc, Hc, bDlt, Hc, 512);
    ln_res<<<gLN, blk, 0, stream>>>(o, bDlt, ln1g + i * Hc, ln1b + i * Hc, o, obf);

    // --- cross-attention ---
    gemm_mfma<64, 64, false, 1><<<dim3(8, 32), blk, 0, stream>>>(
        obf, wbuf + 1572864 + (size_t)i * 262144, bq_c + i * Hc, Hc, bQc, Hc, 512);
    attn_cross<<<gATT, blk, 0, stream>>>(
        bQc, bKc + i * 512, bVtc + (size_t)i * 512 * 2048, bAtt);
    gemm_mfma<64, 64, false, 0><<<dim3(8, 32), blk, 0, stream>>>(
        bAtt, wbuf + 3145728 + (size_t)i * 262144, bo_c + i * Hc, Hc, bDlt, Hc, 512);
    ln_res<<<gLN, blk, 0, stream>>>(o, bDlt, ln2g + i * Hc, ln2b + i * Hc, o, obf);

    // --- feedforward ---
    gemm_mfma<128, 128, true, 1><<<dim3(16, 16), blk, 0, stream>>>(
        obf, wbuf + 4194304 + (size_t)i * 1048576, b1 + i * FFc, FFc, bH, FFc, 512);
    gemm_mfma<64, 64, false, 0><<<dim3(8, 32), blk, 0, stream>>>(
        bH, wbuf + 6291456 + (size_t)i * 1048576, b2 + i * Hc, Hc, bDlt, Hc, 2048);
    float* lnout = (i == NLc - 1) ? (float*)d_out : o;
    ln_res<<<gLN, blk, 0, stream>>>(o, bDlt, ln3g + i * Hc, ln3b + i * Hc, lnout, obf);
  }
}

// Round 8
// 441.287 us; speedup vs baseline: 1.2375x; 1.1235x over previous
//
#include <hip/hip_runtime.h>

static constexpr int Hc  = 512;
static constexpr int NHc = 8;
static constexpr int DHc = 64;
static constexpr int NLc = 2;
static constexpr int Rc  = 64;
static constexpr int FFc = 2048;
static constexpr int Bc  = 4;
static constexpr int Tc  = 512;
#define NEGV (-1e10f)
#define EPSV 1e-5f
#define THRV 6.0f

typedef unsigned short u16;
typedef __attribute__((ext_vector_type(8))) short s16x8;
typedef __attribute__((ext_vector_type(4))) float f32x4;

__device__ __forceinline__ f32x4 mfma_bf16(s16x8 a, s16x8 b, f32x4 c) {
  return __builtin_amdgcn_mfma_f32_16x16x32_bf16(a, b, c, 0, 0, 0);
}
__device__ __forceinline__ u16 f2bf(float f) {
  union { float f; unsigned u; } x; x.f = f;
  unsigned r = (x.u + 0x7FFFu + ((x.u >> 16) & 1u)) >> 16;
  return (u16)r;
}
__device__ __forceinline__ float bf2f(u16 h) {
  union { unsigned u; float f; } x; x.u = ((unsigned)h) << 16;
  return x.f;
}
__device__ __forceinline__ unsigned cvtpk(float a, float b) {
  unsigned r;
  asm("v_cvt_pk_bf16_f32 %0, %1, %2" : "=v"(r) : "v"(a), "v"(b));
  return r;
}

// ---------------------------------------------------------------------------
// bf16 MFMA GEMM: C[M,N] = A[M,K] @ Wt[N,K]^T (+bias for col<biasN) (+relu)
// ---------------------------------------------------------------------------
template <int BM, int BN, bool RELU, int OUT>  // OUT: 0=f32, 1=bf16
__global__ __launch_bounds__(256) void gemm_mfma(
    const u16* __restrict__ A, const u16* __restrict__ Wt,
    const float* __restrict__ bias, int biasN,
    void* __restrict__ Cout, int N, int K) {
  __shared__ u16 As[BM * 32];
  __shared__ u16 Bs[BN * 32];
  const int tid = threadIdx.x;
  const int w = tid >> 6, lane = tid & 63, g = lane >> 4, li = lane & 15;
  const int bn = blockIdx.x * BN, bm = blockIdx.y * BM;
  const int r0 = (w & 1) * (BM / 2), c0 = (w >> 1) * (BN / 2);
  constexpr int MR = BM / 32, NR = BN / 32;
  f32x4 acc[MR][NR];
#pragma unroll
  for (int i = 0; i < MR; ++i)
#pragma unroll
    for (int j = 0; j < NR; ++j) acc[i][j] = (f32x4){0.f, 0.f, 0.f, 0.f};

  for (int k0 = 0; k0 < K; k0 += 32) {
    __syncthreads();
#pragma unroll
    for (int it = 0; it < BM / 64; ++it) {
      int s = it * 256 + tid;
      int row = s >> 2, ch = s & 3;
      s16x8 v = *(const s16x8*)(A + (size_t)(bm + row) * K + k0 + ch * 8);
      *(s16x8*)&As[row * 32 + ((ch ^ (row & 3)) * 8)] = v;
    }
#pragma unroll
    for (int it = 0; it < BN / 64; ++it) {
      int s = it * 256 + tid;
      int row = s >> 2, ch = s & 3;
      s16x8 v = *(const s16x8*)(Wt + (size_t)(bn + row) * K + k0 + ch * 8);
      *(s16x8*)&Bs[row * 32 + ((ch ^ (row & 3)) * 8)] = v;
    }
    __syncthreads();
    s16x8 ar[MR], br[NR];
#pragma unroll
    for (int i = 0; i < MR; ++i) {
      int row = r0 + i * 16 + li;
      ar[i] = *(const s16x8*)&As[row * 32 + ((g ^ (row & 3)) * 8)];
    }
#pragma unroll
    for (int j = 0; j < NR; ++j) {
      int row = c0 + j * 16 + li;
      br[j] = *(const s16x8*)&Bs[row * 32 + ((g ^ (row & 3)) * 8)];
    }
#pragma unroll
    for (int i = 0; i < MR; ++i)
#pragma unroll
      for (int j = 0; j < NR; ++j) acc[i][j] = mfma_bf16(ar[i], br[j], acc[i][j]);
  }

#pragma unroll
  for (int j = 0; j < NR; ++j) {
    int col = bn + c0 + j * 16 + li;
    float bv = (bias && col < biasN) ? bias[col] : 0.f;
#pragma unroll
    for (int i = 0; i < MR; ++i) {
#pragma unroll
      for (int r = 0; r < 4; ++r) {
        int rowg = bm + r0 + i * 16 + 4 * g + r;
        float v = acc[i][j][r] + bv;
        if (RELU) v = fmaxf(v, 0.f);
        if (OUT == 0) ((float*)Cout)[(size_t)rowg * N + col] = v;
        else          ((u16*)Cout)[(size_t)rowg * N + col] = f2bf(v);
      }
    }
  }
}

// ---------------------------------------------------------------------------
// Weight transpose+convert: f32 [Ks][Ns] -> bf16 [Ns][Ks] at dstOff
// ---------------------------------------------------------------------------
struct WPtrs { const float* p[10]; };

__global__ __launch_bounds__(256) void wcvt(WPtrs wp, u16* __restrict__ dst) {
  constexpr int NE = 20;
  constexpr int srcIdx[NE] = {0,1,0,1,3,3,4,4,5,5,6,6,7,7,2,2,8,8,9,9};
  constexpr int srcOff[NE] = {0,0,262144,262144,0,262144,0,262144,0,262144,
                              0,262144,0,262144,0,262144,0,1048576,0,1048576};
  constexpr int dstOff[NE] = {0,262144,524288,786432,1048576,1310720,
                              1572864,1835008,2097152,2359296,2621440,2883584,
                              3145728,3407872,3670016,3932160,
                              4194304,5242880,6291456,7340032};
  constexpr int KsA[NE] = {512,512,512,512,512,512,512,512,512,512,
                           512,512,512,512,512,512,512,512,2048,2048};
  constexpr int NsA[NE] = {512,512,512,512,512,512,512,512,512,512,
                           512,512,512,512,512,512,2048,2048,512,512};
  constexpr int tileStart[NE] = {0,64,128,192,256,320,384,448,512,576,
                                 640,704,768,832,896,960,1024,1280,1536,1792};
  __shared__ float ts[64 * 65];
  const int tid = threadIdx.x;
  const int bid = blockIdx.x;
  int e = 0;
#pragma unroll
  for (int i = 1; i < NE; ++i) if (bid >= tileStart[i]) e = i;
  const int t = bid - tileStart[e];
  const int Ks_ = KsA[e], Ns_ = NsA[e];
  const int tn = t % (Ns_ >> 6), tk = t / (Ns_ >> 6);
  const float* src = wp.p[srcIdx[e]] + srcOff[e];

  {
    int r = tid >> 2, cb = (tid & 3) * 16;
    const float* sp = src + (size_t)(tk * 64 + r) * Ns_ + tn * 64 + cb;
#pragma unroll
    for (int j = 0; j < 4; ++j) {
      float4 v = ((const float4*)sp)[j];
      float* d = &ts[r * 65 + cb + j * 4];
      d[0] = v.x; d[1] = v.y; d[2] = v.z; d[3] = v.w;
    }
  }
  __syncthreads();
  {
    int n = tid >> 2, kb = (tid & 3) * 16;
    u16* dp = dst + dstOff[e] + (size_t)(tn * 64 + n) * Ks_ + tk * 64 + kb;
    s16x8 o0, o1;
#pragma unroll
    for (int j = 0; j < 8; ++j) o0[j] = (short)f2bf(ts[(kb + j) * 65 + n]);
#pragma unroll
    for (int j = 0; j < 8; ++j) o1[j] = (short)f2bf(ts[(kb + 8 + j) * 65 + n]);
    *(s16x8*)dp = o0;
    *(s16x8*)(dp + 8) = o1;
  }
}

// ---------------------------------------------------------------------------
// activations f32->bf16 (blocks 0..1023); block 1024: relv -> relv^T bf16
// ---------------------------------------------------------------------------
__global__ __launch_bounds__(256) void acvt(
    const float* __restrict__ q, const float* __restrict__ kv,
    const float* __restrict__ relv,
    u16* __restrict__ obf, u16* __restrict__ kvbf, u16* __restrict__ relvt) {
  int bid = blockIdx.x, tid = threadIdx.x;
  if (bid == 1024) {
    int d = tid >> 2, rb = (tid & 3) * 16;
    s16x8 o0, o1;
#pragma unroll
    for (int j = 0; j < 8; ++j) o0[j] = (short)f2bf(relv[(rb + j) * 64 + d]);
#pragma unroll
    for (int j = 0; j < 8; ++j) o1[j] = (short)f2bf(relv[(rb + 8 + j) * 64 + d]);
    *(s16x8*)(relvt + d * 64 + rb) = o0;
    *(s16x8*)(relvt + d * 64 + rb + 8) = o1;
    return;
  }
  int i = bid * 256 + tid;
  const float* src; u16* dst; size_t off;
  if (i < 131072) { src = q; dst = obf; off = (size_t)i * 8; }
  else { src = kv; dst = kvbf; off = (size_t)(i - 131072) * 8; }
  float4 a = *(const float4*)(src + off);
  float4 b = *(const float4*)(src + off + 4);
  s16x8 o;
  o[0] = (short)f2bf(a.x); o[1] = (short)f2bf(a.y);
  o[2] = (short)f2bf(a.z); o[3] = (short)f2bf(a.w);
  o[4] = (short)f2bf(b.x); o[5] = (short)f2bf(b.y);
  o[6] = (short)f2bf(b.z); o[7] = (short)f2bf(b.w);
  *(s16x8*)(dst + off) = o;
}

// ---------------------------------------------------------------------------
// Qr[(row*8+h), r] = sum_d Q[row, h*64+d] * relk[r, d]  (Q = bQK, stride 1024)
// ---------------------------------------------------------------------------
__global__ __launch_bounds__(256) void qr_kernel(
    const u16* __restrict__ Q, const float* __restrict__ relk,
    float* __restrict__ Qr) {
  __shared__ float rk[64 * 65];
  __shared__ float qs[4][64];
  const int tid = threadIdx.x;
  {
    int r = tid >> 2, cb = (tid & 3) * 16;
    const float* sp = relk + r * 64 + cb;
#pragma unroll
    for (int j = 0; j < 4; ++j) {
      float4 v = ((const float4*)sp)[j];
      float* d = &rk[r * 65 + cb + j * 4];
      d[0] = v.x; d[1] = v.y; d[2] = v.z; d[3] = v.w;
    }
  }
  const int sub = tid >> 6, r = tid & 63;
  const int unit = blockIdx.x * 4 + sub;  // unit = row*8 + h
  qs[sub][r] = bf2f(Q[(size_t)(unit >> 3) * 1024 + (unit & 7) * 64 + r]);
  __syncthreads();
  float acc = 0.f;
#pragma unroll
  for (int d = 0; d < 64; ++d) acc += qs[sub][d] * rk[r * 65 + d];
  Qr[(size_t)unit * 64 + r] = acc;
}

// ---------------------------------------------------------------------------
// Split-KV attention (flash-decode style), block-level splits.
// Each single-wave block scans 2 chunks UNCONDITIONALLY; masked cols give
// p = exp(NEGV - NEGV) = 1 while mrow stays NEGV; the merge factor
// f = exp(m_s - m) zeroes garbage partials exactly (m finite) or combines
// uniform sums (all m_s = NEGV -> reference's uniform softmax). No barriers,
// no continuation path. Partials: po[idx*4+s][64] f32, pms[idx*4+s]{m,rsum}.
// ---------------------------------------------------------------------------
#define RELID(RV, r) ((r) == 0 ? (RV).x : (r) == 1 ? (RV).y : (r) == 2 ? (RV).z : (RV).w)

#define LOADKREL(KF, RF, C8) do {                                              \
    _Pragma("unroll") for (int mt = 0; mt < 4; ++mt) {                         \
      KF[mt * 2 + 0] = *(const s16x8*)(kp + (size_t)(C8) * 65536 + mt * 16384);\
      KF[mt * 2 + 1] = *(const s16x8*)(kp + (size_t)(C8) * 65536 + mt * 16384 + 32); \
      RF[mt] = *(const int4*)(rp + (C8) * 64 + mt * 16);                       \
    } } while (0)

#define COMPUTE_SELF(KF, RF, C8) do {                                          \
    s16x8 vf[8];                                                               \
    _Pragma("unroll") for (int df = 0; df < 4; ++df) {                         \
      vf[df * 2 + 0] = *(const s16x8*)(vp + (size_t)(C8) * 64 + df * 32768);   \
      vf[df * 2 + 1] = *(const s16x8*)(vp + (size_t)(C8) * 64 + df * 32768 + 32); } \
    f32x4 sf[4];                                                               \
    _Pragma("unroll") for (int mt = 0; mt < 4; ++mt) {                         \
      sf[mt] = (f32x4){0.f, 0.f, 0.f, 0.f};                                    \
      sf[mt] = mfma_bf16(KF[mt * 2 + 0], aq0, sf[mt]);                         \
      sf[mt] = mfma_bf16(KF[mt * 2 + 1], aq1, sf[mt]); }                       \
    float p[4][4];                                                             \
    float pmax = NEGV;                                                         \
    _Pragma("unroll") for (int mt = 0; mt < 4; ++mt) {                         \
      _Pragma("unroll") for (int r = 0; r < 4; ++r) {                          \
        int rel = RELID(RF[mt], r);                                            \
        bool valid = (rel != 0) && ((C8) * 64 + mt * 16 + 4 * g + r <= lrow);  \
        p[mt][r] = valid ? (sf[mt][r] + qrs[li * 66 + rel]) * 0.125f : NEGV;   \
        pmax = fmaxf(pmax, p[mt][r]); } }                                      \
    pmax = fmaxf(pmax, __shfl_xor(pmax, 16));                                  \
    pmax = fmaxf(pmax, __shfl_xor(pmax, 32));                                  \
    if (__any(pmax > mrow + THRV)) {                                           \
      float mnew = (pmax > mrow + THRV) ? pmax : mrow;                         \
      float f = __expf(mrow - mnew);                                           \
      rsum *= f;                                                               \
      _Pragma("unroll") for (int j = 0; j < 8; ++j) {                          \
        float2* p2 = (float2*)&bk[li * 66 + g * 16 + 2 * j];                   \
        float2 v = *p2; v.x *= f; v.y *= f; *p2 = v; }                         \
      _Pragma("unroll") for (int r = 0; r < 4; ++r) {                          \
        float fr = __shfl(f, 4 * g + r);                                       \
        _Pragma("unroll") for (int df = 0; df < 4; ++df) oacc[df][r] *= fr; }  \
      mrow = mnew; }                                                           \
    unsigned pk[4][2];                                                         \
    _Pragma("unroll") for (int mt = 0; mt < 4; ++mt) {                         \
      _Pragma("unroll") for (int r = 0; r < 4; ++r) {                          \
        float pv = __expf(p[mt][r] - mrow);                                    \
        p[mt][r] = pv;                                                         \
        rsum += pv;                                                            \
        if (pv > 0.f) atomicAdd(&bk[li * 66 + RELID(RF[mt], r)], pv); }        \
      pk[mt][0] = cvtpk(p[mt][0], p[mt][1]);                                   \
      pk[mt][1] = cvtpk(p[mt][2], p[mt][3]); }                                 \
    _Pragma("unroll") for (int kk = 0; kk < 2; ++kk) {                         \
      union { s16x8 v; unsigned u[4]; } pa;                                    \
      _Pragma("unroll") for (int q = 0; q < 4; ++q) {                          \
        int src = ((2 * (g & 1) + (q >> 1)) << 4) + li;                        \
        unsigned uA = __shfl(pk[2 * kk][q & 1], src);                          \
        unsigned uB = __shfl(pk[2 * kk + 1][q & 1], src);                      \
        pa.u[q] = (g < 2) ? uA : uB; }                                         \
      _Pragma("unroll") for (int df = 0; df < 4; ++df)                         \
        oacc[df] = mfma_bf16(pa.v, vf[df * 2 + kk], oacc[df]); }               \
  } while (0)

__global__ __launch_bounds__(64) void attn_self_part(
    const u16* __restrict__ Qb, const u16* __restrict__ Kb,  // stride 1024
    const u16* __restrict__ VT,                              // [512][2048]
    const float* __restrict__ Qr, const int* __restrict__ rel_ids,
    const u16* __restrict__ relvt,
    float* __restrict__ po, float2* __restrict__ pms) {
  __shared__ float qrs[16 * 66];
  __shared__ float buck[16 * 66];
  float* bk = buck;

  const int lane = threadIdx.x;
  const int g = lane >> 4, li = lane & 15;
  const int qt = blockIdx.x, h = blockIdx.y;
  const int b = blockIdx.z >> 2, s = blockIdx.z & 3;
  const int lrow = qt * 16 + li;
  const int growq = b * 512 + qt * 16;

  const u16* qp = Qb + (size_t)(growq + li) * 1024 + h * 64;
  s16x8 aq0 = *(const s16x8*)(qp + g * 8);
  s16x8 aq1 = *(const s16x8*)(qp + 32 + g * 8);
  const u16* kp = Kb + (size_t)(b * 512 + li) * 1024 + h * 64 + g * 8;
  const u16* vp = VT + (size_t)(h * 64 + li) * 2048 + b * 512 + g * 8;
  const int* rp = rel_ids + (size_t)(growq + li) * 512 + 4 * g;

#pragma unroll
  for (int j = 0; j < 4; ++j) {  // stage Qr (16x64) + zero buckets
    int fi = j * 64 + lane;
    int row = fi >> 4, c4 = (fi & 15) * 4;
    float4 v = *(const float4*)(Qr + ((size_t)(growq + row) * 8 + h) * 64 + c4);
    *(float4*)&qrs[row * 66 + c4] = v;
    *(float4*)&buck[row * 66 + c4] = make_float4(0.f, 0.f, 0.f, 0.f);
  }

  float mrow = NEGV, rsum = 0.f;
  f32x4 oacc[4];
#pragma unroll
  for (int d = 0; d < 4; ++d) oacc[d] = (f32x4){0.f, 0.f, 0.f, 0.f};

  {
    s16x8 kA[8]; int4 rA[4];
    LOADKREL(kA, rA, 2 * s);
    COMPUTE_SELF(kA, rA, 2 * s);
  }
  {
    s16x8 kA[8]; int4 rA[4];
    LOADKREL(kA, rA, 2 * s + 1);
    COMPUTE_SELF(kA, rA, 2 * s + 1);
  }

  rsum += __shfl_xor(rsum, 16);
  rsum += __shfl_xor(rsum, 32);

  // rel-V fold into partial: oacc += buck @ relv  (B = relv^T)
#pragma unroll
  for (int kk = 0; kk < 2; ++kk) {
    float bb[8];
#pragma unroll
    for (int j = 0; j < 4; ++j) {
      float2 v = *(const float2*)&bk[li * 66 + kk * 32 + g * 8 + 2 * j];
      bb[2 * j] = v.x; bb[2 * j + 1] = v.y;
    }
    union { s16x8 v; unsigned u[4]; } pb;
#pragma unroll
    for (int q = 0; q < 4; ++q) pb.u[q] = cvtpk(bb[2 * q], bb[2 * q + 1]);
#pragma unroll
    for (int df = 0; df < 4; ++df) {
      s16x8 rb = *(const s16x8*)(relvt + (df * 16 + li) * 64 + kk * 32 + g * 8);
      oacc[df] = mfma_bf16(pb.v, rb, oacc[df]);
    }
  }

  const size_t idx = (size_t)(b * 8 + h) * 512 + qt * 16;
#pragma unroll
  for (int df = 0; df < 4; ++df)
#pragma unroll
    for (int r = 0; r < 4; ++r)
      po[((idx + 4 * g + r) * 4 + s) * 64 + df * 16 + li] = oacc[df][r];
  if (lane < 16) pms[(idx + lane) * 4 + s] = make_float2(mrow, rsum);
}

#define LOADK_X(KF, C8) do {                                                   \
    _Pragma("unroll") for (int mt = 0; mt < 4; ++mt) {                         \
      KF[mt * 2 + 0] = *(const s16x8*)(kp + (size_t)(C8) * 65536 + mt * 16384);\
      KF[mt * 2 + 1] = *(const s16x8*)(kp + (size_t)(C8) * 65536 + mt * 16384 + 32); \
    } } while (0)

#define COMPUTE_X(KF, C8) do {                                                 \
    s16x8 vf[8];                                                               \
    _Pragma("unroll") for (int df = 0; df < 4; ++df) {                         \
      vf[df * 2 + 0] = *(const s16x8*)(vp + (size_t)(C8) * 64 + df * 32768);   \
      vf[df * 2 + 1] = *(const s16x8*)(vp + (size_t)(C8) * 64 + df * 32768 + 32); } \
    f32x4 sf[4];                                                               \
    _Pragma("unroll") for (int mt = 0; mt < 4; ++mt) {                         \
      sf[mt] = (f32x4){0.f, 0.f, 0.f, 0.f};                                    \
      sf[mt] = mfma_bf16(KF[mt * 2 + 0], aq0, sf[mt]);                         \
      sf[mt] = mfma_bf16(KF[mt * 2 + 1], aq1, sf[mt]); }                       \
    float p[4][4];                                                             \
    float pmax = NEGV;                                                         \
    _Pragma("unroll") for (int mt = 0; mt < 4; ++mt)                           \
      _Pragma("unroll") for (int r = 0; r < 4; ++r) {                          \
        p[mt][r] = sf[mt][r] * 0.125f;                                         \
        pmax = fmaxf(pmax, p[mt][r]); }                                        \
    pmax = fmaxf(pmax, __shfl_xor(pmax, 16));                                  \
    pmax = fmaxf(pmax, __shfl_xor(pmax, 32));                                  \
    if (__any(pmax > mrow + THRV)) {                                           \
      float mnew = (pmax > mrow + THRV) ? pmax : mrow;                         \
      float f = __expf(mrow - mnew);                                           \
      rsum *= f;                                                               \
      _Pragma("unroll") for (int r = 0; r < 4; ++r) {                          \
        float fr = __shfl(f, 4 * g + r);                                       \
        _Pragma("unroll") for (int df = 0; df < 4; ++df) oacc[df][r] *= fr; }  \
      mrow = mnew; }                                                           \
    unsigned pk[4][2];                                                         \
    _Pragma("unroll") for (int mt = 0; mt < 4; ++mt) {                         \
      _Pragma("unroll") for (int r = 0; r < 4; ++r) {                          \
        float pv = __expf(p[mt][r] - mrow);                                    \
        p[mt][r] = pv;                                                         \
        rsum += pv; }                                                          \
      pk[mt][0] = cvtpk(p[mt][0], p[mt][1]);                                   \
      pk[mt][1] = cvtpk(p[mt][2], p[mt][3]); }                                 \
    _Pragma("unroll") for (int kk = 0; kk < 2; ++kk) {                         \
      union { s16x8 v; unsigned u[4]; } pa;                                    \
      _Pragma("unroll") for (int q = 0; q < 4; ++q) {                          \
        int src = ((2 * (g & 1) + (q >> 1)) << 4) + li;                        \
        unsigned uA = __shfl(pk[2 * kk][q & 1], src);                          \
        unsigned uB = __shfl(pk[2 * kk + 1][q & 1], src);                      \
        pa.u[q] = (g < 2) ? uA : uB; }                                         \
      _Pragma("unroll") for (int df = 0; df < 4; ++df)                         \
        oacc[df] = mfma_bf16(pa.v, vf[df * 2 + kk], oacc[df]); }               \
  } while (0)

__global__ __launch_bounds__(64) void attn_cross_part(
    const u16* __restrict__ Qb,   // stride 512
    const u16* __restrict__ Kb,   // stride 1024
    const u16* __restrict__ VT,   // stride 2048
    float* __restrict__ po, float2* __restrict__ pms) {
  const int lane = threadIdx.x;
  const int g = lane >> 4, li = lane & 15;
  const int qt = blockIdx.x, h = blockIdx.y;
  const int b = blockIdx.z >> 2, s = blockIdx.z & 3;
  const int growq = b * 512 + qt * 16;

  const u16* qp = Qb + (size_t)(growq + li) * 512 + h * 64;
  s16x8 aq0 = *(const s16x8*)(qp + g * 8);
  s16x8 aq1 = *(const s16x8*)(qp + 32 + g * 8);
  const u16* kp = Kb + (size_t)(b * 512 + li) * 1024 + h * 64 + g * 8;
  const u16* vp = VT + (size_t)(h * 64 + li) * 2048 + b * 512 + g * 8;

  float mrow = NEGV, rsum = 0.f;
  f32x4 oacc[4];
#pragma unroll
  for (int d = 0; d < 4; ++d) oacc[d] = (f32x4){0.f, 0.f, 0.f, 0.f};

  {
    s16x8 kA[8];
    LOADK_X(kA, 2 * s);
    COMPUTE_X(kA, 2 * s);
  }
  {
    s16x8 kA[8];
    LOADK_X(kA, 2 * s + 1);
    COMPUTE_X(kA, 2 * s + 1);
  }

  rsum += __shfl_xor(rsum, 16);
  rsum += __shfl_xor(rsum, 32);

  const size_t idx = (size_t)(b * 8 + h) * 512 + qt * 16;
#pragma unroll
  for (int df = 0; df < 4; ++df)
#pragma unroll
    for (int r = 0; r < 4; ++r)
      po[((idx + 4 * g + r) * 4 + s) * 64 + df * 16 + li] = oacc[df][r];
  if (lane < 16) pms[(idx + lane) * 4 + s] = make_float2(mrow, rsum);
}

// ---------------------------------------------------------------------------
// Merge 4 split partials per row: m = max m_s, f = exp(m_s - m);
// out = (sum f*oacc_s) / (sum f*rsum_s). Exact (garbage splits get f = 0;
// all-masked rows get f = 1 everywhere -> uniform over 512). 16 rows/block.
// ---------------------------------------------------------------------------
__global__ __launch_bounds__(256) void attn_merge(
    const float* __restrict__ po, const float2* __restrict__ pms,
    u16* __restrict__ att) {
  const int t = threadIdx.x;
  const size_t idx = (size_t)blockIdx.x * 16 + (t >> 4);
  const int d4 = (t & 15) * 4;
  float2 ms[4];
  float m = NEGV;
#pragma unroll
  for (int s = 0; s < 4; ++s) {
    ms[s] = pms[idx * 4 + s];
    m = fmaxf(m, ms[s].x);
  }
  float rs = 0.f;
  float4 o = make_float4(0.f, 0.f, 0.f, 0.f);
#pragma unroll
  for (int s = 0; s < 4; ++s) {
    float f = __expf(ms[s].x - m);
    rs += f * ms[s].y;
    float4 v = *(const float4*)(po + (idx * 4 + s) * 64 + d4);
    o.x += f * v.x; o.y += f * v.y; o.z += f * v.z; o.w += f * v.w;
  }
  const float inv = 1.f / rs;
  const int b = (int)(idx >> 12), h = (int)(idx >> 9) & 7, row = (int)(idx & 511);
  ushort4 ov;
  ov.x = f2bf(o.x * inv);
  ov.y = f2bf(o.y * inv);
  ov.z = f2bf(o.z * inv);
  ov.w = f2bf(o.w * inv);
  *(ushort4*)(att + (size_t)(b * 512 + row) * 512 + h * 64 + d4) = ov;
}

// ---------------------------------------------------------------------------
// out = LayerNorm(x + dlt) * g + b ; also writes bf16 copy
// ---------------------------------------------------------------------------
__global__ __launch_bounds__(256) void ln_res(
    const float* __restrict__ x, const float* __restrict__ dlt,
    const float* __restrict__ g, const float* __restrict__ bta,
    float* __restrict__ out, u16* __restrict__ obf) {
  __shared__ float red_s[256];
  const int row = blockIdx.x, tid = threadIdx.x;
  const size_t base = (size_t)row * Hc;
  float v0 = x[base + tid] + dlt[base + tid];
  float v1 = x[base + tid + 256] + dlt[base + tid + 256];

  red_s[tid] = v0 + v1;
  __syncthreads();
  for (int s = 128; s > 0; s >>= 1) {
    if (tid < s) red_s[tid] += red_s[tid + s];
    __syncthreads();
  }
  const float mean = red_s[0] * (1.f / Hc);
  __syncthreads();
  const float d0 = v0 - mean, d1 = v1 - mean;
  red_s[tid] = d0 * d0 + d1 * d1;
  __syncthreads();
  for (int s = 128; s > 0; s >>= 1) {
    if (tid < s) red_s[tid] += red_s[tid + s];
    __syncthreads();
  }
  const float rstd = rsqrtf(red_s[0] * (1.f / Hc) + EPSV);
  float o0 = d0 * rstd * g[tid] + bta[tid];
  float o1 = d1 * rstd * g[tid + 256] + bta[tid + 256];
  out[base + tid] = o0;
  out[base + tid + 256] = o1;
  obf[base + tid] = f2bf(o0);
  obf[base + tid + 256] = f2bf(o1);
}

// ---------------------------------------------------------------------------
extern "C" void kernel_launch(void* const* d_in, const int* in_sizes, int n_in,
                              void* d_out, int out_size, void* d_ws, size_t ws_size,
                              hipStream_t stream) {
  const float* q    = (const float*)d_in[0];
  const float* kv   = (const float*)d_in[1];
  const float* relk = (const float*)d_in[2];
  const float* relv = (const float*)d_in[3];
  const float* Wq_s = (const float*)d_in[4];
  const float* bq_s = (const float*)d_in[5];
  const float* Wk_s = (const float*)d_in[6];
  const float* Wv_s = (const float*)d_in[7];
  const float* Wo_s = (const float*)d_in[8];
  const float* bo_s = (const float*)d_in[9];
  const float* ln1g = (const float*)d_in[10];
  const float* ln1b = (const float*)d_in[11];
  const float* Wq_c = (const float*)d_in[12];
  const float* bq_c = (const float*)d_in[13];
  const float* Wk_c = (const float*)d_in[14];
  const float* Wv_c = (const float*)d_in[15];
  const float* Wo_c = (const float*)d_in[16];
  const float* bo_c = (const float*)d_in[17];
  const float* ln2g = (const float*)d_in[18];
  const float* ln2b = (const float*)d_in[19];
  const float* W1   = (const float*)d_in[20];
  const float* b1   = (const float*)d_in[21];
  const float* W2   = (const float*)d_in[22];
  const float* b2   = (const float*)d_in[23];
  const float* ln3g = (const float*)d_in[24];
  const float* ln3b = (const float*)d_in[25];
  const int*   rel  = (const int*)d_in[26];

  char* wsb = (char*)d_ws;
  const size_t NT = (size_t)Bc * Tc;  // 2048 token rows
  float* o     = (float*)wsb;  wsb += NT * Hc * 4;       // 4MB
  float* bDlt  = (float*)wsb;  wsb += NT * Hc * 4;       // 4MB
  float* Qr    = (float*)wsb;  wsb += NT * 8 * 64 * 4;   // 4MB
  u16* obf     = (u16*)wsb;    wsb += NT * Hc * 2;       // 2MB
  u16* kvbf    = (u16*)wsb;    wsb += NT * Hc * 2;       // 2MB
  u16* bQK     = (u16*)wsb;    wsb += NT * 1024 * 2;     // 4MB
  u16* bVt     = (u16*)wsb;    wsb += (size_t)512 * 2048 * 2;   // 2MB
  u16* bQc     = (u16*)wsb;    wsb += NT * Hc * 2;       // 2MB
  u16* bKc     = (u16*)wsb;    wsb += NT * 1024 * 2;     // 4MB
  u16* bVtc    = (u16*)wsb;    wsb += (size_t)1024 * 2048 * 2;  // 4MB
  u16* bAtt    = (u16*)wsb;    wsb += NT * Hc * 2;       // 2MB
  u16* bH      = (u16*)wsb;    wsb += NT * FFc * 2;      // 8MB
  u16* relvt   = (u16*)wsb;    wsb += 64 * 64 * 2;       // 8KB
  u16* wbuf    = (u16*)wsb;    wsb += (size_t)8388608 * 2;  // 16MB
  float* po    = (float*)wsb;  wsb += (size_t)16384 * 4 * 64 * 4;  // 16MB
  float2* pms  = (float2*)wsb; wsb += (size_t)16384 * 4 * 8;       // 512KB

  WPtrs wp;
  wp.p[0] = Wq_s; wp.p[1] = Wk_s; wp.p[2] = Wv_s; wp.p[3] = Wo_s;
  wp.p[4] = Wq_c; wp.p[5] = Wk_c; wp.p[6] = Wv_c; wp.p[7] = Wo_c;
  wp.p[8] = W1;   wp.p[9] = W2;

  dim3 blk(256);
  wcvt<<<dim3(2048), blk, 0, stream>>>(wp, wbuf);
  acvt<<<dim3(1025), blk, 0, stream>>>(q, kv, relv, obf, kvbf, relvt);
  hipMemcpyAsync(o, q, NT * Hc * 4, hipMemcpyDeviceToDevice, stream);

  // cross K (both layers) and cross V^T (both layers)
  gemm_mfma<64, 128, false, 1><<<dim3(8, 32), blk, 0, stream>>>(
      kvbf, wbuf + 2097152, nullptr, 0, bKc, 1024, 512);
  gemm_mfma<64, 128, false, 1><<<dim3(16, 16), blk, 0, stream>>>(
      wbuf + 2621440, kvbf, nullptr, 0, bVtc, 2048, 512);

  const dim3 gLN(NT);
  const dim3 gPART(32, 8, 16);
  const dim3 gMERGE(1024);
  for (int i = 0; i < NLc; ++i) {
    // --- relation-aware masked self-attention ---
    gemm_mfma<64, 128, false, 1><<<dim3(8, 32), blk, 0, stream>>>(
        obf, wbuf + (size_t)i * 524288, bq_s + i * Hc, Hc, bQK, 1024, 512);
    gemm_mfma<64, 64, false, 1><<<dim3(32, 8), blk, 0, stream>>>(
        wbuf + 3670016 + (size_t)i * 262144, obf, nullptr, 0, bVt, 2048, 512);
    qr_kernel<<<dim3(4096), blk, 0, stream>>>(bQK, relk, Qr);
    attn_self_part<<<gPART, dim3(64), 0, stream>>>(
        bQK, bQK + 512, bVt, Qr, rel, relvt, po, pms);
    attn_merge<<<gMERGE, blk, 0, stream>>>(po, pms, bAtt);
    gemm_mfma<64, 64, false, 0><<<dim3(8, 32), blk, 0, stream>>>(
        bAtt, wbuf + 1048576 + (size_t)i * 262144, bo_s + i * Hc, Hc, bDlt, Hc, 512);
    ln_res<<<gLN, blk, 0, stream>>>(o, bDlt, ln1g + i * Hc, ln1b + i * Hc, o, obf);

    // --- cross-attention ---
    gemm_mfma<64, 64, false, 1><<<dim3(8, 32), blk, 0, stream>>>(
        obf, wbuf + 1572864 + (size_t)i * 262144, bq_c + i * Hc, Hc, bQc, Hc, 512);
    attn_cross_part<<<gPART, dim3(64), 0, stream>>>(
        bQc, bKc + i * 512, bVtc + (size_t)i * 512 * 2048, po, pms);
    attn_merge<<<gMERGE, blk, 0, stream>>>(po, pms, bAtt);
    gemm_mfma<64, 64, false, 0><<<dim3(8, 32), blk, 0, stream>>>(
        bAtt, wbuf + 3145728 + (size_t)i * 262144, bo_c + i * Hc, Hc, bDlt, Hc, 512);
    ln_res<<<gLN, blk, 0, stream>>>(o, bDlt, ln2g + i * Hc, ln2b + i * Hc, o, obf);

    // --- feedforward ---
    gemm_mfma<128, 128, true, 1><<<dim3(16, 16), blk, 0, stream>>>(
        obf, wbuf + 4194304 + (size_t)i * 1048576, b1 + i * FFc, FFc, bH, FFc, 512);
    gemm_mfma<64, 64, false, 0><<<dim3(8, 32), blk, 0, stream>>>(
        bH, wbuf + 6291456 + (size_t)i * 1048576, b2 + i * Hc, Hc, bDlt, Hc, 2048);
    float* lnout = (i == NLc - 1) ? (float*)d_out : o;
    ln_res<<<gLN, blk, 0, stream>>>(o, bDlt, ln3g + i * Hc, ln3b + i * Hc, lnout, obf);
  }
}

// Round 9
// 389.419 us; speedup vs baseline: 1.4023x; 1.1332x over previous
//
#include <hip/hip_runtime.h>

static constexpr int Hc  = 512;
static constexpr int NHc = 8;
static constexpr int DHc = 64;
static constexpr int NLc = 2;
static constexpr int Rc  = 64;
static constexpr int FFc = 2048;
static constexpr int Bc  = 4;
static constexpr int Tc  = 512;
#define NEGV (-1e10f)
#define EPSV 1e-5f
#define THRV 6.0f

typedef unsigned short u16;
typedef unsigned char u8;
typedef __attribute__((ext_vector_type(8))) short s16x8;
typedef __attribute__((ext_vector_type(4))) float f32x4;

__device__ __forceinline__ f32x4 mfma_bf16(s16x8 a, s16x8 b, f32x4 c) {
  return __builtin_amdgcn_mfma_f32_16x16x32_bf16(a, b, c, 0, 0, 0);
}
__device__ __forceinline__ u16 f2bf(float f) {
  union { float f; unsigned u; } x; x.f = f;
  unsigned r = (x.u + 0x7FFFu + ((x.u >> 16) & 1u)) >> 16;
  return (u16)r;
}
__device__ __forceinline__ float bf2f(u16 h) {
  union { unsigned u; float f; } x; x.u = ((unsigned)h) << 16;
  return x.f;
}
__device__ __forceinline__ unsigned cvtpk(float a, float b) {
  unsigned r;
  asm("v_cvt_pk_bf16_f32 %0, %1, %2" : "=v"(r) : "v"(a), "v"(b));
  return r;
}

// ---------------------------------------------------------------------------
// bf16 MFMA GEMM: C[M,N] = A[M,K] @ Wt[N,K]^T (+bias for col<biasN) (+relu)
// Register double-buffer: tile k+1 global loads issue right after tile k's
// LDS store, hiding HBM/L2 latency under the MFMA phase.
// ---------------------------------------------------------------------------
template <int BM, int BN, bool RELU, int OUT>  // OUT: 0=f32, 1=bf16
__global__ __launch_bounds__(256) void gemm_mfma(
    const u16* __restrict__ A, const u16* __restrict__ Wt,
    const float* __restrict__ bias, int biasN,
    void* __restrict__ Cout, int N, int K) {
  __shared__ u16 As[BM * 32];
  __shared__ u16 Bs[BN * 32];
  const int tid = threadIdx.x;
  const int w = tid >> 6, lane = tid & 63, g = lane >> 4, li = lane & 15;
  const int bn = blockIdx.x * BN, bm = blockIdx.y * BM;
  const int r0 = (w & 1) * (BM / 2), c0 = (w >> 1) * (BN / 2);
  constexpr int MR = BM / 32, NR = BN / 32;
  constexpr int AIT = BM / 64, BIT = BN / 64;
  f32x4 acc[MR][NR];
#pragma unroll
  for (int i = 0; i < MR; ++i)
#pragma unroll
    for (int j = 0; j < NR; ++j) acc[i][j] = (f32x4){0.f, 0.f, 0.f, 0.f};

  s16x8 va[AIT], vb[BIT];
#pragma unroll
  for (int it = 0; it < AIT; ++it) {
    int s = it * 256 + tid, row = s >> 2, ch = s & 3;
    va[it] = *(const s16x8*)(A + (size_t)(bm + row) * K + ch * 8);
  }
#pragma unroll
  for (int it = 0; it < BIT; ++it) {
    int s = it * 256 + tid, row = s >> 2, ch = s & 3;
    vb[it] = *(const s16x8*)(Wt + (size_t)(bn + row) * K + ch * 8);
  }

  for (int k0 = 0; k0 < K; k0 += 32) {
    __syncthreads();  // previous-iteration readers done before overwrite
#pragma unroll
    for (int it = 0; it < AIT; ++it) {
      int s = it * 256 + tid, row = s >> 2, ch = s & 3;
      *(s16x8*)&As[row * 32 + ((ch ^ (row & 3)) * 8)] = va[it];
    }
#pragma unroll
    for (int it = 0; it < BIT; ++it) {
      int s = it * 256 + tid, row = s >> 2, ch = s & 3;
      *(s16x8*)&Bs[row * 32 + ((ch ^ (row & 3)) * 8)] = vb[it];
    }
    if (k0 + 32 < K) {  // prefetch next K-tile into registers
#pragma unroll
      for (int it = 0; it < AIT; ++it) {
        int s = it * 256 + tid, row = s >> 2, ch = s & 3;
        va[it] = *(const s16x8*)(A + (size_t)(bm + row) * K + k0 + 32 + ch * 8);
      }
#pragma unroll
      for (int it = 0; it < BIT; ++it) {
        int s = it * 256 + tid, row = s >> 2, ch = s & 3;
        vb[it] = *(const s16x8*)(Wt + (size_t)(bn + row) * K + k0 + 32 + ch * 8);
      }
    }
    __syncthreads();
    s16x8 ar[MR], br[NR];
#pragma unroll
    for (int i = 0; i < MR; ++i) {
      int row = r0 + i * 16 + li;
      ar[i] = *(const s16x8*)&As[row * 32 + ((g ^ (row & 3)) * 8)];
    }
#pragma unroll
    for (int j = 0; j < NR; ++j) {
      int row = c0 + j * 16 + li;
      br[j] = *(const s16x8*)&Bs[row * 32 + ((g ^ (row & 3)) * 8)];
    }
#pragma unroll
    for (int i = 0; i < MR; ++i)
#pragma unroll
      for (int j = 0; j < NR; ++j) acc[i][j] = mfma_bf16(ar[i], br[j], acc[i][j]);
  }

#pragma unroll
  for (int j = 0; j < NR; ++j) {
    int col = bn + c0 + j * 16 + li;
    float bv = (bias && col < biasN) ? bias[col] : 0.f;
#pragma unroll
    for (int i = 0; i < MR; ++i) {
#pragma unroll
      for (int r = 0; r < 4; ++r) {
        int rowg = bm + r0 + i * 16 + 4 * g + r;
        float v = acc[i][j][r] + bv;
        if (RELU) v = fmaxf(v, 0.f);
        if (OUT == 0) ((float*)Cout)[(size_t)rowg * N + col] = v;
        else          ((u16*)Cout)[(size_t)rowg * N + col] = f2bf(v);
      }
    }
  }
}

// ---------------------------------------------------------------------------
// Weight transpose+convert: f32 [Ks][Ns] -> bf16 [Ns][Ks] at dstOff
// ---------------------------------------------------------------------------
struct WPtrs { const float* p[10]; };

__global__ __launch_bounds__(256) void wcvt(WPtrs wp, u16* __restrict__ dst) {
  constexpr int NE = 20;
  constexpr int srcIdx[NE] = {0,1,0,1,3,3,4,4,5,5,6,6,7,7,2,2,8,8,9,9};
  constexpr int srcOff[NE] = {0,0,262144,262144,0,262144,0,262144,0,262144,
                              0,262144,0,262144,0,262144,0,1048576,0,1048576};
  constexpr int dstOff[NE] = {0,262144,524288,786432,1048576,1310720,
                              1572864,1835008,2097152,2359296,2621440,2883584,
                              3145728,3407872,3670016,3932160,
                              4194304,5242880,6291456,7340032};
  constexpr int KsA[NE] = {512,512,512,512,512,512,512,512,512,512,
                           512,512,512,512,512,512,512,512,2048,2048};
  constexpr int NsA[NE] = {512,512,512,512,512,512,512,512,512,512,
                           512,512,512,512,512,512,2048,2048,512,512};
  constexpr int tileStart[NE] = {0,64,128,192,256,320,384,448,512,576,
                                 640,704,768,832,896,960,1024,1280,1536,1792};
  __shared__ float ts[64 * 65];
  const int tid = threadIdx.x;
  const int bid = blockIdx.x;
  int e = 0;
#pragma unroll
  for (int i = 1; i < NE; ++i) if (bid >= tileStart[i]) e = i;
  const int t = bid - tileStart[e];
  const int Ks_ = KsA[e], Ns_ = NsA[e];
  const int tn = t % (Ns_ >> 6), tk = t / (Ns_ >> 6);
  const float* src = wp.p[srcIdx[e]] + srcOff[e];

  {
    int r = tid >> 2, cb = (tid & 3) * 16;
    const float* sp = src + (size_t)(tk * 64 + r) * Ns_ + tn * 64 + cb;
#pragma unroll
    for (int j = 0; j < 4; ++j) {
      float4 v = ((const float4*)sp)[j];
      float* d = &ts[r * 65 + cb + j * 4];
      d[0] = v.x; d[1] = v.y; d[2] = v.z; d[3] = v.w;
    }
  }
  __syncthreads();
  {
    int n = tid >> 2, kb = (tid & 3) * 16;
    u16* dp = dst + dstOff[e] + (size_t)(tn * 64 + n) * Ks_ + tk * 64 + kb;
    s16x8 o0, o1;
#pragma unroll
    for (int j = 0; j < 8; ++j) o0[j] = (short)f2bf(ts[(kb + j) * 65 + n]);
#pragma unroll
    for (int j = 0; j < 8; ++j) o1[j] = (short)f2bf(ts[(kb + 8 + j) * 65 + n]);
    *(s16x8*)dp = o0;
    *(s16x8*)(dp + 8) = o1;
  }
}

// ---------------------------------------------------------------------------
// activations f32->bf16 (blocks 0..1023); block 1024: relv -> relv^T bf16;
// blocks 1025..1536: rel_ids int32 -> u8 pack (values < 64 fit).
// ---------------------------------------------------------------------------
__global__ __launch_bounds__(256) void acvt(
    const float* __restrict__ q, const float* __restrict__ kv,
    const float* __restrict__ relv, const int* __restrict__ rel,
    u16* __restrict__ obf, u16* __restrict__ kvbf, u16* __restrict__ relvt,
    u8* __restrict__ rel8) {
  int bid = blockIdx.x, tid = threadIdx.x;
  if (bid >= 1025) {
    size_t i = (size_t)(bid - 1025) * 2048 + (size_t)tid * 8;
    int4 a = *(const int4*)(rel + i);
    int4 b = *(const int4*)(rel + i + 4);
    unsigned lo = (unsigned)(a.x & 255) | ((unsigned)(a.y & 255) << 8) |
                  ((unsigned)(a.z & 255) << 16) | ((unsigned)(a.w & 255) << 24);
    unsigned hi = (unsigned)(b.x & 255) | ((unsigned)(b.y & 255) << 8) |
                  ((unsigned)(b.z & 255) << 16) | ((unsigned)(b.w & 255) << 24);
    *(uint2*)(rel8 + i) = make_uint2(lo, hi);
    return;
  }
  if (bid == 1024) {
    int d = tid >> 2, rb = (tid & 3) * 16;
    s16x8 o0, o1;
#pragma unroll
    for (int j = 0; j < 8; ++j) o0[j] = (short)f2bf(relv[(rb + j) * 64 + d]);
#pragma unroll
    for (int j = 0; j < 8; ++j) o1[j] = (short)f2bf(relv[(rb + 8 + j) * 64 + d]);
    *(s16x8*)(relvt + d * 64 + rb) = o0;
    *(s16x8*)(relvt + d * 64 + rb + 8) = o1;
    return;
  }
  int i = bid * 256 + tid;
  const float* src; u16* dst; size_t off;
  if (i < 131072) { src = q; dst = obf; off = (size_t)i * 8; }
  else { src = kv; dst = kvbf; off = (size_t)(i - 131072) * 8; }
  float4 a = *(const float4*)(src + off);
  float4 b = *(const float4*)(src + off + 4);
  s16x8 o;
  o[0] = (short)f2bf(a.x); o[1] = (short)f2bf(a.y);
  o[2] = (short)f2bf(a.z); o[3] = (short)f2bf(a.w);
  o[4] = (short)f2bf(b.x); o[5] = (short)f2bf(b.y);
  o[6] = (short)f2bf(b.z); o[7] = (short)f2bf(b.w);
  *(s16x8*)(dst + off) = o;
}

// ---------------------------------------------------------------------------
// Qr[(row*8+h), r] = sum_d Q[row, h*64+d] * relk[r, d]  (bf16 out)
// ---------------------------------------------------------------------------
__global__ __launch_bounds__(256) void qr_kernel(
    const u16* __restrict__ Q, const float* __restrict__ relk,
    u16* __restrict__ Qr) {
  __shared__ float rk[64 * 65];
  __shared__ float qs[4][64];
  const int tid = threadIdx.x;
  {
    int r = tid >> 2, cb = (tid & 3) * 16;
    const float* sp = relk + r * 64 + cb;
#pragma unroll
    for (int j = 0; j < 4; ++j) {
      float4 v = ((const float4*)sp)[j];
      float* d = &rk[r * 65 + cb + j * 4];
      d[0] = v.x; d[1] = v.y; d[2] = v.z; d[3] = v.w;
    }
  }
  const int sub = tid >> 6, r = tid & 63;
  const int unit = blockIdx.x * 4 + sub;  // unit = row*8 + h
  qs[sub][r] = bf2f(Q[(size_t)(unit >> 3) * 1024 + (unit & 7) * 64 + r]);
  __syncthreads();
  float acc = 0.f;
#pragma unroll
  for (int d = 0; d < 64; ++d) acc += qs[sub][d] * rk[r * 65 + d];
  Qr[(size_t)unit * 64 + r] = f2bf(acc);
}

// ---------------------------------------------------------------------------
// Split-KV attention (flash-decode style), block-level splits, ILP-2:
// both chunks' K+rel loads issue upfront; chunk-1 latency hides under
// chunk-0 compute. Masked cols give p=exp(NEGV-NEGV)=1 while m stays NEGV;
// merge factor f=exp(m_s-m) zeroes garbage exactly / combines uniform sums.
// ---------------------------------------------------------------------------
#define LOADKREL(KF, RF, C8) do {                                              \
    _Pragma("unroll") for (int mt = 0; mt < 4; ++mt) {                         \
      KF[mt * 2 + 0] = *(const s16x8*)(kp + (size_t)(C8) * 65536 + mt * 16384);\
      KF[mt * 2 + 1] = *(const s16x8*)(kp + (size_t)(C8) * 65536 + mt * 16384 + 32); \
      RF[mt] = *(const unsigned*)(rp8 + (C8) * 64 + mt * 16);                  \
    } } while (0)

#define COMPUTE_SELF(KF, RF, C8) do {                                          \
    s16x8 vf[8];                                                               \
    _Pragma("unroll") for (int df = 0; df < 4; ++df) {                         \
      vf[df * 2 + 0] = *(const s16x8*)(vp + (size_t)(C8) * 64 + df * 32768);   \
      vf[df * 2 + 1] = *(const s16x8*)(vp + (size_t)(C8) * 64 + df * 32768 + 32); } \
    f32x4 sf[4];                                                               \
    _Pragma("unroll") for (int mt = 0; mt < 4; ++mt) {                         \
      sf[mt] = (f32x4){0.f, 0.f, 0.f, 0.f};                                    \
      sf[mt] = mfma_bf16(KF[mt * 2 + 0], aq0, sf[mt]);                         \
      sf[mt] = mfma_bf16(KF[mt * 2 + 1], aq1, sf[mt]); }                       \
    float p[4][4];                                                             \
    int rl[4][4];                                                              \
    float pmax = NEGV;                                                         \
    _Pragma("unroll") for (int mt = 0; mt < 4; ++mt) {                         \
      _Pragma("unroll") for (int r = 0; r < 4; ++r) {                          \
        int rel = (int)((RF[mt] >> (8 * r)) & 255u);                           \
        rl[mt][r] = rel;                                                       \
        bool valid = (rel != 0) && ((C8) * 64 + mt * 16 + 4 * g + r <= lrow);  \
        p[mt][r] = valid ? (sf[mt][r] + qrs[li * 66 + rel]) * 0.125f : NEGV;   \
        pmax = fmaxf(pmax, p[mt][r]); } }                                      \
    pmax = fmaxf(pmax, __shfl_xor(pmax, 16));                                  \
    pmax = fmaxf(pmax, __shfl_xor(pmax, 32));                                  \
    if (__any(pmax > mrow + THRV)) {                                           \
      float mnew = (pmax > mrow + THRV) ? pmax : mrow;                         \
      float f = __expf(mrow - mnew);                                           \
      rsum *= f;                                                               \
      _Pragma("unroll") for (int j = 0; j < 8; ++j) {                          \
        float2* p2 = (float2*)&bk[li * 66 + g * 16 + 2 * j];                   \
        float2 v = *p2; v.x *= f; v.y *= f; *p2 = v; }                         \
      _Pragma("unroll") for (int r = 0; r < 4; ++r) {                          \
        float fr = __shfl(f, 4 * g + r);                                       \
        _Pragma("unroll") for (int df = 0; df < 4; ++df) oacc[df][r] *= fr; }  \
      mrow = mnew; }                                                           \
    unsigned pk[4][2];                                                         \
    _Pragma("unroll") for (int mt = 0; mt < 4; ++mt) {                         \
      _Pragma("unroll") for (int r = 0; r < 4; ++r) {                          \
        float pv = __expf(p[mt][r] - mrow);                                    \
        p[mt][r] = pv;                                                         \
        rsum += pv;                                                            \
        if (pv > 0.f) atomicAdd(&bk[li * 66 + rl[mt][r]], pv); }               \
      pk[mt][0] = cvtpk(p[mt][0], p[mt][1]);                                   \
      pk[mt][1] = cvtpk(p[mt][2], p[mt][3]); }                                 \
    _Pragma("unroll") for (int kk = 0; kk < 2; ++kk) {                         \
      union { s16x8 v; unsigned u[4]; } pa;                                    \
      _Pragma("unroll") for (int q = 0; q < 4; ++q) {                          \
        int src = ((2 * (g & 1) + (q >> 1)) << 4) + li;                        \
        unsigned uA = __shfl(pk[2 * kk][q & 1], src);                          \
        unsigned uB = __shfl(pk[2 * kk + 1][q & 1], src);                      \
        pa.u[q] = (g < 2) ? uA : uB; }                                         \
      _Pragma("unroll") for (int df = 0; df < 4; ++df)                         \
        oacc[df] = mfma_bf16(pa.v, vf[df * 2 + kk], oacc[df]); }               \
  } while (0)

__global__ __launch_bounds__(64) void attn_self_part(
    const u16* __restrict__ Qb, const u16* __restrict__ Kb,  // stride 1024
    const u16* __restrict__ VT,                              // [512][2048]
    const u16* __restrict__ Qrb, const u8* __restrict__ rel8,
    const u16* __restrict__ relvt,
    float* __restrict__ po, float2* __restrict__ pms) {
  __shared__ float qrs[16 * 66];
  __shared__ float buck[16 * 66];
  float* bk = buck;

  const int lane = threadIdx.x;
  const int g = lane >> 4, li = lane & 15;
  const int qt = blockIdx.x, h = blockIdx.y;
  const int b = blockIdx.z >> 2, s = blockIdx.z & 3;
  const int lrow = qt * 16 + li;
  const int growq = b * 512 + qt * 16;

  const u16* qp = Qb + (size_t)(growq + li) * 1024 + h * 64;
  s16x8 aq0 = *(const s16x8*)(qp + g * 8);
  s16x8 aq1 = *(const s16x8*)(qp + 32 + g * 8);
  const u16* kp = Kb + (size_t)(b * 512 + li) * 1024 + h * 64 + g * 8;
  const u16* vp = VT + (size_t)(h * 64 + li) * 2048 + b * 512 + g * 8;
  const u8* rp8 = rel8 + (size_t)(growq + li) * 512 + 4 * g;

  {  // stage Qr (bf16 -> f32 LDS) + zero buckets
    int row = lane >> 2, c16 = (lane & 3) * 16;
    const u16* qrp = Qrb + ((size_t)(growq + row) * 8 + h) * 64 + c16;
    s16x8 v0 = *(const s16x8*)qrp;
    s16x8 v1 = *(const s16x8*)(qrp + 8);
#pragma unroll
    for (int j = 0; j < 8; ++j) {
      qrs[row * 66 + c16 + j] = bf2f((u16)v0[j]);
      qrs[row * 66 + c16 + 8 + j] = bf2f((u16)v1[j]);
    }
#pragma unroll
    for (int j = 0; j < 5; ++j) {  // 264 float4s cover 16*66
      int fid = j * 64 + lane;
      if (fid < 264) *(float4*)&buck[fid * 4] = make_float4(0.f, 0.f, 0.f, 0.f);
    }
  }

  float mrow = NEGV, rsum = 0.f;
  f32x4 oacc[4];
#pragma unroll
  for (int d = 0; d < 4; ++d) oacc[d] = (f32x4){0.f, 0.f, 0.f, 0.f};

  // ILP-2: both chunks' K+rel loads issue before any compute
  s16x8 kA[8], kB[8];
  unsigned rA[4], rB[4];
  LOADKREL(kA, rA, 2 * s);
  LOADKREL(kB, rB, 2 * s + 1);
  COMPUTE_SELF(kA, rA, 2 * s);
  COMPUTE_SELF(kB, rB, 2 * s + 1);

  rsum += __shfl_xor(rsum, 16);
  rsum += __shfl_xor(rsum, 32);

  // rel-V fold into partial: oacc += buck @ relv  (B = relv^T)
#pragma unroll
  for (int kk = 0; kk < 2; ++kk) {
    float bb[8];
#pragma unroll
    for (int j = 0; j < 4; ++j) {
      float2 v = *(const float2*)&bk[li * 66 + kk * 32 + g * 8 + 2 * j];
      bb[2 * j] = v.x; bb[2 * j + 1] = v.y;
    }
    union { s16x8 v; unsigned u[4]; } pb;
#pragma unroll
    for (int q = 0; q < 4; ++q) pb.u[q] = cvtpk(bb[2 * q], bb[2 * q + 1]);
#pragma unroll
    for (int df = 0; df < 4; ++df) {
      s16x8 rb = *(const s16x8*)(relvt + (df * 16 + li) * 64 + kk * 32 + g * 8);
      oacc[df] = mfma_bf16(pb.v, rb, oacc[df]);
    }
  }

  const size_t idx = (size_t)(b * 8 + h) * 512 + qt * 16;
#pragma unroll
  for (int df = 0; df < 4; ++df)
#pragma unroll
    for (int r = 0; r < 4; ++r)
      po[((idx + 4 * g + r) * 4 + s) * 64 + df * 16 + li] = oacc[df][r];
  if (lane < 16) pms[(idx + lane) * 4 + s] = make_float2(mrow, rsum);
}

#define LOADK_X(KF, C8) do {                                                   \
    _Pragma("unroll") for (int mt = 0; mt < 4; ++mt) {                         \
      KF[mt * 2 + 0] = *(const s16x8*)(kp + (size_t)(C8) * 65536 + mt * 16384);\
      KF[mt * 2 + 1] = *(const s16x8*)(kp + (size_t)(C8) * 65536 + mt * 16384 + 32); \
    } } while (0)

#define COMPUTE_X(KF, C8) do {                                                 \
    s16x8 vf[8];                                                               \
    _Pragma("unroll") for (int df = 0; df < 4; ++df) {                         \
      vf[df * 2 + 0] = *(const s16x8*)(vp + (size_t)(C8) * 64 + df * 32768);   \
      vf[df * 2 + 1] = *(const s16x8*)(vp + (size_t)(C8) * 64 + df * 32768 + 32); } \
    f32x4 sf[4];                                                               \
    _Pragma("unroll") for (int mt = 0; mt < 4; ++mt) {                         \
      sf[mt] = (f32x4){0.f, 0.f, 0.f, 0.f};                                    \
      sf[mt] = mfma_bf16(KF[mt * 2 + 0], aq0, sf[mt]);                         \
      sf[mt] = mfma_bf16(KF[mt * 2 + 1], aq1, sf[mt]); }                       \
    float p[4][4];                                                             \
    float pmax = NEGV;                                                         \
    _Pragma("unroll") for (int mt = 0; mt < 4; ++mt)                           \
      _Pragma("unroll") for (int r = 0; r < 4; ++r) {                          \
        p[mt][r] = sf[mt][r] * 0.125f;                                         \
        pmax = fmaxf(pmax, p[mt][r]); }                                        \
    pmax = fmaxf(pmax, __shfl_xor(pmax, 16));                                  \
    pmax = fmaxf(pmax, __shfl_xor(pmax, 32));                                  \
    if (__any(pmax > mrow + THRV)) {                                           \
      float mnew = (pmax > mrow + THRV) ? pmax : mrow;                         \
      float f = __expf(mrow - mnew);                                           \
      rsum *= f;                                                               \
      _Pragma("unroll") for (int r = 0; r < 4; ++r) {                          \
        float fr = __shfl(f, 4 * g + r);                                       \
        _Pragma("unroll") for (int df = 0; df < 4; ++df) oacc[df][r] *= fr; }  \
      mrow = mnew; }                                                           \
    unsigned pk[4][2];                                                         \
    _Pragma("unroll") for (int mt = 0; mt < 4; ++mt) {                         \
      _Pragma("unroll") for (int r = 0; r < 4; ++r) {                          \
        float pv = __expf(p[mt][r] - mrow);                                    \
        p[mt][r] = pv;                                                         \
        rsum += pv; }                                                          \
      pk[mt][0] = cvtpk(p[mt][0], p[mt][1]);                                   \
      pk[mt][1] = cvtpk(p[mt][2], p[mt][3]); }                                 \
    _Pragma("unroll") for (int kk = 0; kk < 2; ++kk) {                         \
      union { s16x8 v; unsigned u[4]; } pa;                                    \
      _Pragma("unroll") for (int q = 0; q < 4; ++q) {                          \
        int src = ((2 * (g & 1) + (q >> 1)) << 4) + li;                        \
        unsigned uA = __shfl(pk[2 * kk][q & 1], src);                          \
        unsigned uB = __shfl(pk[2 * kk + 1][q & 1], src);                      \
        pa.u[q] = (g < 2) ? uA : uB; }                                         \
      _Pragma("unroll") for (int df = 0; df < 4; ++df)                         \
        oacc[df] = mfma_bf16(pa.v, vf[df * 2 + kk], oacc[df]); }               \
  } while (0)

__global__ __launch_bounds__(64) void attn_cross_part(
    const u16* __restrict__ Qb,   // stride 512
    const u16* __restrict__ Kb,   // stride 1024
    const u16* __restrict__ VT,   // stride 2048
    float* __restrict__ po, float2* __restrict__ pms) {
  const int lane = threadIdx.x;
  const int g = lane >> 4, li = lane & 15;
  const int qt = blockIdx.x, h = blockIdx.y;
  const int b = blockIdx.z >> 2, s = blockIdx.z & 3;
  const int growq = b * 512 + qt * 16;

  const u16* qp = Qb + (size_t)(growq + li) * 512 + h * 64;
  s16x8 aq0 = *(const s16x8*)(qp + g * 8);
  s16x8 aq1 = *(const s16x8*)(qp + 32 + g * 8);
  const u16* kp = Kb + (size_t)(b * 512 + li) * 1024 + h * 64 + g * 8;
  const u16* vp = VT + (size_t)(h * 64 + li) * 2048 + b * 512 + g * 8;

  float mrow = NEGV, rsum = 0.f;
  f32x4 oacc[4];
#pragma unroll
  for (int d = 0; d < 4; ++d) oacc[d] = (f32x4){0.f, 0.f, 0.f, 0.f};

  s16x8 kA[8], kB[8];
  LOADK_X(kA, 2 * s);
  LOADK_X(kB, 2 * s + 1);
  COMPUTE_X(kA, 2 * s);
  COMPUTE_X(kB, 2 * s + 1);

  rsum += __shfl_xor(rsum, 16);
  rsum += __shfl_xor(rsum, 32);

  const size_t idx = (size_t)(b * 8 + h) * 512 + qt * 16;
#pragma unroll
  for (int df = 0; df < 4; ++df)
#pragma unroll
    for (int r = 0; r < 4; ++r)
      po[((idx + 4 * g + r) * 4 + s) * 64 + df * 16 + li] = oacc[df][r];
  if (lane < 16) pms[(idx + lane) * 4 + s] = make_float2(mrow, rsum);
}

// ---------------------------------------------------------------------------
// Merge 4 split partials per row: m = max m_s, f = exp(m_s - m);
// out = (sum f*oacc_s) / (sum f*rsum_s). 16 rows/block.
// ---------------------------------------------------------------------------
__global__ __launch_bounds__(256) void attn_merge(
    const float* __restrict__ po, const float2* __restrict__ pms,
    u16* __restrict__ att) {
  const int t = threadIdx.x;
  const size_t idx = (size_t)blockIdx.x * 16 + (t >> 4);
  const int d4 = (t & 15) * 4;
  float2 ms[4];
  float m = NEGV;
#pragma unroll
  for (int s = 0; s < 4; ++s) {
    ms[s] = pms[idx * 4 + s];
    m = fmaxf(m, ms[s].x);
  }
  float rs = 0.f;
  float4 o = make_float4(0.f, 0.f, 0.f, 0.f);
#pragma unroll
  for (int s = 0; s < 4; ++s) {
    float f = __expf(ms[s].x - m);
    rs += f * ms[s].y;
    float4 v = *(const float4*)(po + (idx * 4 + s) * 64 + d4);
    o.x += f * v.x; o.y += f * v.y; o.z += f * v.z; o.w += f * v.w;
  }
  const float inv = 1.f / rs;
  const int b = (int)(idx >> 12), h = (int)(idx >> 9) & 7, row = (int)(idx & 511);
  ushort4 ov;
  ov.x = f2bf(o.x * inv);
  ov.y = f2bf(o.y * inv);
  ov.z = f2bf(o.z * inv);
  ov.w = f2bf(o.w * inv);
  *(ushort4*)(att + (size_t)(b * 512 + row) * 512 + h * 64 + d4) = ov;
}

// ---------------------------------------------------------------------------
// out = LayerNorm(x + dlt) * g + b ; also writes bf16 copy
// ---------------------------------------------------------------------------
__global__ __launch_bounds__(256) void ln_res(
    const float* __restrict__ x, const float* __restrict__ dlt,
    const float* __restrict__ g, const float* __restrict__ bta,
    float* __restrict__ out, u16* __restrict__ obf) {
  __shared__ float red_s[256];
  const int row = blockIdx.x, tid = threadIdx.x;
  const size_t base = (size_t)row * Hc;
  float v0 = x[base + tid] + dlt[base + tid];
  float v1 = x[base + tid + 256] + dlt[base + tid + 256];

  red_s[tid] = v0 + v1;
  __syncthreads();
  for (int s = 128; s > 0; s >>= 1) {
    if (tid < s) red_s[tid] += red_s[tid + s];
    __syncthreads();
  }
  const float mean = red_s[0] * (1.f / Hc);
  __syncthreads();
  const float d0 = v0 - mean, d1 = v1 - mean;
  red_s[tid] = d0 * d0 + d1 * d1;
  __syncthreads();
  for (int s = 128; s > 0; s >>= 1) {
    if (tid < s) red_s[tid] += red_s[tid + s];
    __syncthreads();
  }
  const float rstd = rsqrtf(red_s[0] * (1.f / Hc) + EPSV);
  float o0 = d0 * rstd * g[tid] + bta[tid];
  float o1 = d1 * rstd * g[tid + 256] + bta[tid + 256];
  out[base + tid] = o0;
  out[base + tid + 256] = o1;
  obf[base + tid] = f2bf(o0);
  obf[base + tid + 256] = f2bf(o1);
}

// ---------------------------------------------------------------------------
extern "C" void kernel_launch(void* const* d_in, const int* in_sizes, int n_in,
                              void* d_out, int out_size, void* d_ws, size_t ws_size,
                              hipStream_t stream) {
  const float* q    = (const float*)d_in[0];
  const float* kv   = (const float*)d_in[1];
  const float* relk = (const float*)d_in[2];
  const float* relv = (const float*)d_in[3];
  const float* Wq_s = (const float*)d_in[4];
  const float* bq_s = (const float*)d_in[5];
  const float* Wk_s = (const float*)d_in[6];
  const float* Wv_s = (const float*)d_in[7];
  const float* Wo_s = (const float*)d_in[8];
  const float* bo_s = (const float*)d_in[9];
  const float* ln1g = (const float*)d_in[10];
  const float* ln1b = (const float*)d_in[11];
  const float* Wq_c = (const float*)d_in[12];
  const float* bq_c = (const float*)d_in[13];
  const float* Wk_c = (const float*)d_in[14];
  const float* Wv_c = (const float*)d_in[15];
  const float* Wo_c = (const float*)d_in[16];
  const float* bo_c = (const float*)d_in[17];
  const float* ln2g = (const float*)d_in[18];
  const float* ln2b = (const float*)d_in[19];
  const float* W1   = (const float*)d_in[20];
  const float* b1   = (const float*)d_in[21];
  const float* W2   = (const float*)d_in[22];
  const float* b2   = (const float*)d_in[23];
  const float* ln3g = (const float*)d_in[24];
  const float* ln3b = (const float*)d_in[25];
  const int*   rel  = (const int*)d_in[26];

  char* wsb = (char*)d_ws;
  const size_t NT = (size_t)Bc * Tc;  // 2048 token rows
  float* o     = (float*)wsb;  wsb += NT * Hc * 4;       // 4MB
  float* bDlt  = (float*)wsb;  wsb += NT * Hc * 4;       // 4MB
  u16* Qr      = (u16*)wsb;    wsb += NT * 8 * 64 * 2;   // 2MB (bf16)
  u16* obf     = (u16*)wsb;    wsb += NT * Hc * 2;       // 2MB
  u16* kvbf    = (u16*)wsb;    wsb += NT * Hc * 2;       // 2MB
  u16* bQK     = (u16*)wsb;    wsb += NT * 1024 * 2;     // 4MB
  u16* bVt     = (u16*)wsb;    wsb += (size_t)512 * 2048 * 2;   // 2MB
  u16* bQc     = (u16*)wsb;    wsb += NT * Hc * 2;       // 2MB
  u16* bKc     = (u16*)wsb;    wsb += NT * 1024 * 2;     // 4MB
  u16* bVtc    = (u16*)wsb;    wsb += (size_t)1024 * 2048 * 2;  // 4MB
  u16* bAtt    = (u16*)wsb;    wsb += NT * Hc * 2;       // 2MB
  u16* bH      = (u16*)wsb;    wsb += NT * FFc * 2;      // 8MB
  u16* relvt   = (u16*)wsb;    wsb += 64 * 64 * 2;       // 8KB
  u8* rel8     = (u8*)wsb;     wsb += (size_t)NT * 512;  // 1MB
  u16* wbuf    = (u16*)wsb;    wsb += (size_t)8388608 * 2;  // 16MB
  float* po    = (float*)wsb;  wsb += (size_t)16384 * 4 * 64 * 4;  // 16MB
  float2* pms  = (float2*)wsb; wsb += (size_t)16384 * 4 * 8;       // 512KB

  WPtrs wp;
  wp.p[0] = Wq_s; wp.p[1] = Wk_s; wp.p[2] = Wv_s; wp.p[3] = Wo_s;
  wp.p[4] = Wq_c; wp.p[5] = Wk_c; wp.p[6] = Wv_c; wp.p[7] = Wo_c;
  wp.p[8] = W1;   wp.p[9] = W2;

  dim3 blk(256);
  wcvt<<<dim3(2048), blk, 0, stream>>>(wp, wbuf);
  acvt<<<dim3(1537), blk, 0, stream>>>(q, kv, relv, rel, obf, kvbf, relvt, rel8);
  hipMemcpyAsync(o, q, NT * Hc * 4, hipMemcpyDeviceToDevice, stream);

  // cross K (both layers) and cross V^T (both layers)
  gemm_mfma<64, 128, false, 1><<<dim3(8, 32), blk, 0, stream>>>(
      kvbf, wbuf + 2097152, nullptr, 0, bKc, 1024, 512);
  gemm_mfma<64, 128, false, 1><<<dim3(16, 16), blk, 0, stream>>>(
      wbuf + 2621440, kvbf, nullptr, 0, bVtc, 2048, 512);

  const dim3 gLN(NT);
  const dim3 gPART(32, 8, 16);
  const dim3 gMERGE(1024);
  for (int i = 0; i < NLc; ++i) {
    // --- relation-aware masked self-attention ---
    gemm_mfma<64, 128, false, 1><<<dim3(8, 32), blk, 0, stream>>>(
        obf, wbuf + (size_t)i * 524288, bq_s + i * Hc, Hc, bQK, 1024, 512);
    gemm_mfma<64, 64, false, 1><<<dim3(32, 8), blk, 0, stream>>>(
        wbuf + 3670016 + (size_t)i * 262144, obf, nullptr, 0, bVt, 2048, 512);
    qr_kernel<<<dim3(4096), blk, 0, stream>>>(bQK, relk, Qr);
    attn_self_part<<<gPART, dim3(64), 0, stream>>>(
        bQK, bQK + 512, bVt, Qr, rel8, relvt, po, pms);
    attn_merge<<<gMERGE, blk, 0, stream>>>(po, pms, bAtt);
    gemm_mfma<64, 64, false, 0><<<dim3(8, 32), blk, 0, stream>>>(
        bAtt, wbuf + 1048576 + (size_t)i * 262144, bo_s + i * Hc, Hc, bDlt, Hc, 512);
    ln_res<<<gLN, blk, 0, stream>>>(o, bDlt, ln1g + i * Hc, ln1b + i * Hc, o, obf);

    // --- cross-attention ---
    gemm_mfma<64, 64, false, 1><<<dim3(8, 32), blk, 0, stream>>>(
        obf, wbuf + 1572864 + (size_t)i * 262144, bq_c + i * Hc, Hc, bQc, Hc, 512);
    attn_cross_part<<<gPART, dim3(64), 0, stream>>>(
        bQc, bKc + i * 512, bVtc + (size_t)i * 512 * 2048, po, pms);
    attn_merge<<<gMERGE, blk, 0, stream>>>(po, pms, bAtt);
    gemm_mfma<64, 64, false, 0><<<dim3(8, 32), blk, 0, stream>>>(
        bAtt, wbuf + 3145728 + (size_t)i * 262144, bo_c + i * Hc, Hc, bDlt, Hc, 512);
    ln_res<<<gLN, blk, 0, stream>>>(o, bDlt, ln2g + i * Hc, ln2b + i * Hc, o, obf);

    // --- feedforward ---
    gemm_mfma<64, 128, true, 1><<<dim3(16, 32), blk, 0, stream>>>(
        obf, wbuf + 4194304 + (size_t)i * 1048576, b1 + i * FFc, FFc, bH, FFc, 512);
    gemm_mfma<64, 64, false, 0><<<dim3(8, 32), blk, 0, stream>>>(
        bH, wbuf + 6291456 + (size_t)i * 1048576, b2 + i * Hc, Hc, bDlt, Hc, 2048);
    float* lnout = (i == NLc - 1) ? (float*)d_out : o;
    ln_res<<<gLN, blk, 0, stream>>>(o, bDlt, ln3g + i * Hc, ln3b + i * Hc, lnout, obf);
  }
}

// Round 10
// 382.506 us; speedup vs baseline: 1.4276x; 1.0181x over previous
//
#include <hip/hip_runtime.h>

static constexpr int Hc  = 512;
static constexpr int NHc = 8;
static constexpr int DHc = 64;
static constexpr int NLc = 2;
static constexpr int Rc  = 64;
static constexpr int FFc = 2048;
static constexpr int Bc  = 4;
static constexpr int Tc  = 512;
#define NEGV (-1e10f)
#define EPSV 1e-5f
#define THRV 6.0f

typedef unsigned short u16;
typedef unsigned char u8;
typedef __attribute__((ext_vector_type(8))) short s16x8;
typedef __attribute__((ext_vector_type(4))) float f32x4;

__device__ __forceinline__ f32x4 mfma_bf16(s16x8 a, s16x8 b, f32x4 c) {
  return __builtin_amdgcn_mfma_f32_16x16x32_bf16(a, b, c, 0, 0, 0);
}
__device__ __forceinline__ u16 f2bf(float f) {
  union { float f; unsigned u; } x; x.f = f;
  unsigned r = (x.u + 0x7FFFu + ((x.u >> 16) & 1u)) >> 16;
  return (u16)r;
}
__device__ __forceinline__ float bf2f(u16 h) {
  union { unsigned u; float f; } x; x.u = ((unsigned)h) << 16;
  return x.f;
}
__device__ __forceinline__ unsigned cvtpk(float a, float b) {
  unsigned r;
  asm("v_cvt_pk_bf16_f32 %0, %1, %2" : "=v"(r) : "v"(a), "v"(b));
  return r;
}

// ---------------------------------------------------------------------------
// bf16 MFMA GEMM: C[M,N] = A[M,K] @ Wt[N,K]^T (+bias for col<biasN) (+relu)
// Register double-buffer: tile k+1 global loads issue right after tile k's
// LDS store, hiding HBM/L2 latency under the MFMA phase.
// ---------------------------------------------------------------------------
template <int BM, int BN, bool RELU, int OUT>  // OUT: 0=f32, 1=bf16
__global__ __launch_bounds__(256) void gemm_mfma(
    const u16* __restrict__ A, const u16* __restrict__ Wt,
    const float* __restrict__ bias, int biasN,
    void* __restrict__ Cout, int N, int K) {
  __shared__ u16 As[BM * 32];
  __shared__ u16 Bs[BN * 32];
  const int tid = threadIdx.x;
  const int w = tid >> 6, lane = tid & 63, g = lane >> 4, li = lane & 15;
  const int bn = blockIdx.x * BN, bm = blockIdx.y * BM;
  const int r0 = (w & 1) * (BM / 2), c0 = (w >> 1) * (BN / 2);
  constexpr int MR = BM / 32, NR = BN / 32;
  constexpr int AIT = BM / 64, BIT = BN / 64;
  f32x4 acc[MR][NR];
#pragma unroll
  for (int i = 0; i < MR; ++i)
#pragma unroll
    for (int j = 0; j < NR; ++j) acc[i][j] = (f32x4){0.f, 0.f, 0.f, 0.f};

  s16x8 va[AIT], vb[BIT];
#pragma unroll
  for (int it = 0; it < AIT; ++it) {
    int s = it * 256 + tid, row = s >> 2, ch = s & 3;
    va[it] = *(const s16x8*)(A + (size_t)(bm + row) * K + ch * 8);
  }
#pragma unroll
  for (int it = 0; it < BIT; ++it) {
    int s = it * 256 + tid, row = s >> 2, ch = s & 3;
    vb[it] = *(const s16x8*)(Wt + (size_t)(bn + row) * K + ch * 8);
  }

  for (int k0 = 0; k0 < K; k0 += 32) {
    __syncthreads();  // previous-iteration readers done before overwrite
#pragma unroll
    for (int it = 0; it < AIT; ++it) {
      int s = it * 256 + tid, row = s >> 2, ch = s & 3;
      *(s16x8*)&As[row * 32 + ((ch ^ (row & 3)) * 8)] = va[it];
    }
#pragma unroll
    for (int it = 0; it < BIT; ++it) {
      int s = it * 256 + tid, row = s >> 2, ch = s & 3;
      *(s16x8*)&Bs[row * 32 + ((ch ^ (row & 3)) * 8)] = vb[it];
    }
    if (k0 + 32 < K) {  // prefetch next K-tile into registers
#pragma unroll
      for (int it = 0; it < AIT; ++it) {
        int s = it * 256 + tid, row = s >> 2, ch = s & 3;
        va[it] = *(const s16x8*)(A + (size_t)(bm + row) * K + k0 + 32 + ch * 8);
      }
#pragma unroll
      for (int it = 0; it < BIT; ++it) {
        int s = it * 256 + tid, row = s >> 2, ch = s & 3;
        vb[it] = *(const s16x8*)(Wt + (size_t)(bn + row) * K + k0 + 32 + ch * 8);
      }
    }
    __syncthreads();
    s16x8 ar[MR], br[NR];
#pragma unroll
    for (int i = 0; i < MR; ++i) {
      int row = r0 + i * 16 + li;
      ar[i] = *(const s16x8*)&As[row * 32 + ((g ^ (row & 3)) * 8)];
    }
#pragma unroll
    for (int j = 0; j < NR; ++j) {
      int row = c0 + j * 16 + li;
      br[j] = *(const s16x8*)&Bs[row * 32 + ((g ^ (row & 3)) * 8)];
    }
#pragma unroll
    for (int i = 0; i < MR; ++i)
#pragma unroll
      for (int j = 0; j < NR; ++j) acc[i][j] = mfma_bf16(ar[i], br[j], acc[i][j]);
  }

#pragma unroll
  for (int j = 0; j < NR; ++j) {
    int col = bn + c0 + j * 16 + li;
    float bv = (bias && col < biasN) ? bias[col] : 0.f;
#pragma unroll
    for (int i = 0; i < MR; ++i) {
#pragma unroll
      for (int r = 0; r < 4; ++r) {
        int rowg = bm + r0 + i * 16 + 4 * g + r;
        float v = acc[i][j][r] + bv;
        if (RELU) v = fmaxf(v, 0.f);
        if (OUT == 0) ((float*)Cout)[(size_t)rowg * N + col] = v;
        else          ((u16*)Cout)[(size_t)rowg * N + col] = f2bf(v);
      }
    }
  }
}

// ---------------------------------------------------------------------------
// Weight transpose+convert: f32 [Ks][Ns] -> bf16 [Ns][Ks] at dstOff
// ---------------------------------------------------------------------------
struct WPtrs { const float* p[10]; };

__global__ __launch_bounds__(256) void wcvt(WPtrs wp, u16* __restrict__ dst) {
  constexpr int NE = 20;
  constexpr int srcIdx[NE] = {0,1,0,1,3,3,4,4,5,5,6,6,7,7,2,2,8,8,9,9};
  constexpr int srcOff[NE] = {0,0,262144,262144,0,262144,0,262144,0,262144,
                              0,262144,0,262144,0,262144,0,1048576,0,1048576};
  constexpr int dstOff[NE] = {0,262144,524288,786432,1048576,1310720,
                              1572864,1835008,2097152,2359296,2621440,2883584,
                              3145728,3407872,3670016,3932160,
                              4194304,5242880,6291456,7340032};
  constexpr int KsA[NE] = {512,512,512,512,512,512,512,512,512,512,
                           512,512,512,512,512,512,512,512,2048,2048};
  constexpr int NsA[NE] = {512,512,512,512,512,512,512,512,512,512,
                           512,512,512,512,512,512,2048,2048,512,512};
  constexpr int tileStart[NE] = {0,64,128,192,256,320,384,448,512,576,
                                 640,704,768,832,896,960,1024,1280,1536,1792};
  __shared__ float ts[64 * 65];
  const int tid = threadIdx.x;
  const int bid = blockIdx.x;
  int e = 0;
#pragma unroll
  for (int i = 1; i < NE; ++i) if (bid >= tileStart[i]) e = i;
  const int t = bid - tileStart[e];
  const int Ks_ = KsA[e], Ns_ = NsA[e];
  const int tn = t % (Ns_ >> 6), tk = t / (Ns_ >> 6);
  const float* src = wp.p[srcIdx[e]] + srcOff[e];

  {
    int r = tid >> 2, cb = (tid & 3) * 16;
    const float* sp = src + (size_t)(tk * 64 + r) * Ns_ + tn * 64 + cb;
#pragma unroll
    for (int j = 0; j < 4; ++j) {
      float4 v = ((const float4*)sp)[j];
      float* d = &ts[r * 65 + cb + j * 4];
      d[0] = v.x; d[1] = v.y; d[2] = v.z; d[3] = v.w;
    }
  }
  __syncthreads();
  {
    int n = tid >> 2, kb = (tid & 3) * 16;
    u16* dp = dst + dstOff[e] + (size_t)(tn * 64 + n) * Ks_ + tk * 64 + kb;
    s16x8 o0, o1;
#pragma unroll
    for (int j = 0; j < 8; ++j) o0[j] = (short)f2bf(ts[(kb + j) * 65 + n]);
#pragma unroll
    for (int j = 0; j < 8; ++j) o1[j] = (short)f2bf(ts[(kb + 8 + j) * 65 + n]);
    *(s16x8*)dp = o0;
    *(s16x8*)(dp + 8) = o1;
  }
}

// ---------------------------------------------------------------------------
// activations f32->bf16 (blocks 0..1023); block 1024: relv -> relv^T bf16;
// blocks 1025..1536: rel_ids int32 -> u8 pack (values < 64 fit).
// ---------------------------------------------------------------------------
__global__ __launch_bounds__(256) void acvt(
    const float* __restrict__ q, const float* __restrict__ kv,
    const float* __restrict__ relv, const int* __restrict__ rel,
    u16* __restrict__ obf, u16* __restrict__ kvbf, u16* __restrict__ relvt,
    u8* __restrict__ rel8) {
  int bid = blockIdx.x, tid = threadIdx.x;
  if (bid >= 1025) {
    size_t i = (size_t)(bid - 1025) * 2048 + (size_t)tid * 8;
    int4 a = *(const int4*)(rel + i);
    int4 b = *(const int4*)(rel + i + 4);
    unsigned lo = (unsigned)(a.x & 255) | ((unsigned)(a.y & 255) << 8) |
                  ((unsigned)(a.z & 255) << 16) | ((unsigned)(a.w & 255) << 24);
    unsigned hi = (unsigned)(b.x & 255) | ((unsigned)(b.y & 255) << 8) |
                  ((unsigned)(b.z & 255) << 16) | ((unsigned)(b.w & 255) << 24);
    *(uint2*)(rel8 + i) = make_uint2(lo, hi);
    return;
  }
  if (bid == 1024) {
    int d = tid >> 2, rb = (tid & 3) * 16;
    s16x8 o0, o1;
#pragma unroll
    for (int j = 0; j < 8; ++j) o0[j] = (short)f2bf(relv[(rb + j) * 64 + d]);
#pragma unroll
    for (int j = 0; j < 8; ++j) o1[j] = (short)f2bf(relv[(rb + 8 + j) * 64 + d]);
    *(s16x8*)(relvt + d * 64 + rb) = o0;
    *(s16x8*)(relvt + d * 64 + rb + 8) = o1;
    return;
  }
  int i = bid * 256 + tid;
  const float* src; u16* dst; size_t off;
  if (i < 131072) { src = q; dst = obf; off = (size_t)i * 8; }
  else { src = kv; dst = kvbf; off = (size_t)(i - 131072) * 8; }
  float4 a = *(const float4*)(src + off);
  float4 b = *(const float4*)(src + off + 4);
  s16x8 o;
  o[0] = (short)f2bf(a.x); o[1] = (short)f2bf(a.y);
  o[2] = (short)f2bf(a.z); o[3] = (short)f2bf(a.w);
  o[4] = (short)f2bf(b.x); o[5] = (short)f2bf(b.y);
  o[6] = (short)f2bf(b.z); o[7] = (short)f2bf(b.w);
  *(s16x8*)(dst + off) = o;
}

// ---------------------------------------------------------------------------
// Qr[(row*8+h), r] = sum_d Q[row, h*64+d] * relk[r, d]  (bf16 out)
// ---------------------------------------------------------------------------
__global__ __launch_bounds__(256) void qr_kernel(
    const u16* __restrict__ Q, const float* __restrict__ relk,
    u16* __restrict__ Qr) {
  __shared__ float rk[64 * 65];
  __shared__ float qs[4][64];
  const int tid = threadIdx.x;
  {
    int r = tid >> 2, cb = (tid & 3) * 16;
    const float* sp = relk + r * 64 + cb;
#pragma unroll
    for (int j = 0; j < 4; ++j) {
      float4 v = ((const float4*)sp)[j];
      float* d = &rk[r * 65 + cb + j * 4];
      d[0] = v.x; d[1] = v.y; d[2] = v.z; d[3] = v.w;
    }
  }
  const int sub = tid >> 6, r = tid & 63;
  const int unit = blockIdx.x * 4 + sub;  // unit = row*8 + h
  qs[sub][r] = bf2f(Q[(size_t)(unit >> 3) * 1024 + (unit & 7) * 64 + r]);
  __syncthreads();
  float acc = 0.f;
#pragma unroll
  for (int d = 0; d < 64; ++d) acc += qs[sub][d] * rk[r * 65 + d];
  Qr[(size_t)unit * 64 + r] = f2bf(acc);
}

// ---------------------------------------------------------------------------
// Fragment pack: rewrite K (token-major, stride kstride) and V^T (d-major,
// stride vstride) into MFMA-fragment order so attention loads are
// lane-contiguous 1KB wave transactions:
//   Kf[(b*8+h)*8+c8][mt*2+kk][lane][8] = K[b*512+c8*64+mt*16+li][h*64+kk*32+g*8..]
//   Vf[(b*8+h)*8+c8][df*2+kk][lane][8] = V^T[h*64+df*16+li][b*512+c8*64+kk*32+g*8..]
// Grid (8 c8, 8 h, 4 b) x 128 thr. Scattered reads paid ONCE (vs 32x in attn).
// ---------------------------------------------------------------------------
__global__ __launch_bounds__(128) void pack_frags(
    const u16* __restrict__ Kin, int kstride,
    const u16* __restrict__ VTin, int vstride,
    u16* __restrict__ Kf, u16* __restrict__ Vf) {
  const int t = threadIdx.x;
  const int c8 = blockIdx.x, h = blockIdx.y, b = blockIdx.z;
  u16* kdst = Kf + (size_t)((b * 8 + h) * 8 + c8) * 4096;
  u16* vdst = Vf + (size_t)((b * 8 + h) * 8 + c8) * 4096;
#pragma unroll
  for (int i = 0; i < 4; ++i) {
    int s = i * 128 + t;
    int mt = s >> 7, kk = (s >> 6) & 1, lane = s & 63;
    int g = lane >> 4, li = lane & 15;
    s16x8 kv = *(const s16x8*)(
        Kin + (size_t)(b * 512 + c8 * 64 + mt * 16 + li) * kstride +
        h * 64 + kk * 32 + g * 8);
    s16x8 vv = *(const s16x8*)(
        VTin + (size_t)(h * 64 + mt * 16 + li) * vstride +
        b * 512 + c8 * 64 + kk * 32 + g * 8);
    *(s16x8*)(kdst + (mt * 2 + kk) * 512 + lane * 8) = kv;
    *(s16x8*)(vdst + (mt * 2 + kk) * 512 + lane * 8) = vv;
  }
}

// ---------------------------------------------------------------------------
// Split-KV attention (flash-decode style), block-level splits, ILP-2,
// fragment-packed K/V (all loads lane-contiguous). Masked cols give
// p=exp(NEGV-NEGV)=1 while m stays NEGV; merge factor f=exp(m_s-m) zeroes
// garbage partials exactly / combines uniform sums.
// ---------------------------------------------------------------------------
#define LOADKREL(KF, RF, C8) do {                                              \
    _Pragma("unroll") for (int mt = 0; mt < 4; ++mt) {                         \
      KF[mt * 2 + 0] = *(const s16x8*)(kfb + (size_t)(C8) * 4096 + (mt * 2 + 0) * 512 + lane * 8); \
      KF[mt * 2 + 1] = *(const s16x8*)(kfb + (size_t)(C8) * 4096 + (mt * 2 + 1) * 512 + lane * 8); \
      RF[mt] = *(const unsigned*)(rp8 + (C8) * 64 + mt * 16);                  \
    } } while (0)

#define COMPUTE_SELF(KF, RF, C8) do {                                          \
    s16x8 vf[8];                                                               \
    _Pragma("unroll") for (int df = 0; df < 4; ++df) {                         \
      vf[df * 2 + 0] = *(const s16x8*)(vfb + (size_t)(C8) * 4096 + (df * 2 + 0) * 512 + lane * 8); \
      vf[df * 2 + 1] = *(const s16x8*)(vfb + (size_t)(C8) * 4096 + (df * 2 + 1) * 512 + lane * 8); } \
    f32x4 sf[4];                                                               \
    _Pragma("unroll") for (int mt = 0; mt < 4; ++mt) {                         \
      sf[mt] = (f32x4){0.f, 0.f, 0.f, 0.f};                                    \
      sf[mt] = mfma_bf16(KF[mt * 2 + 0], aq0, sf[mt]);                         \
      sf[mt] = mfma_bf16(KF[mt * 2 + 1], aq1, sf[mt]); }                       \
    float p[4][4];                                                             \
    int rl[4][4];                                                              \
    float pmax = NEGV;                                                         \
    _Pragma("unroll") for (int mt = 0; mt < 4; ++mt) {                         \
      _Pragma("unroll") for (int r = 0; r < 4; ++r) {                          \
        int rel = (int)((RF[mt] >> (8 * r)) & 255u);                           \
        rl[mt][r] = rel;                                                       \
        bool valid = (rel != 0) && ((C8) * 64 + mt * 16 + 4 * g + r <= lrow);  \
        p[mt][r] = valid ? (sf[mt][r] + qrs[li * 66 + rel]) * 0.125f : NEGV;   \
        pmax = fmaxf(pmax, p[mt][r]); } }                                      \
    pmax = fmaxf(pmax, __shfl_xor(pmax, 16));                                  \
    pmax = fmaxf(pmax, __shfl_xor(pmax, 32));                                  \
    if (__any(pmax > mrow + THRV)) {                                           \
      float mnew = (pmax > mrow + THRV) ? pmax : mrow;                         \
      float f = __expf(mrow - mnew);                                           \
      rsum *= f;                                                               \
      _Pragma("unroll") for (int j = 0; j < 8; ++j) {                          \
        float2* p2 = (float2*)&bk[li * 66 + g * 16 + 2 * j];                   \
        float2 v = *p2; v.x *= f; v.y *= f; *p2 = v; }                         \
      _Pragma("unroll") for (int r = 0; r < 4; ++r) {                          \
        float fr = __shfl(f, 4 * g + r);                                       \
        _Pragma("unroll") for (int df = 0; df < 4; ++df) oacc[df][r] *= fr; }  \
      mrow = mnew; }                                                           \
    unsigned pk[4][2];                                                         \
    _Pragma("unroll") for (int mt = 0; mt < 4; ++mt) {                         \
      _Pragma("unroll") for (int r = 0; r < 4; ++r) {                          \
        float pv = __expf(p[mt][r] - mrow);                                    \
        p[mt][r] = pv;                                                         \
        rsum += pv;                                                            \
        if (pv > 0.f) atomicAdd(&bk[li * 66 + rl[mt][r]], pv); }               \
      pk[mt][0] = cvtpk(p[mt][0], p[mt][1]);                                   \
      pk[mt][1] = cvtpk(p[mt][2], p[mt][3]); }                                 \
    _Pragma("unroll") for (int kk = 0; kk < 2; ++kk) {                         \
      union { s16x8 v; unsigned u[4]; } pa;                                    \
      _Pragma("unroll") for (int q = 0; q < 4; ++q) {                          \
        int src = ((2 * (g & 1) + (q >> 1)) << 4) + li;                        \
        unsigned uA = __shfl(pk[2 * kk][q & 1], src);                          \
        unsigned uB = __shfl(pk[2 * kk + 1][q & 1], src);                      \
        pa.u[q] = (g < 2) ? uA : uB; }                                         \
      _Pragma("unroll") for (int df = 0; df < 4; ++df)                         \
        oacc[df] = mfma_bf16(pa.v, vf[df * 2 + kk], oacc[df]); }               \
  } while (0)

__global__ __launch_bounds__(64) void attn_self_part(
    const u16* __restrict__ Qb,                              // stride 1024
    const u16* __restrict__ Kf, const u16* __restrict__ Vf,  // frag-packed
    const u16* __restrict__ Qrb, const u8* __restrict__ rel8,
    const u16* __restrict__ relvt,
    float* __restrict__ po, float2* __restrict__ pms) {
  __shared__ float qrs[16 * 66];
  __shared__ float buck[16 * 66];
  float* bk = buck;

  const int lane = threadIdx.x;
  const int g = lane >> 4, li = lane & 15;
  const int qt = blockIdx.x, h = blockIdx.y;
  const int b = blockIdx.z >> 2, s = blockIdx.z & 3;
  const int lrow = qt * 16 + li;
  const int growq = b * 512 + qt * 16;

  const u16* qp = Qb + (size_t)(growq + li) * 1024 + h * 64;
  s16x8 aq0 = *(const s16x8*)(qp + g * 8);
  s16x8 aq1 = *(const s16x8*)(qp + 32 + g * 8);
  const u16* kfb = Kf + (size_t)((b * 8 + h) * 8) * 4096;
  const u16* vfb = Vf + (size_t)((b * 8 + h) * 8) * 4096;
  const u8* rp8 = rel8 + (size_t)(growq + li) * 512 + 4 * g;

  {  // stage Qr (bf16 -> f32 LDS) + zero buckets
    int row = lane >> 2, c16 = (lane & 3) * 16;
    const u16* qrp = Qrb + ((size_t)(growq + row) * 8 + h) * 64 + c16;
    s16x8 v0 = *(const s16x8*)qrp;
    s16x8 v1 = *(const s16x8*)(qrp + 8);
#pragma unroll
    for (int j = 0; j < 8; ++j) {
      qrs[row * 66 + c16 + j] = bf2f((u16)v0[j]);
      qrs[row * 66 + c16 + 8 + j] = bf2f((u16)v1[j]);
    }
#pragma unroll
    for (int j = 0; j < 5; ++j) {  // 264 float4s cover 16*66
      int fid = j * 64 + lane;
      if (fid < 264) *(float4*)&buck[fid * 4] = make_float4(0.f, 0.f, 0.f, 0.f);
    }
  }

  float mrow = NEGV, rsum = 0.f;
  f32x4 oacc[4];
#pragma unroll
  for (int d = 0; d < 4; ++d) oacc[d] = (f32x4){0.f, 0.f, 0.f, 0.f};

  // ILP-2: both chunks' K+rel loads issue before any compute
  s16x8 kA[8], kB[8];
  unsigned rA[4], rB[4];
  LOADKREL(kA, rA, 2 * s);
  LOADKREL(kB, rB, 2 * s + 1);
  COMPUTE_SELF(kA, rA, 2 * s);
  COMPUTE_SELF(kB, rB, 2 * s + 1);

  rsum += __shfl_xor(rsum, 16);
  rsum += __shfl_xor(rsum, 32);

  // rel-V fold into partial: oacc += buck @ relv  (B = relv^T)
#pragma unroll
  for (int kk = 0; kk < 2; ++kk) {
    float bb[8];
#pragma unroll
    for (int j = 0; j < 4; ++j) {
      float2 v = *(const float2*)&bk[li * 66 + kk * 32 + g * 8 + 2 * j];
      bb[2 * j] = v.x; bb[2 * j + 1] = v.y;
    }
    union { s16x8 v; unsigned u[4]; } pb;
#pragma unroll
    for (int q = 0; q < 4; ++q) pb.u[q] = cvtpk(bb[2 * q], bb[2 * q + 1]);
#pragma unroll
    for (int df = 0; df < 4; ++df) {
      s16x8 rb = *(const s16x8*)(relvt + (df * 16 + li) * 64 + kk * 32 + g * 8);
      oacc[df] = mfma_bf16(pb.v, rb, oacc[df]);
    }
  }

  const size_t idx = (size_t)(b * 8 + h) * 512 + qt * 16;
#pragma unroll
  for (int df = 0; df < 4; ++df)
#pragma unroll
    for (int r = 0; r < 4; ++r)
      po[((idx + 4 * g + r) * 4 + s) * 64 + df * 16 + li] = oacc[df][r];
  if (lane < 16) pms[(idx + lane) * 4 + s] = make_float2(mrow, rsum);
}

#define LOADK_X(KF, C8) do {                                                   \
    _Pragma("unroll") for (int mt = 0; mt < 4; ++mt) {                         \
      KF[mt * 2 + 0] = *(const s16x8*)(kfb + (size_t)(C8) * 4096 + (mt * 2 + 0) * 512 + lane * 8); \
      KF[mt * 2 + 1] = *(const s16x8*)(kfb + (size_t)(C8) * 4096 + (mt * 2 + 1) * 512 + lane * 8); \
    } } while (0)

#define COMPUTE_X(KF, C8) do {                                                 \
    s16x8 vf[8];                                                               \
    _Pragma("unroll") for (int df = 0; df < 4; ++df) {                         \
      vf[df * 2 + 0] = *(const s16x8*)(vfb + (size_t)(C8) * 4096 + (df * 2 + 0) * 512 + lane * 8); \
      vf[df * 2 + 1] = *(const s16x8*)(vfb + (size_t)(C8) * 4096 + (df * 2 + 1) * 512 + lane * 8); } \
    f32x4 sf[4];                                                               \
    _Pragma("unroll") for (int mt = 0; mt < 4; ++mt) {                         \
      sf[mt] = (f32x4){0.f, 0.f, 0.f, 0.f};                                    \
      sf[mt] = mfma_bf16(KF[mt * 2 + 0], aq0, sf[mt]);                         \
      sf[mt] = mfma_bf16(KF[mt * 2 + 1], aq1, sf[mt]); }                       \
    float p[4][4];                                                             \
    float pmax = NEGV;                                                         \
    _Pragma("unroll") for (int mt = 0; mt < 4; ++mt)                           \
      _Pragma("unroll") for (int r = 0; r < 4; ++r) {                          \
        p[mt][r] = sf[mt][r] * 0.125f;                                         \
        pmax = fmaxf(pmax, p[mt][r]); }                                        \
    pmax = fmaxf(pmax, __shfl_xor(pmax, 16));                                  \
    pmax = fmaxf(pmax, __shfl_xor(pmax, 32));                                  \
    if (__any(pmax > mrow + THRV)) {                                           \
      float mnew = (pmax > mrow + THRV) ? pmax : mrow;                         \
      float f = __expf(mrow - mnew);                                           \
      rsum *= f;                                                               \
      _Pragma("unroll") for (int r = 0; r < 4; ++r) {                          \
        float fr = __shfl(f, 4 * g + r);                                       \
        _Pragma("unroll") for (int df = 0; df < 4; ++df) oacc[df][r] *= fr; }  \
      mrow = mnew; }                                                           \
    unsigned pk[4][2];                                                         \
    _Pragma("unroll") for (int mt = 0; mt < 4; ++mt) {                         \
      _Pragma("unroll") for (int r = 0; r < 4; ++r) {                          \
        float pv = __expf(p[mt][r] - mrow);                                    \
        p[mt][r] = pv;                                                         \
        rsum += pv; }                                                          \
      pk[mt][0] = cvtpk(p[mt][0], p[mt][1]);                                   \
      pk[mt][1] = cvtpk(p[mt][2], p[mt][3]); }                                 \
    _Pragma("unroll") for (int kk = 0; kk < 2; ++kk) {                         \
      union { s16x8 v; unsigned u[4]; } pa;                                    \
      _Pragma("unroll") for (int q = 0; q < 4; ++q) {                          \
        int src = ((2 * (g & 1) + (q >> 1)) << 4) + li;                        \
        unsigned uA = __shfl(pk[2 * kk][q & 1], src);                          \
        unsigned uB = __shfl(pk[2 * kk + 1][q & 1], src);                      \
        pa.u[q] = (g < 2) ? uA : uB; }                                         \
      _Pragma("unroll") for (int df = 0; df < 4; ++df)                         \
        oacc[df] = mfma_bf16(pa.v, vf[df * 2 + kk], oacc[df]); }               \
  } while (0)

__global__ __launch_bounds__(64) void attn_cross_part(
    const u16* __restrict__ Qb,                              // stride 512
    const u16* __restrict__ Kf, const u16* __restrict__ Vf,  // frag-packed
    float* __restrict__ po, float2* __restrict__ pms) {
  const int lane = threadIdx.x;
  const int g = lane >> 4, li = lane & 15;
  const int qt = blockIdx.x, h = blockIdx.y;
  const int b = blockIdx.z >> 2, s = blockIdx.z & 3;
  const int growq = b * 512 + qt * 16;

  const u16* qp = Qb + (size_t)(growq + li) * 512 + h * 64;
  s16x8 aq0 = *(const s16x8*)(qp + g * 8);
  s16x8 aq1 = *(const s16x8*)(qp + 32 + g * 8);
  const u16* kfb = Kf + (size_t)((b * 8 + h) * 8) * 4096;
  const u16* vfb = Vf + (size_t)((b * 8 + h) * 8) * 4096;

  float mrow = NEGV, rsum = 0.f;
  f32x4 oacc[4];
#pragma unroll
  for (int d = 0; d < 4; ++d) oacc[d] = (f32x4){0.f, 0.f, 0.f, 0.f};

  s16x8 kA[8], kB[8];
  LOADK_X(kA, 2 * s);
  LOADK_X(kB, 2 * s + 1);
  COMPUTE_X(kA, 2 * s);
  COMPUTE_X(kB, 2 * s + 1);

  rsum += __shfl_xor(rsum, 16);
  rsum += __shfl_xor(rsum, 32);

  const size_t idx = (size_t)(b * 8 + h) * 512 + qt * 16;
#pragma unroll
  for (int df = 0; df < 4; ++df)
#pragma unroll
    for (int r = 0; r < 4; ++r)
      po[((idx + 4 * g + r) * 4 + s) * 64 + df * 16 + li] = oacc[df][r];
  if (lane < 16) pms[(idx + lane) * 4 + s] = make_float2(mrow, rsum);
}

// ---------------------------------------------------------------------------
// Merge 4 split partials per row: m = max m_s, f = exp(m_s - m);
// out = (sum f*oacc_s) / (sum f*rsum_s). 16 rows/block.
// ---------------------------------------------------------------------------
__global__ __launch_bounds__(256) void attn_merge(
    const float* __restrict__ po, const float2* __restrict__ pms,
    u16* __restrict__ att) {
  const int t = threadIdx.x;
  const size_t idx = (size_t)blockIdx.x * 16 + (t >> 4);
  const int d4 = (t & 15) * 4;
  float2 ms[4];
  float m = NEGV;
#pragma unroll
  for (int s = 0; s < 4; ++s) {
    ms[s] = pms[idx * 4 + s];
    m = fmaxf(m, ms[s].x);
  }
  float rs = 0.f;
  float4 o = make_float4(0.f, 0.f, 0.f, 0.f);
#pragma unroll
  for (int s = 0; s < 4; ++s) {
    float f = __expf(ms[s].x - m);
    rs += f * ms[s].y;
    float4 v = *(const float4*)(po + (idx * 4 + s) * 64 + d4);
    o.x += f * v.x; o.y += f * v.y; o.z += f * v.z; o.w += f * v.w;
  }
  const float inv = 1.f / rs;
  const int b = (int)(idx >> 12), h = (int)(idx >> 9) & 7, row = (int)(idx & 511);
  ushort4 ov;
  ov.x = f2bf(o.x * inv);
  ov.y = f2bf(o.y * inv);
  ov.z = f2bf(o.z * inv);
  ov.w = f2bf(o.w * inv);
  *(ushort4*)(att + (size_t)(b * 512 + row) * 512 + h * 64 + d4) = ov;
}

// ---------------------------------------------------------------------------
// out = LayerNorm(x + dlt) * g + b ; also writes bf16 copy
// ---------------------------------------------------------------------------
__global__ __launch_bounds__(256) void ln_res(
    const float* __restrict__ x, const float* __restrict__ dlt,
    const float* __restrict__ g, const float* __restrict__ bta,
    float* __restrict__ out, u16* __restrict__ obf) {
  __shared__ float red_s[256];
  const int row = blockIdx.x, tid = threadIdx.x;
  const size_t base = (size_t)row * Hc;
  float v0 = x[base + tid] + dlt[base + tid];
  float v1 = x[base + tid + 256] + dlt[base + tid + 256];

  red_s[tid] = v0 + v1;
  __syncthreads();
  for (int s = 128; s > 0; s >>= 1) {
    if (tid < s) red_s[tid] += red_s[tid + s];
    __syncthreads();
  }
  const float mean = red_s[0] * (1.f / Hc);
  __syncthreads();
  const float d0 = v0 - mean, d1 = v1 - mean;
  red_s[tid] = d0 * d0 + d1 * d1;
  __syncthreads();
  for (int s = 128; s > 0; s >>= 1) {
    if (tid < s) red_s[tid] += red_s[tid + s];
    __syncthreads();
  }
  const float rstd = rsqrtf(red_s[0] * (1.f / Hc) + EPSV);
  float o0 = d0 * rstd * g[tid] + bta[tid];
  float o1 = d1 * rstd * g[tid + 256] + bta[tid + 256];
  out[base + tid] = o0;
  out[base + tid + 256] = o1;
  obf[base + tid] = f2bf(o0);
  obf[base + tid + 256] = f2bf(o1);
}

// ---------------------------------------------------------------------------
extern "C" void kernel_launch(void* const* d_in, const int* in_sizes, int n_in,
                              void* d_out, int out_size, void* d_ws, size_t ws_size,
                              hipStream_t stream) {
  const float* q    = (const float*)d_in[0];
  const float* kv   = (const float*)d_in[1];
  const float* relk = (const float*)d_in[2];
  const float* relv = (const float*)d_in[3];
  const float* Wq_s = (const float*)d_in[4];
  const float* bq_s = (const float*)d_in[5];
  const float* Wk_s = (const float*)d_in[6];
  const float* Wv_s = (const float*)d_in[7];
  const float* Wo_s = (const float*)d_in[8];
  const float* bo_s = (const float*)d_in[9];
  const float* ln1g = (const float*)d_in[10];
  const float* ln1b = (const float*)d_in[11];
  const float* Wq_c = (const float*)d_in[12];
  const float* bq_c = (const float*)d_in[13];
  const float* Wk_c = (const float*)d_in[14];
  const float* Wv_c = (const float*)d_in[15];
  const float* Wo_c = (const float*)d_in[16];
  const float* bo_c = (const float*)d_in[17];
  const float* ln2g = (const float*)d_in[18];
  const float* ln2b = (const float*)d_in[19];
  const float* W1   = (const float*)d_in[20];
  const float* b1   = (const float*)d_in[21];
  const float* W2   = (const float*)d_in[22];
  const float* b2   = (const float*)d_in[23];
  const float* ln3g = (const float*)d_in[24];
  const float* ln3b = (const float*)d_in[25];
  const int*   rel  = (const int*)d_in[26];

  char* wsb = (char*)d_ws;
  const size_t NT = (size_t)Bc * Tc;  // 2048 token rows
  float* o     = (float*)wsb;  wsb += NT * Hc * 4;       // 4MB
  float* bDlt  = (float*)wsb;  wsb += NT * Hc * 4;       // 4MB
  u16* Qr      = (u16*)wsb;    wsb += NT * 8 * 64 * 2;   // 2MB (bf16)
  u16* obf     = (u16*)wsb;    wsb += NT * Hc * 2;       // 2MB
  u16* kvbf    = (u16*)wsb;    wsb += NT * Hc * 2;       // 2MB
  u16* bQK     = (u16*)wsb;    wsb += NT * 1024 * 2;     // 4MB
  u16* bVt     = (u16*)wsb;    wsb += (size_t)512 * 2048 * 2;   // 2MB
  u16* bQc     = (u16*)wsb;    wsb += NT * Hc * 2;       // 2MB
  u16* bKc     = (u16*)wsb;    wsb += NT * 1024 * 2;     // 4MB
  u16* bVtc    = (u16*)wsb;    wsb += (size_t)1024 * 2048 * 2;  // 4MB
  u16* bAtt    = (u16*)wsb;    wsb += NT * Hc * 2;       // 2MB
  u16* bH      = (u16*)wsb;    wsb += NT * FFc * 2;      // 8MB
  u16* relvt   = (u16*)wsb;    wsb += 64 * 64 * 2;       // 8KB
  u8* rel8     = (u8*)wsb;     wsb += (size_t)NT * 512;  // 1MB
  u16* wbuf    = (u16*)wsb;    wsb += (size_t)8388608 * 2;  // 16MB
  float* po    = (float*)wsb;  wsb += (size_t)16384 * 4 * 64 * 4;  // 16MB
  float2* pms  = (float2*)wsb; wsb += (size_t)16384 * 4 * 8;       // 512KB
  u16* KfX0    = (u16*)wsb;    wsb += (size_t)1048576 * 2;  // 2MB cross frag K L0
  u16* VfX0    = (u16*)wsb;    wsb += (size_t)1048576 * 2;  // 2MB
  u16* KfX1    = (u16*)wsb;    wsb += (size_t)1048576 * 2;  // 2MB cross frag K L1
  u16* VfX1    = (u16*)wsb;    wsb += (size_t)1048576 * 2;  // 2MB
  // self frags alias bH (dead outside FFN; repacked per layer before attn)
  u16* KfS     = bH;
  u16* VfS     = bH + 1048576;

  WPtrs wp;
  wp.p[0] = Wq_s; wp.p[1] = Wk_s; wp.p[2] = Wv_s; wp.p[3] = Wo_s;
  wp.p[4] = Wq_c; wp.p[5] = Wk_c; wp.p[6] = Wv_c; wp.p[7] = Wo_c;
  wp.p[8] = W1;   wp.p[9] = W2;

  dim3 blk(256);
  wcvt<<<dim3(2048), blk, 0, stream>>>(wp, wbuf);
  acvt<<<dim3(1537), blk, 0, stream>>>(q, kv, relv, rel, obf, kvbf, relvt, rel8);
  hipMemcpyAsync(o, q, NT * Hc * 4, hipMemcpyDeviceToDevice, stream);

  // cross K (both layers) and cross V^T (both layers), then frag-pack
  gemm_mfma<64, 128, false, 1><<<dim3(8, 32), blk, 0, stream>>>(
      kvbf, wbuf + 2097152, nullptr, 0, bKc, 1024, 512);
  gemm_mfma<64, 128, false, 1><<<dim3(16, 16), blk, 0, stream>>>(
      wbuf + 2621440, kvbf, nullptr, 0, bVtc, 2048, 512);
  const dim3 gPK(8, 8, 4);
  pack_frags<<<gPK, dim3(128), 0, stream>>>(bKc, 1024, bVtc, 2048, KfX0, VfX0);
  pack_frags<<<gPK, dim3(128), 0, stream>>>(bKc + 512, 1024,
      bVtc + (size_t)512 * 2048, 2048, KfX1, VfX1);

  const dim3 gLN(NT);
  const dim3 gPART(32, 8, 16);
  const dim3 gMERGE(1024);
  for (int i = 0; i < NLc; ++i) {
    // --- relation-aware masked self-attention ---
    gemm_mfma<64, 128, false, 1><<<dim3(8, 32), blk, 0, stream>>>(
        obf, wbuf + (size_t)i * 524288, bq_s + i * Hc, Hc, bQK, 1024, 512);
    gemm_mfma<64, 64, false, 1><<<dim3(32, 8), blk, 0, stream>>>(
        wbuf + 3670016 + (size_t)i * 262144, obf, nullptr, 0, bVt, 2048, 512);
    qr_kernel<<<dim3(4096), blk, 0, stream>>>(bQK, relk, Qr);
    pack_frags<<<gPK, dim3(128), 0, stream>>>(bQK + 512, 1024, bVt, 2048, KfS, VfS);
    attn_self_part<<<gPART, dim3(64), 0, stream>>>(
        bQK, KfS, VfS, Qr, rel8, relvt, po, pms);
    attn_merge<<<gMERGE, blk, 0, stream>>>(po, pms, bAtt);
    gemm_mfma<64, 64, false, 0><<<dim3(8, 32), blk, 0, stream>>>(
        bAtt, wbuf + 1048576 + (size_t)i * 262144, bo_s + i * Hc, Hc, bDlt, Hc, 512);
    ln_res<<<gLN, blk, 0, stream>>>(o, bDlt, ln1g + i * Hc, ln1b + i * Hc, o, obf);

    // --- cross-attention ---
    gemm_mfma<64, 64, false, 1><<<dim3(8, 32), blk, 0, stream>>>(
        obf, wbuf + 1572864 + (size_t)i * 262144, bq_c + i * Hc, Hc, bQc, Hc, 512);
    attn_cross_part<<<gPART, dim3(64), 0, stream>>>(
        bQc, i ? KfX1 : KfX0, i ? VfX1 : VfX0, po, pms);
    attn_merge<<<gMERGE, blk, 0, stream>>>(po, pms, bAtt);
    gemm_mfma<64, 64, false, 0><<<dim3(8, 32), blk, 0, stream>>>(
        bAtt, wbuf + 3145728 + (size_t)i * 262144, bo_c + i * Hc, Hc, bDlt, Hc, 512);
    ln_res<<<gLN, blk, 0, stream>>>(o, bDlt, ln2g + i * Hc, ln2b + i * Hc, o, obf);

    // --- feedforward ---
    gemm_mfma<64, 128, true, 1><<<dim3(16, 32), blk, 0, stream>>>(
        obf, wbuf + 4194304 + (size_t)i * 1048576, b1 + i * FFc, FFc, bH, FFc, 512);
    gemm_mfma<64, 64, false, 0><<<dim3(8, 32), blk, 0, stream>>>(
        bH, wbuf + 6291456 + (size_t)i * 1048576, b2 + i * Hc, Hc, bDlt, Hc, 2048);
    float* lnout = (i == NLc - 1) ? (float*)d_out : o;
    ln_res<<<gLN, blk, 0, stream>>>(o, bDlt, ln3g + i * Hc, ln3b + i * Hc, lnout, obf);
  }
}

// Round 11
// 380.777 us; speedup vs baseline: 1.4341x; 1.0045x over previous
//
#include <hip/hip_runtime.h>

static constexpr int Hc  = 512;
static constexpr int NHc = 8;
static constexpr int DHc = 64;
static constexpr int NLc = 2;
static constexpr int Rc  = 64;
static constexpr int FFc = 2048;
static constexpr int Bc  = 4;
static constexpr int Tc  = 512;
#define NEGV (-1e10f)
#define EPSV 1e-5f
#define THRV 6.0f

typedef unsigned short u16;
typedef unsigned char u8;
typedef __attribute__((ext_vector_type(8))) short s16x8;
typedef __attribute__((ext_vector_type(4))) float f32x4;

__device__ __forceinline__ f32x4 mfma_bf16(s16x8 a, s16x8 b, f32x4 c) {
  return __builtin_amdgcn_mfma_f32_16x16x32_bf16(a, b, c, 0, 0, 0);
}
__device__ __forceinline__ u16 f2bf(float f) {
  union { float f; unsigned u; } x; x.f = f;
  unsigned r = (x.u + 0x7FFFu + ((x.u >> 16) & 1u)) >> 16;
  return (u16)r;
}
__device__ __forceinline__ float bf2f(u16 h) {
  union { unsigned u; float f; } x; x.u = ((unsigned)h) << 16;
  return x.f;
}
__device__ __forceinline__ unsigned cvtpk(float a, float b) {
  unsigned r;
  asm("v_cvt_pk_bf16_f32 %0, %1, %2" : "=v"(r) : "v"(a), "v"(b));
  return r;
}

// ---------------------------------------------------------------------------
// bf16 MFMA GEMM: C[M,N] = A[M,K] @ Wt[N,K]^T (+bias for col<biasN) (+relu)
// Register double-buffer of the next K-tile.
// ---------------------------------------------------------------------------
template <int BM, int BN, bool RELU, int OUT>  // OUT: 0=f32, 1=bf16
__global__ __launch_bounds__(256) void gemm_mfma(
    const u16* __restrict__ A, const u16* __restrict__ Wt,
    const float* __restrict__ bias, int biasN,
    void* __restrict__ Cout, int N, int K) {
  __shared__ u16 As[BM * 32];
  __shared__ u16 Bs[BN * 32];
  const int tid = threadIdx.x;
  const int w = tid >> 6, lane = tid & 63, g = lane >> 4, li = lane & 15;
  const int bn = blockIdx.x * BN, bm = blockIdx.y * BM;
  const int r0 = (w & 1) * (BM / 2), c0 = (w >> 1) * (BN / 2);
  constexpr int MR = BM / 32, NR = BN / 32;
  constexpr int AIT = BM / 64, BIT = BN / 64;
  f32x4 acc[MR][NR];
#pragma unroll
  for (int i = 0; i < MR; ++i)
#pragma unroll
    for (int j = 0; j < NR; ++j) acc[i][j] = (f32x4){0.f, 0.f, 0.f, 0.f};

  s16x8 va[AIT], vb[BIT];
#pragma unroll
  for (int it = 0; it < AIT; ++it) {
    int s = it * 256 + tid, row = s >> 2, ch = s & 3;
    va[it] = *(const s16x8*)(A + (size_t)(bm + row) * K + ch * 8);
  }
#pragma unroll
  for (int it = 0; it < BIT; ++it) {
    int s = it * 256 + tid, row = s >> 2, ch = s & 3;
    vb[it] = *(const s16x8*)(Wt + (size_t)(bn + row) * K + ch * 8);
  }

  for (int k0 = 0; k0 < K; k0 += 32) {
    __syncthreads();
#pragma unroll
    for (int it = 0; it < AIT; ++it) {
      int s = it * 256 + tid, row = s >> 2, ch = s & 3;
      *(s16x8*)&As[row * 32 + ((ch ^ (row & 3)) * 8)] = va[it];
    }
#pragma unroll
    for (int it = 0; it < BIT; ++it) {
      int s = it * 256 + tid, row = s >> 2, ch = s & 3;
      *(s16x8*)&Bs[row * 32 + ((ch ^ (row & 3)) * 8)] = vb[it];
    }
    if (k0 + 32 < K) {
#pragma unroll
      for (int it = 0; it < AIT; ++it) {
        int s = it * 256 + tid, row = s >> 2, ch = s & 3;
        va[it] = *(const s16x8*)(A + (size_t)(bm + row) * K + k0 + 32 + ch * 8);
      }
#pragma unroll
      for (int it = 0; it < BIT; ++it) {
        int s = it * 256 + tid, row = s >> 2, ch = s & 3;
        vb[it] = *(const s16x8*)(Wt + (size_t)(bn + row) * K + k0 + 32 + ch * 8);
      }
    }
    __syncthreads();
    s16x8 ar[MR], br[NR];
#pragma unroll
    for (int i = 0; i < MR; ++i) {
      int row = r0 + i * 16 + li;
      ar[i] = *(const s16x8*)&As[row * 32 + ((g ^ (row & 3)) * 8)];
    }
#pragma unroll
    for (int j = 0; j < NR; ++j) {
      int row = c0 + j * 16 + li;
      br[j] = *(const s16x8*)&Bs[row * 32 + ((g ^ (row & 3)) * 8)];
    }
#pragma unroll
    for (int i = 0; i < MR; ++i)
#pragma unroll
      for (int j = 0; j < NR; ++j) acc[i][j] = mfma_bf16(ar[i], br[j], acc[i][j]);
  }

#pragma unroll
  for (int j = 0; j < NR; ++j) {
    int col = bn + c0 + j * 16 + li;
    float bv = (bias && col < biasN) ? bias[col] : 0.f;
#pragma unroll
    for (int i = 0; i < MR; ++i) {
#pragma unroll
      for (int r = 0; r < 4; ++r) {
        int rowg = bm + r0 + i * 16 + 4 * g + r;
        float v = acc[i][j][r] + bv;
        if (RELU) v = fmaxf(v, 0.f);
        if (OUT == 0) ((float*)Cout)[(size_t)rowg * N + col] = v;
        else          ((u16*)Cout)[(size_t)rowg * N + col] = f2bf(v);
      }
    }
  }
}

// ---------------------------------------------------------------------------
// Weight transpose+convert: f32 [Ks][Ns] -> bf16 [Ns][Ks] at dstOff
// ---------------------------------------------------------------------------
struct WPtrs { const float* p[10]; };

__global__ __launch_bounds__(256) void wcvt(WPtrs wp, u16* __restrict__ dst) {
  constexpr int NE = 20;
  constexpr int srcIdx[NE] = {0,1,0,1,3,3,4,4,5,5,6,6,7,7,2,2,8,8,9,9};
  constexpr int srcOff[NE] = {0,0,262144,262144,0,262144,0,262144,0,262144,
                              0,262144,0,262144,0,262144,0,1048576,0,1048576};
  constexpr int dstOff[NE] = {0,262144,524288,786432,1048576,1310720,
                              1572864,1835008,2097152,2359296,2621440,2883584,
                              3145728,3407872,3670016,3932160,
                              4194304,5242880,6291456,7340032};
  constexpr int KsA[NE] = {512,512,512,512,512,512,512,512,512,512,
                           512,512,512,512,512,512,512,512,2048,2048};
  constexpr int NsA[NE] = {512,512,512,512,512,512,512,512,512,512,
                           512,512,512,512,512,512,2048,2048,512,512};
  constexpr int tileStart[NE] = {0,64,128,192,256,320,384,448,512,576,
                                 640,704,768,832,896,960,1024,1280,1536,1792};
  __shared__ float ts[64 * 65];
  const int tid = threadIdx.x;
  const int bid = blockIdx.x;
  int e = 0;
#pragma unroll
  for (int i = 1; i < NE; ++i) if (bid >= tileStart[i]) e = i;
  const int t = bid - tileStart[e];
  const int Ks_ = KsA[e], Ns_ = NsA[e];
  const int tn = t % (Ns_ >> 6), tk = t / (Ns_ >> 6);
  const float* src = wp.p[srcIdx[e]] + srcOff[e];

  {
    int r = tid >> 2, cb = (tid & 3) * 16;
    const float* sp = src + (size_t)(tk * 64 + r) * Ns_ + tn * 64 + cb;
#pragma unroll
    for (int j = 0; j < 4; ++j) {
      float4 v = ((const float4*)sp)[j];
      float* d = &ts[r * 65 + cb + j * 4];
      d[0] = v.x; d[1] = v.y; d[2] = v.z; d[3] = v.w;
    }
  }
  __syncthreads();
  {
    int n = tid >> 2, kb = (tid & 3) * 16;
    u16* dp = dst + dstOff[e] + (size_t)(tn * 64 + n) * Ks_ + tk * 64 + kb;
    s16x8 o0, o1;
#pragma unroll
    for (int j = 0; j < 8; ++j) o0[j] = (short)f2bf(ts[(kb + j) * 65 + n]);
#pragma unroll
    for (int j = 0; j < 8; ++j) o1[j] = (short)f2bf(ts[(kb + 8 + j) * 65 + n]);
    *(s16x8*)dp = o0;
    *(s16x8*)(dp + 8) = o1;
  }
}

// ---------------------------------------------------------------------------
// activations f32->bf16 + f32 copy of q (blocks 0..1023); block 1024:
// relv -> relv^T bf16; blocks 1025..1536: rel_ids int32 -> u8 pack.
// ---------------------------------------------------------------------------
__global__ __launch_bounds__(256) void acvt(
    const float* __restrict__ q, const float* __restrict__ kv,
    const float* __restrict__ relv, const int* __restrict__ rel,
    u16* __restrict__ obf, u16* __restrict__ kvbf, u16* __restrict__ relvt,
    u8* __restrict__ rel8, float* __restrict__ ocp) {
  int bid = blockIdx.x, tid = threadIdx.x;
  if (bid >= 1025) {
    size_t i = (size_t)(bid - 1025) * 2048 + (size_t)tid * 8;
    int4 a = *(const int4*)(rel + i);
    int4 b = *(const int4*)(rel + i + 4);
    unsigned lo = (unsigned)(a.x & 255) | ((unsigned)(a.y & 255) << 8) |
                  ((unsigned)(a.z & 255) << 16) | ((unsigned)(a.w & 255) << 24);
    unsigned hi = (unsigned)(b.x & 255) | ((unsigned)(b.y & 255) << 8) |
                  ((unsigned)(b.z & 255) << 16) | ((unsigned)(b.w & 255) << 24);
    *(uint2*)(rel8 + i) = make_uint2(lo, hi);
    return;
  }
  if (bid == 1024) {
    int d = tid >> 2, rb = (tid & 3) * 16;
    s16x8 o0, o1;
#pragma unroll
    for (int j = 0; j < 8; ++j) o0[j] = (short)f2bf(relv[(rb + j) * 64 + d]);
#pragma unroll
    for (int j = 0; j < 8; ++j) o1[j] = (short)f2bf(relv[(rb + 8 + j) * 64 + d]);
    *(s16x8*)(relvt + d * 64 + rb) = o0;
    *(s16x8*)(relvt + d * 64 + rb + 8) = o1;
    return;
  }
  int i = bid * 256 + tid;
  const float* src; u16* dst; size_t off;
  bool isq = (i < 131072);
  if (isq) { src = q; dst = obf; off = (size_t)i * 8; }
  else { src = kv; dst = kvbf; off = (size_t)(i - 131072) * 8; }
  float4 a = *(const float4*)(src + off);
  float4 b = *(const float4*)(src + off + 4);
  if (isq) {  // fold the o = q f32 copy (replaces hipMemcpyAsync)
    *(float4*)(ocp + off) = a;
    *(float4*)(ocp + off + 4) = b;
  }
  s16x8 o;
  o[0] = (short)f2bf(a.x); o[1] = (short)f2bf(a.y);
  o[2] = (short)f2bf(a.z); o[3] = (short)f2bf(a.w);
  o[4] = (short)f2bf(b.x); o[5] = (short)f2bf(b.y);
  o[6] = (short)f2bf(b.z); o[7] = (short)f2bf(b.w);
  *(s16x8*)(dst + off) = o;
}

// ---------------------------------------------------------------------------
// Qr[(row*8+h), r] = sum_d Q[row, h*64+d] * relk[r, d]  (bf16 out)
// ---------------------------------------------------------------------------
__global__ __launch_bounds__(256) void qr_kernel(
    const u16* __restrict__ Q, const float* __restrict__ relk,
    u16* __restrict__ Qr) {
  __shared__ float rk[64 * 65];
  __shared__ float qs[4][64];
  const int tid = threadIdx.x;
  {
    int r = tid >> 2, cb = (tid & 3) * 16;
    const float* sp = relk + r * 64 + cb;
#pragma unroll
    for (int j = 0; j < 4; ++j) {
      float4 v = ((const float4*)sp)[j];
      float* d = &rk[r * 65 + cb + j * 4];
      d[0] = v.x; d[1] = v.y; d[2] = v.z; d[3] = v.w;
    }
  }
  const int sub = tid >> 6, r = tid & 63;
  const int unit = blockIdx.x * 4 + sub;  // unit = row*8 + h
  qs[sub][r] = bf2f(Q[(size_t)(unit >> 3) * 1024 + (unit & 7) * 64 + r]);
  __syncthreads();
  float acc = 0.f;
#pragma unroll
  for (int d = 0; d < 64; ++d) acc += qs[sub][d] * rk[r * 65 + d];
  Qr[(size_t)unit * 64 + r] = f2bf(acc);
}

// ---------------------------------------------------------------------------
// Fragment pack: K / V^T -> MFMA-fragment order (lane-contiguous loads).
// ---------------------------------------------------------------------------
__global__ __launch_bounds__(128) void pack_frags(
    const u16* __restrict__ Kin, int kstride,
    const u16* __restrict__ VTin, int vstride,
    u16* __restrict__ Kf, u16* __restrict__ Vf) {
  const int t = threadIdx.x;
  const int c8 = blockIdx.x, h = blockIdx.y, b = blockIdx.z;
  u16* kdst = Kf + (size_t)((b * 8 + h) * 8 + c8) * 4096;
  u16* vdst = Vf + (size_t)((b * 8 + h) * 8 + c8) * 4096;
#pragma unroll
  for (int i = 0; i < 4; ++i) {
    int s = i * 128 + t;
    int mt = s >> 7, kk = (s >> 6) & 1, lane = s & 63;
    int g = lane >> 4, li = lane & 15;
    s16x8 kv = *(const s16x8*)(
        Kin + (size_t)(b * 512 + c8 * 64 + mt * 16 + li) * kstride +
        h * 64 + kk * 32 + g * 8);
    s16x8 vv = *(const s16x8*)(
        VTin + (size_t)(h * 64 + mt * 16 + li) * vstride +
        b * 512 + c8 * 64 + kk * 32 + g * 8);
    *(s16x8*)(kdst + (mt * 2 + kk) * 512 + lane * 8) = kv;
    *(s16x8*)(vdst + (mt * 2 + kk) * 512 + lane * 8) = vv;
  }
}

// ---------------------------------------------------------------------------
// Split-KV attention: ONE CHUNK PER WAVE (8 splits), bf16 partials.
// Masked cols give p=exp(NEGV-NEGV)=1 while m stays NEGV; merge factor
// f=exp(m_s-m) zeroes garbage partials exactly / combines uniform sums.
// Grid: (32 qt, 8 h, 4b x 8s) x 64 thr.
// ---------------------------------------------------------------------------
#define LOADKREL(KF, RF, C8) do {                                              \
    _Pragma("unroll") for (int mt = 0; mt < 4; ++mt) {                         \
      KF[mt * 2 + 0] = *(const s16x8*)(kfb + (size_t)(C8) * 4096 + (mt * 2 + 0) * 512 + lane * 8); \
      KF[mt * 2 + 1] = *(const s16x8*)(kfb + (size_t)(C8) * 4096 + (mt * 2 + 1) * 512 + lane * 8); \
      RF[mt] = *(const unsigned*)(rp8 + (C8) * 64 + mt * 16);                  \
    } } while (0)

#define COMPUTE_SELF(KF, RF, C8) do {                                          \
    s16x8 vf[8];                                                               \
    _Pragma("unroll") for (int df = 0; df < 4; ++df) {                         \
      vf[df * 2 + 0] = *(const s16x8*)(vfb + (size_t)(C8) * 4096 + (df * 2 + 0) * 512 + lane * 8); \
      vf[df * 2 + 1] = *(const s16x8*)(vfb + (size_t)(C8) * 4096 + (df * 2 + 1) * 512 + lane * 8); } \
    f32x4 sf[4];                                                               \
    _Pragma("unroll") for (int mt = 0; mt < 4; ++mt) {                         \
      sf[mt] = (f32x4){0.f, 0.f, 0.f, 0.f};                                    \
      sf[mt] = mfma_bf16(KF[mt * 2 + 0], aq0, sf[mt]);                         \
      sf[mt] = mfma_bf16(KF[mt * 2 + 1], aq1, sf[mt]); }                       \
    float p[4][4];                                                             \
    int rl[4][4];                                                              \
    float pmax = NEGV;                                                         \
    _Pragma("unroll") for (int mt = 0; mt < 4; ++mt) {                         \
      _Pragma("unroll") for (int r = 0; r < 4; ++r) {                          \
        int rel = (int)((RF[mt] >> (8 * r)) & 255u);                           \
        rl[mt][r] = rel;                                                       \
        bool valid = (rel != 0) && ((C8) * 64 + mt * 16 + 4 * g + r <= lrow);  \
        p[mt][r] = valid ? (sf[mt][r] + qrs[li * 66 + rel]) * 0.125f : NEGV;   \
        pmax = fmaxf(pmax, p[mt][r]); } }                                      \
    pmax = fmaxf(pmax, __shfl_xor(pmax, 16));                                  \
    pmax = fmaxf(pmax, __shfl_xor(pmax, 32));                                  \
    if (__any(pmax > mrow + THRV)) {                                           \
      float mnew = (pmax > mrow + THRV) ? pmax : mrow;                         \
      float f = __expf(mrow - mnew);                                           \
      rsum *= f;                                                               \
      _Pragma("unroll") for (int j = 0; j < 8; ++j) {                          \
        float2* p2 = (float2*)&bk[li * 66 + g * 16 + 2 * j];                   \
        float2 v = *p2; v.x *= f; v.y *= f; *p2 = v; }                         \
      _Pragma("unroll") for (int r = 0; r < 4; ++r) {                          \
        float fr = __shfl(f, 4 * g + r);                                       \
        _Pragma("unroll") for (int df = 0; df < 4; ++df) oacc[df][r] *= fr; }  \
      mrow = mnew; }                                                           \
    unsigned pk[4][2];                                                         \
    _Pragma("unroll") for (int mt = 0; mt < 4; ++mt) {                         \
      _Pragma("unroll") for (int r = 0; r < 4; ++r) {                          \
        float pv = __expf(p[mt][r] - mrow);                                    \
        p[mt][r] = pv;                                                         \
        rsum += pv;                                                            \
        if (pv > 0.f) atomicAdd(&bk[li * 66 + rl[mt][r]], pv); }               \
      pk[mt][0] = cvtpk(p[mt][0], p[mt][1]);                                   \
      pk[mt][1] = cvtpk(p[mt][2], p[mt][3]); }                                 \
    _Pragma("unroll") for (int kk = 0; kk < 2; ++kk) {                         \
      union { s16x8 v; unsigned u[4]; } pa;                                    \
      _Pragma("unroll") for (int q = 0; q < 4; ++q) {                          \
        int src = ((2 * (g & 1) + (q >> 1)) << 4) + li;                        \
        unsigned uA = __shfl(pk[2 * kk][q & 1], src);                          \
        unsigned uB = __shfl(pk[2 * kk + 1][q & 1], src);                      \
        pa.u[q] = (g < 2) ? uA : uB; }                                         \
      _Pragma("unroll") for (int df = 0; df < 4; ++df)                         \
        oacc[df] = mfma_bf16(pa.v, vf[df * 2 + kk], oacc[df]); }               \
  } while (0)

__global__ __launch_bounds__(64) void attn_self_part(
    const u16* __restrict__ Qb,                              // stride 1024
    const u16* __restrict__ Kf, const u16* __restrict__ Vf,  // frag-packed
    const u16* __restrict__ Qrb, const u8* __restrict__ rel8,
    const u16* __restrict__ relvt,
    u16* __restrict__ po, float2* __restrict__ pms) {
  __shared__ float qrs[16 * 66];
  __shared__ float buck[16 * 66];
  float* bk = buck;

  const int lane = threadIdx.x;
  const int g = lane >> 4, li = lane & 15;
  const int qt = blockIdx.x, h = blockIdx.y;
  const int b = blockIdx.z >> 3, s = blockIdx.z & 7;
  const int lrow = qt * 16 + li;
  const int growq = b * 512 + qt * 16;

  const u16* qp = Qb + (size_t)(growq + li) * 1024 + h * 64;
  s16x8 aq0 = *(const s16x8*)(qp + g * 8);
  s16x8 aq1 = *(const s16x8*)(qp + 32 + g * 8);
  const u16* kfb = Kf + (size_t)((b * 8 + h) * 8) * 4096;
  const u16* vfb = Vf + (size_t)((b * 8 + h) * 8) * 4096;
  const u8* rp8 = rel8 + (size_t)(growq + li) * 512 + 4 * g;

  {  // stage Qr (bf16 -> f32 LDS) + zero buckets
    int row = lane >> 2, c16 = (lane & 3) * 16;
    const u16* qrp = Qrb + ((size_t)(growq + row) * 8 + h) * 64 + c16;
    s16x8 v0 = *(const s16x8*)qrp;
    s16x8 v1 = *(const s16x8*)(qrp + 8);
#pragma unroll
    for (int j = 0; j < 8; ++j) {
      qrs[row * 66 + c16 + j] = bf2f((u16)v0[j]);
      qrs[row * 66 + c16 + 8 + j] = bf2f((u16)v1[j]);
    }
#pragma unroll
    for (int j = 0; j < 5; ++j) {  // 264 float4s cover 16*66
      int fid = j * 64 + lane;
      if (fid < 264) *(float4*)&buck[fid * 4] = make_float4(0.f, 0.f, 0.f, 0.f);
    }
  }

  float mrow = NEGV, rsum = 0.f;
  f32x4 oacc[4];
#pragma unroll
  for (int d = 0; d < 4; ++d) oacc[d] = (f32x4){0.f, 0.f, 0.f, 0.f};

  {  // single chunk per wave
    s16x8 kA[8];
    unsigned rA[4];
    LOADKREL(kA, rA, s);
    COMPUTE_SELF(kA, rA, s);
  }

  rsum += __shfl_xor(rsum, 16);
  rsum += __shfl_xor(rsum, 32);

  // rel-V fold into partial: oacc += buck @ relv  (B = relv^T)
#pragma unroll
  for (int kk = 0; kk < 2; ++kk) {
    float bb[8];
#pragma unroll
    for (int j = 0; j < 4; ++j) {
      float2 v = *(const float2*)&bk[li * 66 + kk * 32 + g * 8 + 2 * j];
      bb[2 * j] = v.x; bb[2 * j + 1] = v.y;
    }
    union { s16x8 v; unsigned u[4]; } pb;
#pragma unroll
    for (int q = 0; q < 4; ++q) pb.u[q] = cvtpk(bb[2 * q], bb[2 * q + 1]);
#pragma unroll
    for (int df = 0; df < 4; ++df) {
      s16x8 rb = *(const s16x8*)(relvt + (df * 16 + li) * 64 + kk * 32 + g * 8);
      oacc[df] = mfma_bf16(pb.v, rb, oacc[df]);
    }
  }

  const size_t idx = (size_t)(b * 8 + h) * 512 + qt * 16;
#pragma unroll
  for (int df = 0; df < 4; ++df)
#pragma unroll
    for (int r = 0; r < 4; ++r)
      po[(idx + 4 * g + r) * 512 + s * 64 + df * 16 + li] = f2bf(oacc[df][r]);
  if (lane < 16) pms[(idx + lane) * 8 + s] = make_float2(mrow, rsum);
}

#define LOADK_X(KF, C8) do {                                                   \
    _Pragma("unroll") for (int mt = 0; mt < 4; ++mt) {                         \
      KF[mt * 2 + 0] = *(const s16x8*)(kfb + (size_t)(C8) * 4096 + (mt * 2 + 0) * 512 + lane * 8); \
      KF[mt * 2 + 1] = *(const s16x8*)(kfb + (size_t)(C8) * 4096 + (mt * 2 + 1) * 512 + lane * 8); \
    } } while (0)

#define COMPUTE_X(KF, C8) do {                                                 \
    s16x8 vf[8];                                                               \
    _Pragma("unroll") for (int df = 0; df < 4; ++df) {                         \
      vf[df * 2 + 0] = *(const s16x8*)(vfb + (size_t)(C8) * 4096 + (df * 2 + 0) * 512 + lane * 8); \
      vf[df * 2 + 1] = *(const s16x8*)(vfb + (size_t)(C8) * 4096 + (df * 2 + 1) * 512 + lane * 8); } \
    f32x4 sf[4];                                                               \
    _Pragma("unroll") for (int mt = 0; mt < 4; ++mt) {                         \
      sf[mt] = (f32x4){0.f, 0.f, 0.f, 0.f};                                    \
      sf[mt] = mfma_bf16(KF[mt * 2 + 0], aq0, sf[mt]);                         \
      sf[mt] = mfma_bf16(KF[mt * 2 + 1], aq1, sf[mt]); }                       \
    float p[4][4];                                                             \
    float pmax = NEGV;                                                         \
    _Pragma("unroll") for (int mt = 0; mt < 4; ++mt)                           \
      _Pragma("unroll") for (int r = 0; r < 4; ++r) {                          \
        p[mt][r] = sf[mt][r] * 0.125f;                                         \
        pmax = fmaxf(pmax, p[mt][r]); }                                        \
    pmax = fmaxf(pmax, __shfl_xor(pmax, 16));                                  \
    pmax = fmaxf(pmax, __shfl_xor(pmax, 32));                                  \
    if (__any(pmax > mrow + THRV)) {                                           \
      float mnew = (pmax > mrow + THRV) ? pmax : mrow;                         \
      float f = __expf(mrow - mnew);                                           \
      rsum *= f;                                                               \
      _Pragma("unroll") for (int r = 0; r < 4; ++r) {                          \
        float fr = __shfl(f, 4 * g + r);                                       \
        _Pragma("unroll") for (int df = 0; df < 4; ++df) oacc[df][r] *= fr; }  \
      mrow = mnew; }                                                           \
    unsigned pk[4][2];                                                         \
    _Pragma("unroll") for (int mt = 0; mt < 4; ++mt) {                         \
      _Pragma("unroll") for (int r = 0; r < 4; ++r) {                          \
        float pv = __expf(p[mt][r] - mrow);                                    \
        p[mt][r] = pv;                                                         \
        rsum += pv; }                                                          \
      pk[mt][0] = cvtpk(p[mt][0], p[mt][1]);                                   \
      pk[mt][1] = cvtpk(p[mt][2], p[mt][3]); }                                 \
    _Pragma("unroll") for (int kk = 0; kk < 2; ++kk) {                         \
      union { s16x8 v; unsigned u[4]; } pa;                                    \
      _Pragma("unroll") for (int q = 0; q < 4; ++q) {                          \
        int src = ((2 * (g & 1) + (q >> 1)) << 4) + li;                        \
        unsigned uA = __shfl(pk[2 * kk][q & 1], src);                          \
        unsigned uB = __shfl(pk[2 * kk + 1][q & 1], src);                      \
        pa.u[q] = (g < 2) ? uA : uB; }                                         \
      _Pragma("unroll") for (int df = 0; df < 4; ++df)                         \
        oacc[df] = mfma_bf16(pa.v, vf[df * 2 + kk], oacc[df]); }               \
  } while (0)

__global__ __launch_bounds__(64) void attn_cross_part(
    const u16* __restrict__ Qb,                              // stride 512
    const u16* __restrict__ Kf, const u16* __restrict__ Vf,  // frag-packed
    u16* __restrict__ po, float2* __restrict__ pms) {
  const int lane = threadIdx.x;
  const int g = lane >> 4, li = lane & 15;
  const int qt = blockIdx.x, h = blockIdx.y;
  const int b = blockIdx.z >> 3, s = blockIdx.z & 7;
  const int growq = b * 512 + qt * 16;

  const u16* qp = Qb + (size_t)(growq + li) * 512 + h * 64;
  s16x8 aq0 = *(const s16x8*)(qp + g * 8);
  s16x8 aq1 = *(const s16x8*)(qp + 32 + g * 8);
  const u16* kfb = Kf + (size_t)((b * 8 + h) * 8) * 4096;
  const u16* vfb = Vf + (size_t)((b * 8 + h) * 8) * 4096;

  float mrow = NEGV, rsum = 0.f;
  f32x4 oacc[4];
#pragma unroll
  for (int d = 0; d < 4; ++d) oacc[d] = (f32x4){0.f, 0.f, 0.f, 0.f};

  {
    s16x8 kA[8];
    LOADK_X(kA, s);
    COMPUTE_X(kA, s);
  }

  rsum += __shfl_xor(rsum, 16);
  rsum += __shfl_xor(rsum, 32);

  const size_t idx = (size_t)(b * 8 + h) * 512 + qt * 16;
#pragma unroll
  for (int df = 0; df < 4; ++df)
#pragma unroll
    for (int r = 0; r < 4; ++r)
      po[(idx + 4 * g + r) * 512 + s * 64 + df * 16 + li] = f2bf(oacc[df][r]);
  if (lane < 16) pms[(idx + lane) * 8 + s] = make_float2(mrow, rsum);
}

// ---------------------------------------------------------------------------
// Merge 8 split partials per row: m = max m_s, f = exp(m_s - m);
// out = (sum f*oacc_s) / (sum f*rsum_s). 16 rows/block.
// ---------------------------------------------------------------------------
__global__ __launch_bounds__(256) void attn_merge(
    const u16* __restrict__ po, const float2* __restrict__ pms,
    u16* __restrict__ att) {
  const int t = threadIdx.x;
  const size_t idx = (size_t)blockIdx.x * 16 + (t >> 4);
  const int d4 = (t & 15) * 4;
  float2 ms[8];
  float m = NEGV;
#pragma unroll
  for (int s = 0; s < 8; ++s) {
    ms[s] = pms[idx * 8 + s];
    m = fmaxf(m, ms[s].x);
  }
  float rs = 0.f;
  float4 o = make_float4(0.f, 0.f, 0.f, 0.f);
#pragma unroll
  for (int s = 0; s < 8; ++s) {
    float f = __expf(ms[s].x - m);
    rs += f * ms[s].y;
    ushort4 v = *(const ushort4*)(po + idx * 512 + s * 64 + d4);
    o.x += f * bf2f(v.x); o.y += f * bf2f(v.y);
    o.z += f * bf2f(v.z); o.w += f * bf2f(v.w);
  }
  const float inv = 1.f / rs;
  const int b = (int)(idx >> 12), h = (int)(idx >> 9) & 7, row = (int)(idx & 511);
  ushort4 ov;
  ov.x = f2bf(o.x * inv);
  ov.y = f2bf(o.y * inv);
  ov.z = f2bf(o.z * inv);
  ov.w = f2bf(o.w * inv);
  *(ushort4*)(att + (size_t)(b * 512 + row) * 512 + h * 64 + d4) = ov;
}

// ---------------------------------------------------------------------------
// out = LayerNorm(x + dlt) * g + b ; also writes bf16 copy
// ---------------------------------------------------------------------------
__global__ __launch_bounds__(256) void ln_res(
    const float* __restrict__ x, const float* __restrict__ dlt,
    const float* __restrict__ g, const float* __restrict__ bta,
    float* __restrict__ out, u16* __restrict__ obf) {
  __shared__ float red_s[256];
  const int row = blockIdx.x, tid = threadIdx.x;
  const size_t base = (size_t)row * Hc;
  float v0 = x[base + tid] + dlt[base + tid];
  float v1 = x[base + tid + 256] + dlt[base + tid + 256];

  red_s[tid] = v0 + v1;
  __syncthreads();
  for (int s = 128; s > 0; s >>= 1) {
    if (tid < s) red_s[tid] += red_s[tid + s];
    __syncthreads();
  }
  const float mean = red_s[0] * (1.f / Hc);
  __syncthreads();
  const float d0 = v0 - mean, d1 = v1 - mean;
  red_s[tid] = d0 * d0 + d1 * d1;
  __syncthreads();
  for (int s = 128; s > 0; s >>= 1) {
    if (tid < s) red_s[tid] += red_s[tid + s];
    __syncthreads();
  }
  const float rstd = rsqrtf(red_s[0] * (1.f / Hc) + EPSV);
  float o0 = d0 * rstd * g[tid] + bta[tid];
  float o1 = d1 * rstd * g[tid + 256] + bta[tid + 256];
  out[base + tid] = o0;
  out[base + tid + 256] = o1;
  obf[base + tid] = f2bf(o0);
  obf[base + tid + 256] = f2bf(o1);
}

// ---------------------------------------------------------------------------
extern "C" void kernel_launch(void* const* d_in, const int* in_sizes, int n_in,
                              void* d_out, int out_size, void* d_ws, size_t ws_size,
                              hipStream_t stream) {
  const float* q    = (const float*)d_in[0];
  const float* kv   = (const float*)d_in[1];
  const float* relk = (const float*)d_in[2];
  const float* relv = (const float*)d_in[3];
  const float* Wq_s = (const float*)d_in[4];
  const float* bq_s = (const float*)d_in[5];
  const float* Wk_s = (const float*)d_in[6];
  const float* Wv_s = (const float*)d_in[7];
  const float* Wo_s = (const float*)d_in[8];
  const float* bo_s = (const float*)d_in[9];
  const float* ln1g = (const float*)d_in[10];
  const float* ln1b = (const float*)d_in[11];
  const float* Wq_c = (const float*)d_in[12];
  const float* bq_c = (const float*)d_in[13];
  const float* Wk_c = (const float*)d_in[14];
  const float* Wv_c = (const float*)d_in[15];
  const float* Wo_c = (const float*)d_in[16];
  const float* bo_c = (const float*)d_in[17];
  const float* ln2g = (const float*)d_in[18];
  const float* ln2b = (const float*)d_in[19];
  const float* W1   = (const float*)d_in[20];
  const float* b1   = (const float*)d_in[21];
  const float* W2   = (const float*)d_in[22];
  const float* b2   = (const float*)d_in[23];
  const float* ln3g = (const float*)d_in[24];
  const float* ln3b = (const float*)d_in[25];
  const int*   rel  = (const int*)d_in[26];

  char* wsb = (char*)d_ws;
  const size_t NT = (size_t)Bc * Tc;  // 2048 token rows
  float* o     = (float*)wsb;  wsb += NT * Hc * 4;       // 4MB
  float* bDlt  = (float*)wsb;  wsb += NT * Hc * 4;       // 4MB
  u16* Qr      = (u16*)wsb;    wsb += NT * 8 * 64 * 2;   // 2MB (bf16)
  u16* obf     = (u16*)wsb;    wsb += NT * Hc * 2;       // 2MB
  u16* kvbf    = (u16*)wsb;    wsb += NT * Hc * 2;       // 2MB
  u16* bQK     = (u16*)wsb;    wsb += NT * 1024 * 2;     // 4MB
  u16* bVt     = (u16*)wsb;    wsb += (size_t)512 * 2048 * 2;   // 2MB
  u16* bQc     = (u16*)wsb;    wsb += NT * Hc * 2;       // 2MB
  u16* bKc     = (u16*)wsb;    wsb += NT * 1024 * 2;     // 4MB
  u16* bVtc    = (u16*)wsb;    wsb += (size_t)1024 * 2048 * 2;  // 4MB
  u16* bAtt    = (u16*)wsb;    wsb += NT * Hc * 2;       // 2MB
  u16* bH      = (u16*)wsb;    wsb += NT * FFc * 2;      // 8MB
  u16* relvt   = (u16*)wsb;    wsb += 64 * 64 * 2;       // 8KB
  u8* rel8     = (u8*)wsb;     wsb += (size_t)NT * 512;  // 1MB
  u16* wbuf    = (u16*)wsb;    wsb += (size_t)8388608 * 2;  // 16MB
  u16* po      = (u16*)wsb;    wsb += (size_t)16384 * 512 * 2;  // 16MB (bf16)
  float2* pms  = (float2*)wsb; wsb += (size_t)16384 * 8 * 8;    // 1MB
  u16* KfX0    = (u16*)wsb;    wsb += (size_t)1048576 * 2;  // 2MB
  u16* VfX0    = (u16*)wsb;    wsb += (size_t)1048576 * 2;  // 2MB
  u16* KfX1    = (u16*)wsb;    wsb += (size_t)1048576 * 2;  // 2MB
  u16* VfX1    = (u16*)wsb;    wsb += (size_t)1048576 * 2;  // 2MB
  // self frags alias bH (dead outside FFN; repacked per layer before attn)
  u16* KfS     = bH;
  u16* VfS     = bH + 1048576;

  WPtrs wp;
  wp.p[0] = Wq_s; wp.p[1] = Wk_s; wp.p[2] = Wv_s; wp.p[3] = Wo_s;
  wp.p[4] = Wq_c; wp.p[5] = Wk_c; wp.p[6] = Wv_c; wp.p[7] = Wo_c;
  wp.p[8] = W1;   wp.p[9] = W2;

  dim3 blk(256);
  wcvt<<<dim3(2048), blk, 0, stream>>>(wp, wbuf);
  acvt<<<dim3(1537), blk, 0, stream>>>(q, kv, relv, rel, obf, kvbf, relvt,
                                       rel8, o);

  // cross K (both layers) and cross V^T (both layers), then frag-pack
  gemm_mfma<64, 128, false, 1><<<dim3(8, 32), blk, 0, stream>>>(
      kvbf, wbuf + 2097152, nullptr, 0, bKc, 1024, 512);
  gemm_mfma<64, 128, false, 1><<<dim3(16, 16), blk, 0, stream>>>(
      wbuf + 2621440, kvbf, nullptr, 0, bVtc, 2048, 512);
  const dim3 gPK(8, 8, 4);
  pack_frags<<<gPK, dim3(128), 0, stream>>>(bKc, 1024, bVtc, 2048, KfX0, VfX0);
  pack_frags<<<gPK, dim3(128), 0, stream>>>(bKc + 512, 1024,
      bVtc + (size_t)512 * 2048, 2048, KfX1, VfX1);

  const dim3 gLN(NT);
  const dim3 gPART(32, 8, 32);  // 8 splits per (qt,h,b)
  const dim3 gMERGE(1024);
  for (int i = 0; i < NLc; ++i) {
    // --- relation-aware masked self-attention ---
    gemm_mfma<64, 128, false, 1><<<dim3(8, 32), blk, 0, stream>>>(
        obf, wbuf + (size_t)i * 524288, bq_s + i * Hc, Hc, bQK, 1024, 512);
    gemm_mfma<64, 64, false, 1><<<dim3(32, 8), blk, 0, stream>>>(
        wbuf + 3670016 + (size_t)i * 262144, obf, nullptr, 0, bVt, 2048, 512);
    qr_kernel<<<dim3(4096), blk, 0, stream>>>(bQK, relk, Qr);
    pack_frags<<<gPK, dim3(128), 0, stream>>>(bQK + 512, 1024, bVt, 2048, KfS, VfS);
    attn_self_part<<<gPART, dim3(64), 0, stream>>>(
        bQK, KfS, VfS, Qr, rel8, relvt, po, pms);
    attn_merge<<<gMERGE, blk, 0, stream>>>(po, pms, bAtt);
    gemm_mfma<64, 64, false, 0><<<dim3(8, 32), blk, 0, stream>>>(
        bAtt, wbuf + 1048576 + (size_t)i * 262144, bo_s + i * Hc, Hc, bDlt, Hc, 512);
    ln_res<<<gLN, blk, 0, stream>>>(o, bDlt, ln1g + i * Hc, ln1b + i * Hc, o, obf);

    // --- cross-attention ---
    gemm_mfma<64, 64, false, 1><<<dim3(8, 32), blk, 0, stream>>>(
        obf, wbuf + 1572864 + (size_t)i * 262144, bq_c + i * Hc, Hc, bQc, Hc, 512);
    attn_cross_part<<<gPART, dim3(64), 0, stream>>>(
        bQc, i ? KfX1 : KfX0, i ? VfX1 : VfX0, po, pms);
    attn_merge<<<gMERGE, blk, 0, stream>>>(po, pms, bAtt);
    gemm_mfma<64, 64, false, 0><<<dim3(8, 32), blk, 0, stream>>>(
        bAtt, wbuf + 3145728 + (size_t)i * 262144, bo_c + i * Hc, Hc, bDlt, Hc, 512);
    ln_res<<<gLN, blk, 0, stream>>>(o, bDlt, ln2g + i * Hc, ln2b + i * Hc, o, obf);

    // --- feedforward ---
    gemm_mfma<64, 128, true, 1><<<dim3(16, 32), blk, 0, stream>>>(
        obf, wbuf + 4194304 + (size_t)i * 1048576, b1 + i * FFc, FFc, bH, FFc, 512);
    gemm_mfma<64, 64, false, 0><<<dim3(8, 32), blk, 0, stream>>>(
        bH, wbuf + 6291456 + (size_t)i * 1048576, b2 + i * Hc, Hc, bDlt, Hc, 2048);
    float* lnout = (i == NLc - 1) ? (float*)d_out : o;
    ln_res<<<gLN, blk, 0, stream>>>(o, bDlt, ln3g + i * Hc, ln3b + i * Hc, lnout, obf);
  }
}